// Round 13
// baseline (8174.742 us; speedup 1.0000x reference)
//
#include <hip/hip_runtime.h>
#include <math.h>

// ---------------------------------------------------------------------------
// TinyMyo 8ch/400tok quant transformer — v13: gemm16 with one-shot LDS B-panel
// (no B registers, no per-iter global B) -> low VGPR, 4 waves/SIMD.
// Everything else identical to v12/v10 passing numerics.
// ---------------------------------------------------------------------------

typedef unsigned int u32;
typedef unsigned short u16;
typedef __attribute__((ext_vector_type(4))) int int4v;

#define MFMA_I8(a, b, c) __builtin_amdgcn_mfma_i32_16x16x64_i8((a), (b), (c), 0, 0, 0)

constexpr int NL = 8;
constexpr long ROWS = 102400;  // B*SEQ
constexpr float LOG2E = 1.44269504088896340736f;

// ---- scale slots ----
constexpr int SLOT_X = 0, SLOT_PW = 1, SLOT_EMB = 2, SLOT_CLF = 3, SLOT_POOL = 4;
constexpr int N_SLOT_WORDS = 200 * 16;

// ---- ws layout (float units) ----
constexpr long OFF_GM = 3200;
constexpr long OFF_GL = OFF_GM + 307200;
constexpr long OFF_POOL = OFF_GL + 307200;
constexpr long OFF_PWQ = OFF_POOL + 49152;
constexpr long OFF_CLFQ = OFF_PWQ + 3840;
constexpr long OFF_H = OFF_CLFQ + 1344;
constexpr long OFF_A = OFF_H + 19660800;
constexpr long OFF_U = OFF_A + 19660800;

// ---------------------------------------------------------------------------
// helpers
// ---------------------------------------------------------------------------
__device__ __forceinline__ float warpMax(float v) {
#pragma unroll
  for (int o = 32; o > 0; o >>= 1) v = fmaxf(v, __shfl_down(v, o));
  return v;
}

__device__ __forceinline__ float read_max16(const u32* sc, int slot) {
  const u32* p = sc + slot * 16;
  u32 m = 0;
#pragma unroll
  for (int i = 0; i < 16; ++i) m = max(m, p[i]);
  return __uint_as_float(m);
}

__device__ __forceinline__ float fqs(float x, float s) {
  return fminf(fmaxf(rintf(x / s), -128.0f), 127.0f) * s;
}

// ---------------------------------------------------------------------------
// small utility kernels
// ---------------------------------------------------------------------------
__global__ void k_zero(u32* p, int n) {
  int i = blockIdx.x * blockDim.x + threadIdx.x;
  if (i < n) p[i] = 0u;
}

__global__ __launch_bounds__(256) void k_absmax(const float4* __restrict__ x, long n4,
                                                u32* __restrict__ slot) {
  float m = 0.f;
  for (long i = (long)blockIdx.x * blockDim.x + threadIdx.x; i < n4;
       i += (long)gridDim.x * blockDim.x) {
    float4 v = x[i];
    m = fmaxf(m, fmaxf(fmaxf(fabsf(v.x), fabsf(v.y)), fmaxf(fabsf(v.z), fabsf(v.w))));
  }
  __shared__ float red[4];
  m = warpMax(m);
  int lane = threadIdx.x & 63, w = threadIdx.x >> 6;
  if (lane == 0) red[w] = m;
  __syncthreads();
  if (threadIdx.x == 0) {
    float r = fmaxf(fmaxf(red[0], red[1]), fmaxf(red[2], red[3]));
    atomicMax(slot + (blockIdx.x & 15), __float_as_uint(r));
  }
}

__global__ __launch_bounds__(256) void k_quant4(const float4* __restrict__ in,
                                                float4* __restrict__ out, long n4,
                                                const u32* __restrict__ sc, int slot) {
  float s = read_max16(sc, slot) / 127.0f + 1e-8f;
  for (long i = (long)blockIdx.x * blockDim.x + threadIdx.x; i < n4;
       i += (long)gridDim.x * blockDim.x) {
    float4 v = in[i];
    v.x = fqs(v.x, s); v.y = fqs(v.y, s); v.z = fqs(v.z, s); v.w = fqs(v.w, s);
    out[i] = v;
  }
}

__global__ __launch_bounds__(256) void k_quant_codes(const float4* __restrict__ in,
                                                     u32* __restrict__ out, long n4,
                                                     const u32* __restrict__ sc, int slot) {
  float s = read_max16(sc, slot) / 127.0f + 1e-8f;
  for (long i = (long)blockIdx.x * blockDim.x + threadIdx.x; i < n4;
       i += (long)gridDim.x * blockDim.x) {
    float4 v = in[i];
    int c0 = (int)fminf(fmaxf(rintf(v.x / s), -128.f), 127.f);
    int c1 = (int)fminf(fmaxf(rintf(v.y / s), -128.f), 127.f);
    int c2 = (int)fminf(fmaxf(rintf(v.z / s), -128.f), 127.f);
    int c3 = (int)fminf(fmaxf(rintf(v.w / s), -128.f), 127.f);
    out[i] = (u32)(c0 & 0xff) | ((u32)(c1 & 0xff) << 8) | ((u32)(c2 & 0xff) << 16) |
             ((u32)(c3 & 0xff) << 24);
  }
}

// ---------------------------------------------------------------------------
// patch embed
// ---------------------------------------------------------------------------
__global__ __launch_bounds__(192) void k_patch(const float* __restrict__ x,
                                               const float* __restrict__ pwq,
                                               const float* __restrict__ pb,
                                               const u32* __restrict__ sc,
                                               float* __restrict__ emb,
                                               u32* __restrict__ embSlot) {
  __shared__ float xq[8][20];
  __shared__ float red[3];
  const int tid = threadIdx.x;
  const long rowBase = (long)blockIdx.x * 8;
  const float sx = read_max16(sc, SLOT_X) / 127.0f + 1e-8f;
  if (tid < 160) {
    int r = tid / 20, k = tid % 20;
    xq[r][k] = fqs(x[(rowBase + r) * 20 + k], sx);
  }
  __syncthreads();
  float wreg[20];
#pragma unroll
  for (int k = 0; k < 20; ++k) wreg[k] = pwq[tid * 20 + k];
  const float bias = pb[tid];
  float m = 0.f;
  for (int r = 0; r < 8; ++r) {
    float acc = bias;
#pragma unroll
    for (int k = 0; k < 20; ++k) acc += xq[r][k] * wreg[k];
    emb[(rowBase + r) * 192 + tid] = acc;
    m = fmaxf(m, fabsf(acc));
  }
  m = warpMax(m);
  if ((tid & 63) == 0) red[tid >> 6] = m;
  __syncthreads();
  if (tid == 0)
    atomicMax(embSlot + (blockIdx.x & 15),
              __float_as_uint(fmaxf(fmaxf(red[0], red[1]), red[2])));
}

// ---------------------------------------------------------------------------
// LayerNorm (reads only H), vectorized: lane<48 owns 4 consecutive elements.
// I16: hi/lo i8 planes (packed u32 stores) + per-row scale; else fp32.
// ---------------------------------------------------------------------------
template <bool I16>
__global__ __launch_bounds__(256) void k_ln(const float* __restrict__ x,
                                            const float* __restrict__ g,
                                            const float* __restrict__ bta,
                                            signed char* __restrict__ yh,
                                            signed char* __restrict__ yl,
                                            float* __restrict__ sArow,
                                            float* __restrict__ yf, int rows) {
  int w = threadIdx.x >> 6, lane = threadIdx.x & 63;
  long row = (long)blockIdx.x * 4 + w;
  if (row >= rows) return;
  const bool act = lane < 48;
  float4 v = make_float4(0.f, 0.f, 0.f, 0.f);
  if (act) v = ((const float4*)(x + row * 192))[lane];
  float s = v.x + v.y + v.z + v.w;
#pragma unroll
  for (int o = 32; o > 0; o >>= 1) s += __shfl_down(s, o);
  s = __shfl(s, 0);
  float mean = s / 192.0f;
  float d0 = v.x - mean, d1 = v.y - mean, d2 = v.z - mean, d3 = v.w - mean;
  float q = act ? (d0 * d0 + d1 * d1 + d2 * d2 + d3 * d3) : 0.f;
#pragma unroll
  for (int o = 32; o > 0; o >>= 1) q += __shfl_down(q, o);
  q = __shfl(q, 0);
  float rs = 1.0f / sqrtf(q / 192.0f + 1e-5f);
  float4 gv = make_float4(0.f, 0.f, 0.f, 0.f), bv = gv;
  if (act) {
    gv = ((const float4*)g)[lane];
    bv = ((const float4*)bta)[lane];
  }
  float o0 = d0 * rs * gv.x + bv.x;
  float o1 = d1 * rs * gv.y + bv.y;
  float o2 = d2 * rs * gv.z + bv.z;
  float o3 = d3 * rs * gv.w + bv.w;
  if (I16) {
    float rm = act ? fmaxf(fmaxf(fabsf(o0), fabsf(o1)), fmaxf(fabsf(o2), fabsf(o3))) : 0.f;
#pragma unroll
    for (int o = 32; o > 0; o >>= 1) rm = fmaxf(rm, __shfl_down(rm, o));
    rm = __shfl(rm, 0);
    float sA = rm / 32512.0f + 1e-20f;
    float inv = 1.0f / sA;
    if (act) {
      int c0 = (int)rintf(o0 * inv), c1 = (int)rintf(o1 * inv);
      int c2 = (int)rintf(o2 * inv), c3 = (int)rintf(o3 * inv);
      int h0 = (c0 + 128) >> 8, h1 = (c1 + 128) >> 8;
      int h2 = (c2 + 128) >> 8, h3 = (c3 + 128) >> 8;
      int l0 = c0 - (h0 << 8), l1 = c1 - (h1 << 8);
      int l2 = c2 - (h2 << 8), l3 = c3 - (h3 << 8);
      u32 hw = (u32)(h0 & 0xff) | ((u32)(h1 & 0xff) << 8) | ((u32)(h2 & 0xff) << 16) |
               ((u32)(h3 & 0xff) << 24);
      u32 lw = (u32)(l0 & 0xff) | ((u32)(l1 & 0xff) << 8) | ((u32)(l2 & 0xff) << 16) |
               ((u32)(l3 & 0xff) << 24);
      ((u32*)yh)[row * 48 + lane] = hw;
      ((u32*)yl)[row * 48 + lane] = lw;
    }
    if (lane == 0) sArow[row] = sA;
  } else {
    if (act) ((float4*)(yf + row * 192))[lane] = make_float4(o0, o1, o2, o3);
  }
}

// ---------------------------------------------------------------------------
// weight fp32 -> int8 codes
// ---------------------------------------------------------------------------
__global__ __launch_bounds__(256) void k_wquant(const float4* __restrict__ w,
                                                u32* __restrict__ out, int n4,
                                                const u32* __restrict__ sc, int slot) {
  int i = blockIdx.x * blockDim.x + threadIdx.x;
  if (i >= n4) return;
  float s = read_max16(sc, slot) / 127.0f + 1e-8f;
  float4 v = w[i];
  int c0 = (int)fminf(fmaxf(rintf(v.x / s), -128.f), 127.f);
  int c1 = (int)fminf(fmaxf(rintf(v.y / s), -128.f), 127.f);
  int c2 = (int)fminf(fmaxf(rintf(v.z / s), -128.f), 127.f);
  int c3 = (int)fminf(fmaxf(rintf(v.w / s), -128.f), 127.f);
  out[i] = (u32)(c0 & 0xff) | ((u32)(c1 & 0xff) << 8) | ((u32)(c2 & 0xff) << 16) |
           ((u32)(c3 & 0xff) << 24);
}

// ---------------------------------------------------------------------------
// i16-A x i8-W GEMM. B panel staged ONCE into LDS (padded stride 208);
// A kept in a 6-register rolling window. Block = 4 waves, same 128 rows,
// wave w owns cols [colBase+48w, +48). C = sArow*sW*(256*(AH·W)+AL·W)+bias.
// OM 1: absmax only; OM 2: int8 code store.
// ---------------------------------------------------------------------------
template <bool GELU, int OM>
__global__ __launch_bounds__(256) void k_gemm16(
    const signed char* __restrict__ AH, const signed char* __restrict__ AL,
    const float* __restrict__ sArow, const signed char* __restrict__ W8, int slotW,
    const float* __restrict__ bias, signed char* __restrict__ C8, int N, int ncol,
    u32* __restrict__ sc, int slotO, int colsPerSlot) {
  __shared__ __align__(16) signed char Bs[192 * 208];
  __shared__ float red[4];
  const int tid = threadIdx.x;
  const int bid = blockIdx.x;
  const int vid = (bid & 7) * ((int)gridDim.x >> 3) + (bid >> 3);
  const int bx = vid % ncol;
  const long by = vid / ncol;
  const long rowBase = by * 128;
  const int colBase = bx * 192;
  const float sW = read_max16(sc, slotW) / 127.0f + 1e-8f;

  // stage B panel: 192 rows x 192 B, 16B chunks, 2304 chunks / 256 thr = 9
  {
    const signed char* wp = W8 + (long)colBase * 192;
#pragma unroll
    for (int it = 0; it < 9; ++it) {
      int idx = it * 256 + tid;
      int row = idx / 12, c = idx % 12;
      int4 v = *(const int4*)(wp + (long)row * 192 + c * 16);
      *(int4*)&Bs[row * 208 + c * 16] = v;
    }
  }

  const int lane = tid & 63, w = tid >> 6;
  const int fr = lane & 15, fk = lane >> 4;
  const int wc0 = w * 48;  // local col base of this wave

  float sOinv = 0.f;
  if (OM == 2) sOinv = 1.0f / (read_max16(sc, slotO + colBase / colsPerSlot) / 127.0f + 1e-8f);
  const float inv_sqrt2 = 0.70710678118654752440f;
  float vmax = 0.f;

  const long abase = (rowBase + fr) * 192 + fk * 16;
  __syncthreads();

#pragma unroll
  for (int it = 0; it < 8; ++it) {
    const long ab = abase + (long)it * 16 * 192;
    int4v ahc[3], alc[3];
#pragma unroll
    for (int kk = 0; kk < 3; ++kk) {
      ahc[kk] = *(const int4v*)(AH + ab + kk * 64);
      alc[kk] = *(const int4v*)(AL + ab + kk * 64);
    }
    int4v aH[3], aL[3];
#pragma unroll
    for (int n = 0; n < 3; ++n) {
      aH[n] = (int4v){0, 0, 0, 0};
      aL[n] = (int4v){0, 0, 0, 0};
    }
#pragma unroll
    for (int kk = 0; kk < 3; ++kk) {
#pragma unroll
      for (int n = 0; n < 3; ++n) {
        int4v bfr = *(const int4v*)&Bs[(wc0 + n * 16 + fr) * 208 + kk * 64 + fk * 16];
        aH[n] = MFMA_I8(ahc[kk], bfr, aH[n]);
        aL[n] = MFMA_I8(alc[kk], bfr, aL[n]);
      }
    }
    // epilogue for rows rowBase + it*16 + fk*4 + r
    const long rt = rowBase + it * 16;
    float4 sA4 = *(const float4*)&sArow[rt + fk * 4];
    float sAr[4] = {sA4.x, sA4.y, sA4.z, sA4.w};
#pragma unroll
    for (int n = 0; n < 3; ++n) {
      const int col = colBase + wc0 + n * 16 + fr;
      const float bb = bias[col];
#pragma unroll
      for (int r = 0; r < 4; ++r) {
        const int R = (aH[n][r] << 8) + aL[n][r];
        float val = (float)R * (sAr[r] * sW) + bb;
        if (GELU) val = 0.5f * val * (1.0f + erff(val * inv_sqrt2));
        if (OM == 2) {
          float code = fminf(fmaxf(rintf(val * sOinv), -128.f), 127.f);
          C8[(rt + fk * 4 + r) * N + col] = (signed char)code;
        } else {
          vmax = fmaxf(vmax, fabsf(val));
        }
      }
    }
  }

  if (OM == 1) {
    float m = warpMax(vmax);
    if ((tid & 63) == 0) red[tid >> 6] = m;
    __syncthreads();
    if (tid == 0) {
      float r = fmaxf(fmaxf(red[0], red[1]), fmaxf(red[2], red[3]));
      atomicMax(sc + (slotO + colBase / colsPerSlot) * 16 + ((int)(bx + by) & 15),
                __float_as_uint(r));
    }
  }
}

// ---------------------------------------------------------------------------
// i8-MFMA GEMM (A = int8 codes), LDS-free. OM 1: absmax; OM 3: H += fq.
// BM=128 BN=192.
// ---------------------------------------------------------------------------
template <int OM>
__global__ __launch_bounds__(256) void k_gemm8(
    const signed char* __restrict__ A8, int slotA, const signed char* __restrict__ W8,
    int slotW, const float* __restrict__ bias, float* __restrict__ H, int N, int K,
    u32* __restrict__ sc, int slotO) {
  __shared__ float red[4];
  const int tid = threadIdx.x;
  const long rowBase = (long)blockIdx.y * 128;
  const int colBase = blockIdx.x * 192;
  const float alpha = (read_max16(sc, slotA) / 127.0f + 1e-8f) *
                      (read_max16(sc, slotW) / 127.0f + 1e-8f);

  const int lane = tid & 63, wv = tid >> 6;
  const int wm = wv >> 1, wn = wv & 1;
  const int fr = lane & 15, fk = lane >> 4;

  int4v acc[4][6];
#pragma unroll
  for (int m = 0; m < 4; ++m)
#pragma unroll
    for (int n = 0; n < 6; ++n) acc[m][n] = (int4v){0, 0, 0, 0};

  const long arow0 = rowBase + wm * 64;
  const int bcol0 = colBase + wn * 96;

  for (int k0 = 0; k0 < K; k0 += 64) {
    const int ko = k0 + fk * 16;
    int4v bfr[6];
#pragma unroll
    for (int n = 0; n < 6; ++n)
      bfr[n] = *(const int4v*)(W8 + (long)(bcol0 + n * 16 + fr) * K + ko);
#pragma unroll
    for (int m = 0; m < 4; ++m) {
      int4v af = *(const int4v*)(A8 + (arow0 + m * 16 + fr) * (long)K + ko);
#pragma unroll
      for (int n = 0; n < 6; ++n) acc[m][n] = MFMA_I8(af, bfr[n], acc[m][n]);
    }
  }

  float sO = 1.f;
  if (OM == 3) sO = read_max16(sc, slotO) / 127.0f + 1e-8f;
  float vmax = 0.f;
#pragma unroll
  for (int n = 0; n < 6; ++n) {
    const int col = colBase + wn * 96 + n * 16 + fr;
    const float bb = bias[col];
#pragma unroll
    for (int m = 0; m < 4; ++m) {
#pragma unroll
      for (int r = 0; r < 4; ++r) {
        const long row = rowBase + wm * 64 + m * 16 + fk * 4 + r;
        float val = (float)acc[m][n][r] * alpha + bb;
        if (OM == 3) {
          H[row * N + col] += fqs(val, sO);
        } else {
          vmax = fmaxf(vmax, fabsf(val));
        }
      }
    }
  }
  if (OM == 1) {
    float m = warpMax(vmax);
    if ((tid & 63) == 0) red[tid >> 6] = m;
    __syncthreads();
    if (tid == 0) {
      float r = fmaxf(fmaxf(red[0], red[1]), fmaxf(red[2], red[3]));
      atomicMax(sc + slotO * 16 + ((blockIdx.x + blockIdx.y) & 15), __float_as_uint(r));
    }
  }
}

// ---------------------------------------------------------------------------
// k_vt: per (b,h), transpose V codes [400][64] -> VT8[bh][64][400] + colsumV.
// ---------------------------------------------------------------------------
__global__ __launch_bounds__(256) void k_vt(const signed char* __restrict__ qkv8,
                                            signed char* __restrict__ vt8,
                                            int* __restrict__ colsum) {
  __shared__ __align__(16) signed char T[64 * 80];
  __shared__ int cs[64];
  const int tid = threadIdx.x;
  const int bh = blockIdx.x, b = bh / 3, hh = bh % 3;
  const signed char* vb = qkv8 + (long)b * 400 * 576 + hh * 64 + 384;
  if (tid < 64) cs[tid] = 0;
  const int d = tid >> 2, seg = tid & 3;
  for (int c0 = 0; c0 < 448; c0 += 64) {
    __syncthreads();
    {
      int trow = tid >> 2, c = tid & 3;
      int4 v = make_int4(0, 0, 0, 0);
      if (c0 + trow < 400) v = *(const int4*)(vb + (long)(c0 + trow) * 576 + c * 16);
      *(int4*)&T[trow * 80 + c * 16] = v;
    }
    __syncthreads();
    int4 outw;
    int ssum = 0;
    u32 pk[4];
#pragma unroll
    for (int j = 0; j < 4; ++j) {
      u32 p = 0;
#pragma unroll
      for (int e = 0; e < 4; ++e) {
        int t = seg * 16 + j * 4 + e;
        int v = (int)T[t * 80 + d];
        ssum += v;
        p |= ((u32)(v & 0xff)) << (8 * e);
      }
      pk[j] = p;
    }
    outw.x = (int)pk[0]; outw.y = (int)pk[1]; outw.z = (int)pk[2]; outw.w = (int)pk[3];
    if (c0 + seg * 16 < 400)
      *(int4*)&vt8[(long)bh * 25600 + d * 400 + c0 + seg * 16] = outw;
    atomicAdd(&cs[d], ssum);
  }
  __syncthreads();
  if (tid < 64) colsum[bh * 64 + tid] = cs[tid];
}

// ---------------------------------------------------------------------------
// Attention, i8 MFMA, transposed scores, LDS-free (except P exchange in pv).
// 1D grid 5376, XCD-chunked: bh = vid/7, tile = vid%7.
// ---------------------------------------------------------------------------
__device__ __forceinline__ void attn_swz(int& tile, int& bh) {
  int bid = blockIdx.x;
  int vid = (bid & 7) * ((int)gridDim.x >> 3) + (bid >> 3);
  tile = vid % 7;
  bh = vid / 7;
}

__global__ __launch_bounds__(256) void k_attn0(const signed char* __restrict__ qkv8,
                                               int* __restrict__ gmInt, u32* __restrict__ sc,
                                               int slotQ, int slotSc) {
  __shared__ float red[4];
  const int tid = threadIdx.x;
  int tile, bh;
  attn_swz(tile, bh);
  const int r0 = tile * 64;
  const int b = bh / 3, hh = bh % 3;
  const signed char* qb = qkv8 + (long)b * 400 * 576 + hh * 64;
  const signed char* kb = qb + 192;
  const float sQ = read_max16(sc, slotQ) / 127.0f + 1e-8f;
  const float sK = read_max16(sc, slotQ + 1) / 127.0f + 1e-8f;
  const float sSc = sQ * sK * 0.125f;

  const int lane = tid & 63, w = tid >> 6, fr = lane & 15, fk = lane >> 4;
  const int qloc = 16 * w + fr;
  const int gq = r0 + qloc;
  const bool qv = gq < 400;
  int4v qf = *(const int4v*)(qb + (long)(r0 + qloc) * 576 + fk * 16);

  int aim = 0;
  int rim = -(1 << 30);
  for (int c0 = 0; c0 < 400; c0 += 128) {
#pragma unroll
    for (int tf = 0; tf < 8; ++tf) {
      int4v kf = *(const int4v*)(kb + (long)(c0 + tf * 16 + fr) * 576 + fk * 16);
      int4v s = MFMA_I8(kf, qf, ((int4v){0, 0, 0, 0}));
      const bool tv = (c0 + tf * 16 + fk * 4) < 400;
      if (tv && qv) {
#pragma unroll
        for (int r = 0; r < 4; ++r) {
          int sv = s[r];
          aim = max(aim, max(sv, -sv));
          rim = max(rim, sv);
        }
      }
    }
  }
  rim = max(rim, __shfl_xor(rim, 16));
  rim = max(rim, __shfl_xor(rim, 32));
  if (fk == 0 && qv) gmInt[(long)bh * 400 + gq] = rim;
  float m = warpMax((float)aim * sSc);
  if (lane == 0) red[w] = m;
  __syncthreads();
  if (tid == 0) {
    float r = fmaxf(fmaxf(red[0], red[1]), fmaxf(red[2], red[3]));
    atomicMax(sc + slotSc * 16 + (blockIdx.x & 15), __float_as_uint(r));
  }
}

__global__ __launch_bounds__(256) void k_attn1(const signed char* __restrict__ qkv8,
                                               float* __restrict__ gm, float* __restrict__ gl,
                                               const int* __restrict__ gmInt,
                                               u32* __restrict__ sc, int slotQ, int slotSc,
                                               int slotPr) {
  __shared__ float red[4];
  const int tid = threadIdx.x;
  int tile, bh;
  attn_swz(tile, bh);
  const int r0 = tile * 64;
  const int b = bh / 3, hh = bh % 3;
  const signed char* qb = qkv8 + (long)b * 400 * 576 + hh * 64;
  const signed char* kb = qb + 192;
  const float sQ = read_max16(sc, slotQ) / 127.0f + 1e-8f;
  const float sK = read_max16(sc, slotQ + 1) / 127.0f + 1e-8f;
  const float sSc = sQ * sK * 0.125f;
  const float sS = read_max16(sc, slotSc) / 127.0f + 1e-8f;
  const float c1 = sSc / sS;
  const float c2 = sS * LOG2E;

  const int lane = tid & 63, w = tid >> 6, fr = lane & 15, fk = lane >> 4;
  const int qloc = 16 * w + fr;
  const int gq = r0 + qloc;
  const int gqc = (gq > 399) ? 399 : gq;
  int4v qf = *(const int4v*)(qb + (long)(r0 + qloc) * 576 + fk * 16);

  const int mint = gmInt[(long)bh * 400 + gqc];
  const float cm = fminf(fmaxf(rintf((float)mint * c1), -128.f), 127.f);

  float sum = 0.f;
  for (int c0 = 0; c0 < 400; c0 += 128) {
#pragma unroll
    for (int tf = 0; tf < 8; ++tf) {
      int4v kf = *(const int4v*)(kb + (long)(c0 + tf * 16 + fr) * 576 + fk * 16);
      int4v s = MFMA_I8(kf, qf, ((int4v){0, 0, 0, 0}));
      if ((c0 + tf * 16 + fk * 4) < 400) {
#pragma unroll
        for (int r = 0; r < 4; ++r) {
          float cf = fminf(fmaxf(rintf((float)s[r] * c1), -128.f), 127.f);
          sum += exp2f((cf - cm) * c2);
        }
      }
    }
  }
  sum += __shfl_xor(sum, 16);
  sum += __shfl_xor(sum, 32);
  float cand = 0.f;
  if (fk == 0 && gq < 400) {
    gm[(long)bh * 400 + gq] = cm;
    gl[(long)bh * 400 + gq] = sum;
    cand = 1.0f / sum;
  }
  float m = warpMax(cand);
  if (lane == 0) red[w] = m;
  __syncthreads();
  if (tid == 0) {
    float r = fmaxf(fmaxf(red[0], red[1]), fmaxf(red[2], red[3]));
    atomicMax(sc + slotPr * 16 + (blockIdx.x & 15), __float_as_uint(r));
  }
}

__global__ __launch_bounds__(256) void k_attn_pv(
    const signed char* __restrict__ qkv8, const signed char* __restrict__ vt8,
    const int* __restrict__ colsumV, float* __restrict__ ctx, const float* __restrict__ gm,
    const float* __restrict__ gl, u32* __restrict__ sc, int slotQ, int slotSc, int slotPr,
    int slotCtx) {
  __shared__ __align__(16) signed char Ps[64 * 144];
  __shared__ int colsV[64];
  __shared__ float red[4];
  const int tid = threadIdx.x;
  int tile, bh;
  attn_swz(tile, bh);
  const int r0 = tile * 64;
  const int b = bh / 3, hh = bh % 3;
  const signed char* qb = qkv8 + (long)b * 400 * 576 + hh * 64;
  const signed char* kb = qb + 192;
  const signed char* vtb = vt8 + (long)bh * 25600;
  const float sQ = read_max16(sc, slotQ) / 127.0f + 1e-8f;
  const float sK = read_max16(sc, slotQ + 1) / 127.0f + 1e-8f;
  const float sV = read_max16(sc, slotQ + 2) / 127.0f + 1e-8f;
  const float sSc = sQ * sK * 0.125f;
  const float sS = read_max16(sc, slotSc) / 127.0f + 1e-8f;
  const float sP = read_max16(sc, slotPr) / 255.0f + 1e-8f;
  const float sPV = sP * sV;
  const float c1 = sSc / sS;
  const float c2 = sS * LOG2E;

  if (tid < 64) colsV[tid] = colsumV[bh * 64 + tid];
  const int lane = tid & 63, w = tid >> 6, fr = lane & 15, fk = lane >> 4;
  const int qloc = 16 * w + fr;
  int4v qf = *(const int4v*)(qb + (long)(r0 + qloc) * 576 + fk * 16);

  int gq = r0 + qloc;
  if (gq > 399) gq = 399;
  const float cm = gm[(long)bh * 400 + gq];
  const float invLsp = 1.0f / (gl[(long)bh * 400 + gq] * sP);

  int4v accd[4];
#pragma unroll
  for (int dt = 0; dt < 4; ++dt) accd[dt] = (int4v){0, 0, 0, 0};
  __syncthreads();  // colsV ready

  for (int c0 = 0; c0 < 400; c0 += 128) {
#pragma unroll
    for (int tf = 0; tf < 8; ++tf) {
      int4v kf = *(const int4v*)(kb + (long)(c0 + tf * 16 + fr) * 576 + fk * 16);
      int4v s = MFMA_I8(kf, qf, ((int4v){0, 0, 0, 0}));
      const int tbase = c0 + tf * 16 + fk * 4;
      u32 pack = 0;
      if (tbase < 400) {
#pragma unroll
        for (int r = 0; r < 4; ++r) {
          float cf = fminf(fmaxf(rintf((float)s[r] * c1), -128.f), 127.f);
          float e = exp2f((cf - cm) * c2);
          float pu = fminf(fmaxf(rintf(e * invLsp), 0.f), 255.f);
          int pc = (int)pu - 128;
          pack |= ((u32)(pc & 0xff)) << (8 * r);
        }
      }
      *(u32*)&Ps[qloc * 144 + tf * 16 + fk * 4] = pack;
    }
    __syncthreads();
    int4v pf0 = *(const int4v*)&Ps[qloc * 144 + fk * 16];
    int4v pf1 = *(const int4v*)&Ps[qloc * 144 + 64 + fk * 16];
    const bool v0ok = (c0 + fk * 16) < 400;
    const bool v1ok = (c0 + 64 + fk * 16) < 400;
#pragma unroll
    for (int dt = 0; dt < 4; ++dt) {
      const long vrow = (long)(dt * 16 + fr) * 400;
      int4v vf0 = v0ok ? *(const int4v*)(vtb + vrow + c0 + fk * 16) : (int4v){0, 0, 0, 0};
      int4v vf1 = v1ok ? *(const int4v*)(vtb + vrow + c0 + 64 + fk * 16) : (int4v){0, 0, 0, 0};
      accd[dt] = MFMA_I8(vf0, pf0, accd[dt]);
      accd[dt] = MFMA_I8(vf1, pf1, accd[dt]);
    }
    __syncthreads();
  }
  float vmax = 0.f;
  const int q = r0 + qloc;
  if (q < 400) {
#pragma unroll
    for (int dt = 0; dt < 4; ++dt) {
      const int d0 = dt * 16 + fk * 4;
      float4 o;
      o.x = sPV * (float)(accd[dt][0] + 128 * colsV[d0 + 0]);
      o.y = sPV * (float)(accd[dt][1] + 128 * colsV[d0 + 1]);
      o.z = sPV * (float)(accd[dt][2] + 128 * colsV[d0 + 2]);
      o.w = sPV * (float)(accd[dt][3] + 128 * colsV[d0 + 3]);
      vmax = fmaxf(vmax, fmaxf(fmaxf(fabsf(o.x), fabsf(o.y)), fmaxf(fabsf(o.z), fabsf(o.w))));
      *(float4*)&ctx[(long)(b * 400 + q) * 192 + hh * 64 + d0] = o;
    }
  }
  float m = warpMax(vmax);
  if (lane == 0) red[w] = m;
  __syncthreads();
  if (tid == 0) {
    float r = fmaxf(fmaxf(red[0], red[1]), fmaxf(red[2], red[3]));
    atomicMax(sc + slotCtx * 16 + (blockIdx.x & 15), __float_as_uint(r));
  }
}

// ---------------------------------------------------------------------------
// final pool + logits
// ---------------------------------------------------------------------------
__global__ __launch_bounds__(192) void k_pool(const float* __restrict__ xln,
                                              float* __restrict__ pooled,
                                              u32* __restrict__ slot) {
  int b = blockIdx.x, d = threadIdx.x;
  float sum = 0.f;
  for (int s = 0; s < 400; ++s) sum += xln[((long)b * 400 + s) * 192 + d];
  float v = sum / 400.0f;
  pooled[(long)b * 192 + d] = v;
  __shared__ float red[3];
  float m = warpMax(fabsf(v));
  if ((d & 63) == 0) red[d >> 6] = m;
  __syncthreads();
  if (d == 0)
    atomicMax(slot + (b & 15), __float_as_uint(fmaxf(fmaxf(red[0], red[1]), red[2])));
}

__global__ __launch_bounds__(64) void k_logits(const float* __restrict__ pooled,
                                               const float* __restrict__ clfq,
                                               const float* __restrict__ clfb,
                                               const u32* __restrict__ sc,
                                               float* __restrict__ out) {
  int c = blockIdx.x, b = blockIdx.y, lane = threadIdx.x;
  float sp = read_max16(sc, SLOT_POOL) / 127.0f + 1e-8f;
  float acc = 0.f;
#pragma unroll
  for (int j = 0; j < 3; ++j) {
    int d = lane + 64 * j;
    acc += fqs(pooled[(long)b * 192 + d], sp) * clfq[c * 192 + d];
  }
#pragma unroll
  for (int o = 32; o > 0; o >>= 1) acc += __shfl_down(acc, o);
  if (lane == 0) out[b * 7 + c] = acc + clfb[c];
}

// ---------------------------------------------------------------------------
// host
// ---------------------------------------------------------------------------
static inline int gsz(long n4, long cap) {
  long g = (n4 + 255) / 256;
  return (int)(g < cap ? g : cap);
}

extern "C" void kernel_launch(void* const* d_in, const int* in_sizes, int n_in,
                              void* d_out, int out_size, void* d_ws, size_t ws_size,
                              hipStream_t stream) {
  (void)in_sizes; (void)n_in; (void)out_size; (void)ws_size;

  const float* x = (const float*)d_in[0];
  const float* pw = (const float*)d_in[1];
  const float* pb = (const float*)d_in[2];
  const float* ln1g = (const float*)d_in[3];
  const float* ln1b = (const float*)d_in[4];
  const float* wqkv = (const float*)d_in[5];
  const float* bqkv = (const float*)d_in[6];
  const float* wo = (const float*)d_in[7];
  const float* bo = (const float*)d_in[8];
  const float* ln2g = (const float*)d_in[9];
  const float* ln2b = (const float*)d_in[10];
  const float* w1 = (const float*)d_in[11];
  const float* b1 = (const float*)d_in[12];
  const float* w2 = (const float*)d_in[13];
  const float* b2 = (const float*)d_in[14];
  const float* lnfg = (const float*)d_in[15];
  const float* lnfb = (const float*)d_in[16];
  const float* clfw = (const float*)d_in[17];
  const float* clfb = (const float*)d_in[18];

  float* ws = (float*)d_ws;
  u32* sc = (u32*)d_ws;
  float* GM = ws + OFF_GM;
  int* GMI = (int*)GM;
  float* GL = ws + OFF_GL;
  float* POOL = ws + OFF_POOL;
  float* PWQ = ws + OFF_PWQ;
  float* CLFQ = ws + OFF_CLFQ;
  float* H = ws + OFF_H;
  float* Af = ws + OFF_A;
  signed char* AH8 = (signed char*)(ws + OFF_A);
  signed char* AL8 = AH8 + 19660800;
  float* SAROW = (float*)(AH8 + 2 * 19660800);
  signed char* U8 = (signed char*)(ws + OFF_U);
  signed char* VT8 = U8 + 58982400;
  int* COLSUM = (int*)POOL;
  signed char* WQC = (signed char*)POOL;
  signed char* WOC2 = (signed char*)POOL;          // 36,864 B (wo)
  signed char* W1C2 = (signed char*)POOL + 36864;  // 147,456 B (w1; w2 reuses)
  signed char* W2C2 = (signed char*)POOL + 36864;
  float* out = (float*)d_out;

  k_zero<<<(N_SLOT_WORDS + 255) / 256, 256, 0, stream>>>(sc, N_SLOT_WORDS);

  auto amax = [&](const float* p, long n, int slot) {
    k_absmax<<<gsz(n / 4, 256), 256, 0, stream>>>((const float4*)p, n / 4, sc + slot * 16);
  };
  amax(pw, 3840, SLOT_PW);
  amax(clfw, 1344, SLOT_CLF);
  amax(x, 2048000, SLOT_X);
  for (int i = 0; i < NL; ++i) {
    int Lb = 16 + i * 16;
    amax(wqkv + (long)i * 110592, 110592, Lb + 0);
    amax(wo + (long)i * 36864, 36864, Lb + 1);
    amax(w1 + (long)i * 147456, 147456, Lb + 2);
    amax(w2 + (long)i * 147456, 147456, Lb + 3);
  }
  k_quant4<<<gsz(960, 256), 256, 0, stream>>>((const float4*)pw, (float4*)PWQ, 960, sc, SLOT_PW);
  k_quant4<<<gsz(336, 256), 256, 0, stream>>>((const float4*)clfw, (float4*)CLFQ, 336, sc,
                                              SLOT_CLF);

  // patch embed -> Af -> quant into H; first LN -> i16 planes
  k_patch<<<12800, 192, 0, stream>>>(x, PWQ, pb, sc, Af, sc + SLOT_EMB * 16);
  k_quant4<<<2048, 256, 0, stream>>>((const float4*)Af, (float4*)H, 19660800 / 4, sc, SLOT_EMB);
  k_ln<true><<<(int)(ROWS / 4), 256, 0, stream>>>(H, ln1g, ln1b, AH8, AL8, SAROW, nullptr,
                                                  (int)ROWS);

  for (int i = 0; i < NL; ++i) {
    int Lb = 16 + i * 16;
    // --- attention ---
    k_wquant<<<108, 256, 0, stream>>>((const float4*)(wqkv + (long)i * 110592), (u32*)WQC,
                                      27648, sc, Lb + 0);
    k_gemm16<false, 1><<<2400, 256, 0, stream>>>(AH8, AL8, SAROW, WQC, Lb + 0, bqkv + i * 576,
                                                 nullptr, 576, 3, sc, Lb + 4, 192);
    k_gemm16<false, 2><<<2400, 256, 0, stream>>>(AH8, AL8, SAROW, WQC, Lb + 0, bqkv + i * 576,
                                                 U8, 576, 3, sc, Lb + 4, 192);
    k_vt<<<768, 256, 0, stream>>>(U8, VT8, COLSUM);
    k_attn0<<<5376, 256, 0, stream>>>(U8, GMI, sc, Lb + 4, Lb + 7);
    k_attn1<<<5376, 256, 0, stream>>>(U8, GM, GL, GMI, sc, Lb + 4, Lb + 7, Lb + 8);
    k_attn_pv<<<5376, 256, 0, stream>>>(U8, VT8, COLSUM, Af, GM, GL, sc, Lb + 4, Lb + 7,
                                        Lb + 8, Lb + 9);
    // ctx fp32 (Af) -> int8 codes (U8 head); wo codes into POOL
    k_quant_codes<<<2048, 256, 0, stream>>>((const float4*)Af, (u32*)U8, 19660800 / 4, sc,
                                            Lb + 9);
    k_wquant<<<36, 256, 0, stream>>>((const float4*)(wo + (long)i * 36864), (u32*)WOC2, 9216,
                                     sc, Lb + 1);
    {
      dim3 g(1, 800);
      k_gemm8<1><<<g, 256, 0, stream>>>(U8, Lb + 9, WOC2, Lb + 1, bo + i * 192, nullptr, 192,
                                        192, sc, Lb + 10);
      k_gemm8<3><<<g, 256, 0, stream>>>(U8, Lb + 9, WOC2, Lb + 1, bo + i * 192, H, 192, 192,
                                        sc, Lb + 10);
    }
    // LN2 -> i16 planes
    k_ln<true><<<(int)(ROWS / 4), 256, 0, stream>>>(H, ln2g + i * 192, ln2b + i * 192, AH8,
                                                    AL8, SAROW, nullptr, (int)ROWS);
    // --- MLP ---
    k_wquant<<<144, 256, 0, stream>>>((const float4*)(w1 + (long)i * 147456), (u32*)W1C2,
                                      36864, sc, Lb + 2);
    k_gemm16<true, 1><<<3200, 256, 0, stream>>>(AH8, AL8, SAROW, W1C2, Lb + 2, b1 + i * 768,
                                                nullptr, 768, 4, sc, Lb + 11, 768);
    k_gemm16<true, 2><<<3200, 256, 0, stream>>>(AH8, AL8, SAROW, W1C2, Lb + 2, b1 + i * 768,
                                                U8, 768, 4, sc, Lb + 11, 768);
    k_wquant<<<144, 256, 0, stream>>>((const float4*)(w2 + (long)i * 147456), (u32*)W2C2,
                                      36864, sc, Lb + 3);
    {
      dim3 g(1, 800);
      k_gemm8<1><<<g, 256, 0, stream>>>(U8, Lb + 11, W2C2, Lb + 3, b2 + i * 192, nullptr, 192,
                                        768, sc, Lb + 12);
      k_gemm8<3><<<g, 256, 0, stream>>>(U8, Lb + 11, W2C2, Lb + 3, b2 + i * 192, H, 192, 768,
                                        sc, Lb + 12);
    }
    if (i < NL - 1) {
      k_ln<true><<<(int)(ROWS / 4), 256, 0, stream>>>(H, ln1g + (i + 1) * 192,
                                                      ln1b + (i + 1) * 192, AH8, AL8, SAROW,
                                                      nullptr, (int)ROWS);
    } else {
      k_ln<false><<<(int)(ROWS / 4), 256, 0, stream>>>(H, lnfg, lnfb, nullptr, nullptr,
                                                       nullptr, Af, (int)ROWS);
    }
  }

  // pool + classifier
  k_pool<<<256, 192, 0, stream>>>(Af, POOL, sc + SLOT_POOL * 16);
  {
    dim3 g(7, 256);
    k_logits<<<g, 64, 0, stream>>>(POOL, CLFQ, clfb, sc, out);
  }
}

// Round 14
// 6999.165 us; speedup vs baseline: 1.1680x; 1.1680x over previous
//
#include <hip/hip_runtime.h>
#include <math.h>

// ---------------------------------------------------------------------------
// TinyMyo 8ch/400tok quant transformer — v14: v13 + `#pragma unroll 1` on the
// gemm16 row loop (stop full-unroll register bloat; TLP-based latency hiding).
// ---------------------------------------------------------------------------

typedef unsigned int u32;
typedef unsigned short u16;
typedef __attribute__((ext_vector_type(4))) int int4v;

#define MFMA_I8(a, b, c) __builtin_amdgcn_mfma_i32_16x16x64_i8((a), (b), (c), 0, 0, 0)

constexpr int NL = 8;
constexpr long ROWS = 102400;  // B*SEQ
constexpr float LOG2E = 1.44269504088896340736f;

// ---- scale slots ----
constexpr int SLOT_X = 0, SLOT_PW = 1, SLOT_EMB = 2, SLOT_CLF = 3, SLOT_POOL = 4;
constexpr int N_SLOT_WORDS = 200 * 16;

// ---- ws layout (float units) ----
constexpr long OFF_GM = 3200;
constexpr long OFF_GL = OFF_GM + 307200;
constexpr long OFF_POOL = OFF_GL + 307200;
constexpr long OFF_PWQ = OFF_POOL + 49152;
constexpr long OFF_CLFQ = OFF_PWQ + 3840;
constexpr long OFF_H = OFF_CLFQ + 1344;
constexpr long OFF_A = OFF_H + 19660800;
constexpr long OFF_U = OFF_A + 19660800;

// ---------------------------------------------------------------------------
// helpers
// ---------------------------------------------------------------------------
__device__ __forceinline__ float warpMax(float v) {
#pragma unroll
  for (int o = 32; o > 0; o >>= 1) v = fmaxf(v, __shfl_down(v, o));
  return v;
}

__device__ __forceinline__ float read_max16(const u32* sc, int slot) {
  const u32* p = sc + slot * 16;
  u32 m = 0;
#pragma unroll
  for (int i = 0; i < 16; ++i) m = max(m, p[i]);
  return __uint_as_float(m);
}

__device__ __forceinline__ float fqs(float x, float s) {
  return fminf(fmaxf(rintf(x / s), -128.0f), 127.0f) * s;
}

// ---------------------------------------------------------------------------
// small utility kernels
// ---------------------------------------------------------------------------
__global__ void k_zero(u32* p, int n) {
  int i = blockIdx.x * blockDim.x + threadIdx.x;
  if (i < n) p[i] = 0u;
}

__global__ __launch_bounds__(256) void k_absmax(const float4* __restrict__ x, long n4,
                                                u32* __restrict__ slot) {
  float m = 0.f;
  for (long i = (long)blockIdx.x * blockDim.x + threadIdx.x; i < n4;
       i += (long)gridDim.x * blockDim.x) {
    float4 v = x[i];
    m = fmaxf(m, fmaxf(fmaxf(fabsf(v.x), fabsf(v.y)), fmaxf(fabsf(v.z), fabsf(v.w))));
  }
  __shared__ float red[4];
  m = warpMax(m);
  int lane = threadIdx.x & 63, w = threadIdx.x >> 6;
  if (lane == 0) red[w] = m;
  __syncthreads();
  if (threadIdx.x == 0) {
    float r = fmaxf(fmaxf(red[0], red[1]), fmaxf(red[2], red[3]));
    atomicMax(slot + (blockIdx.x & 15), __float_as_uint(r));
  }
}

__global__ __launch_bounds__(256) void k_quant4(const float4* __restrict__ in,
                                                float4* __restrict__ out, long n4,
                                                const u32* __restrict__ sc, int slot) {
  float s = read_max16(sc, slot) / 127.0f + 1e-8f;
  for (long i = (long)blockIdx.x * blockDim.x + threadIdx.x; i < n4;
       i += (long)gridDim.x * blockDim.x) {
    float4 v = in[i];
    v.x = fqs(v.x, s); v.y = fqs(v.y, s); v.z = fqs(v.z, s); v.w = fqs(v.w, s);
    out[i] = v;
  }
}

__global__ __launch_bounds__(256) void k_quant_codes(const float4* __restrict__ in,
                                                     u32* __restrict__ out, long n4,
                                                     const u32* __restrict__ sc, int slot) {
  float s = read_max16(sc, slot) / 127.0f + 1e-8f;
  for (long i = (long)blockIdx.x * blockDim.x + threadIdx.x; i < n4;
       i += (long)gridDim.x * blockDim.x) {
    float4 v = in[i];
    int c0 = (int)fminf(fmaxf(rintf(v.x / s), -128.f), 127.f);
    int c1 = (int)fminf(fmaxf(rintf(v.y / s), -128.f), 127.f);
    int c2 = (int)fminf(fmaxf(rintf(v.z / s), -128.f), 127.f);
    int c3 = (int)fminf(fmaxf(rintf(v.w / s), -128.f), 127.f);
    out[i] = (u32)(c0 & 0xff) | ((u32)(c1 & 0xff) << 8) | ((u32)(c2 & 0xff) << 16) |
             ((u32)(c3 & 0xff) << 24);
  }
}

// ---------------------------------------------------------------------------
// patch embed
// ---------------------------------------------------------------------------
__global__ __launch_bounds__(192) void k_patch(const float* __restrict__ x,
                                               const float* __restrict__ pwq,
                                               const float* __restrict__ pb,
                                               const u32* __restrict__ sc,
                                               float* __restrict__ emb,
                                               u32* __restrict__ embSlot) {
  __shared__ float xq[8][20];
  __shared__ float red[3];
  const int tid = threadIdx.x;
  const long rowBase = (long)blockIdx.x * 8;
  const float sx = read_max16(sc, SLOT_X) / 127.0f + 1e-8f;
  if (tid < 160) {
    int r = tid / 20, k = tid % 20;
    xq[r][k] = fqs(x[(rowBase + r) * 20 + k], sx);
  }
  __syncthreads();
  float wreg[20];
#pragma unroll
  for (int k = 0; k < 20; ++k) wreg[k] = pwq[tid * 20 + k];
  const float bias = pb[tid];
  float m = 0.f;
  for (int r = 0; r < 8; ++r) {
    float acc = bias;
#pragma unroll
    for (int k = 0; k < 20; ++k) acc += xq[r][k] * wreg[k];
    emb[(rowBase + r) * 192 + tid] = acc;
    m = fmaxf(m, fabsf(acc));
  }
  m = warpMax(m);
  if ((tid & 63) == 0) red[tid >> 6] = m;
  __syncthreads();
  if (tid == 0)
    atomicMax(embSlot + (blockIdx.x & 15),
              __float_as_uint(fmaxf(fmaxf(red[0], red[1]), red[2])));
}

// ---------------------------------------------------------------------------
// LayerNorm (reads only H), vectorized: lane<48 owns 4 consecutive elements.
// I16: hi/lo i8 planes (packed u32 stores) + per-row scale; else fp32.
// ---------------------------------------------------------------------------
template <bool I16>
__global__ __launch_bounds__(256) void k_ln(const float* __restrict__ x,
                                            const float* __restrict__ g,
                                            const float* __restrict__ bta,
                                            signed char* __restrict__ yh,
                                            signed char* __restrict__ yl,
                                            float* __restrict__ sArow,
                                            float* __restrict__ yf, int rows) {
  int w = threadIdx.x >> 6, lane = threadIdx.x & 63;
  long row = (long)blockIdx.x * 4 + w;
  if (row >= rows) return;
  const bool act = lane < 48;
  float4 v = make_float4(0.f, 0.f, 0.f, 0.f);
  if (act) v = ((const float4*)(x + row * 192))[lane];
  float s = v.x + v.y + v.z + v.w;
#pragma unroll
  for (int o = 32; o > 0; o >>= 1) s += __shfl_down(s, o);
  s = __shfl(s, 0);
  float mean = s / 192.0f;
  float d0 = v.x - mean, d1 = v.y - mean, d2 = v.z - mean, d3 = v.w - mean;
  float q = act ? (d0 * d0 + d1 * d1 + d2 * d2 + d3 * d3) : 0.f;
#pragma unroll
  for (int o = 32; o > 0; o >>= 1) q += __shfl_down(q, o);
  q = __shfl(q, 0);
  float rs = 1.0f / sqrtf(q / 192.0f + 1e-5f);
  float4 gv = make_float4(0.f, 0.f, 0.f, 0.f), bv = gv;
  if (act) {
    gv = ((const float4*)g)[lane];
    bv = ((const float4*)bta)[lane];
  }
  float o0 = d0 * rs * gv.x + bv.x;
  float o1 = d1 * rs * gv.y + bv.y;
  float o2 = d2 * rs * gv.z + bv.z;
  float o3 = d3 * rs * gv.w + bv.w;
  if (I16) {
    float rm = act ? fmaxf(fmaxf(fabsf(o0), fabsf(o1)), fmaxf(fabsf(o2), fabsf(o3))) : 0.f;
#pragma unroll
    for (int o = 32; o > 0; o >>= 1) rm = fmaxf(rm, __shfl_down(rm, o));
    rm = __shfl(rm, 0);
    float sA = rm / 32512.0f + 1e-20f;
    float inv = 1.0f / sA;
    if (act) {
      int c0 = (int)rintf(o0 * inv), c1 = (int)rintf(o1 * inv);
      int c2 = (int)rintf(o2 * inv), c3 = (int)rintf(o3 * inv);
      int h0 = (c0 + 128) >> 8, h1 = (c1 + 128) >> 8;
      int h2 = (c2 + 128) >> 8, h3 = (c3 + 128) >> 8;
      int l0 = c0 - (h0 << 8), l1 = c1 - (h1 << 8);
      int l2 = c2 - (h2 << 8), l3 = c3 - (h3 << 8);
      u32 hw = (u32)(h0 & 0xff) | ((u32)(h1 & 0xff) << 8) | ((u32)(h2 & 0xff) << 16) |
               ((u32)(h3 & 0xff) << 24);
      u32 lw = (u32)(l0 & 0xff) | ((u32)(l1 & 0xff) << 8) | ((u32)(l2 & 0xff) << 16) |
               ((u32)(l3 & 0xff) << 24);
      ((u32*)yh)[row * 48 + lane] = hw;
      ((u32*)yl)[row * 48 + lane] = lw;
    }
    if (lane == 0) sArow[row] = sA;
  } else {
    if (act) ((float4*)(yf + row * 192))[lane] = make_float4(o0, o1, o2, o3);
  }
}

// ---------------------------------------------------------------------------
// weight fp32 -> int8 codes
// ---------------------------------------------------------------------------
__global__ __launch_bounds__(256) void k_wquant(const float4* __restrict__ w,
                                                u32* __restrict__ out, int n4,
                                                const u32* __restrict__ sc, int slot) {
  int i = blockIdx.x * blockDim.x + threadIdx.x;
  if (i >= n4) return;
  float s = read_max16(sc, slot) / 127.0f + 1e-8f;
  float4 v = w[i];
  int c0 = (int)fminf(fmaxf(rintf(v.x / s), -128.f), 127.f);
  int c1 = (int)fminf(fmaxf(rintf(v.y / s), -128.f), 127.f);
  int c2 = (int)fminf(fmaxf(rintf(v.z / s), -128.f), 127.f);
  int c3 = (int)fminf(fmaxf(rintf(v.w / s), -128.f), 127.f);
  out[i] = (u32)(c0 & 0xff) | ((u32)(c1 & 0xff) << 8) | ((u32)(c2 & 0xff) << 16) |
           ((u32)(c3 & 0xff) << 24);
}

// ---------------------------------------------------------------------------
// i16-A x i8-W GEMM. B panel staged ONCE into LDS (padded stride 208);
// row loop NOT unrolled (unroll 1) to keep VGPR low and occupancy high.
// Block = 4 waves, same 128 rows, wave w owns cols [colBase+48w, +48).
// C = sArow*sW*(256*(AH·W)+AL·W)+bias [,gelu].
// OM 1: absmax only; OM 2: int8 code store.
// ---------------------------------------------------------------------------
template <bool GELU, int OM>
__global__ __launch_bounds__(256) void k_gemm16(
    const signed char* __restrict__ AH, const signed char* __restrict__ AL,
    const float* __restrict__ sArow, const signed char* __restrict__ W8, int slotW,
    const float* __restrict__ bias, signed char* __restrict__ C8, int N, int ncol,
    u32* __restrict__ sc, int slotO, int colsPerSlot) {
  __shared__ __align__(16) signed char Bs[192 * 208];
  __shared__ float red[4];
  const int tid = threadIdx.x;
  const int bid = blockIdx.x;
  const int vid = (bid & 7) * ((int)gridDim.x >> 3) + (bid >> 3);
  const int bx = vid % ncol;
  const long by = vid / ncol;
  const long rowBase = by * 128;
  const int colBase = bx * 192;
  const float sW = read_max16(sc, slotW) / 127.0f + 1e-8f;

  // stage B panel: 192 rows x 192 B, 16B chunks, 2304 chunks / 256 thr = 9
  {
    const signed char* wp = W8 + (long)colBase * 192;
#pragma unroll
    for (int it = 0; it < 9; ++it) {
      int idx = it * 256 + tid;
      int row = idx / 12, c = idx % 12;
      int4 v = *(const int4*)(wp + (long)row * 192 + c * 16);
      *(int4*)&Bs[row * 208 + c * 16] = v;
    }
  }

  const int lane = tid & 63, w = tid >> 6;
  const int fr = lane & 15, fk = lane >> 4;
  const int wc0 = w * 48;  // local col base of this wave

  float sOinv = 0.f;
  if (OM == 2) sOinv = 1.0f / (read_max16(sc, slotO + colBase / colsPerSlot) / 127.0f + 1e-8f);
  const float inv_sqrt2 = 0.70710678118654752440f;
  float vmax = 0.f;

  const long abase = (rowBase + fr) * 192 + fk * 16;
  __syncthreads();

#pragma unroll 1
  for (int it = 0; it < 8; ++it) {
    const long ab = abase + (long)it * 16 * 192;
    int4v ahc[3], alc[3];
#pragma unroll
    for (int kk = 0; kk < 3; ++kk) {
      ahc[kk] = *(const int4v*)(AH + ab + kk * 64);
      alc[kk] = *(const int4v*)(AL + ab + kk * 64);
    }
    int4v aH[3], aL[3];
#pragma unroll
    for (int n = 0; n < 3; ++n) {
      aH[n] = (int4v){0, 0, 0, 0};
      aL[n] = (int4v){0, 0, 0, 0};
    }
#pragma unroll
    for (int kk = 0; kk < 3; ++kk) {
#pragma unroll
      for (int n = 0; n < 3; ++n) {
        int4v bfr = *(const int4v*)&Bs[(wc0 + n * 16 + fr) * 208 + kk * 64 + fk * 16];
        aH[n] = MFMA_I8(ahc[kk], bfr, aH[n]);
        aL[n] = MFMA_I8(alc[kk], bfr, aL[n]);
      }
    }
    // epilogue for rows rowBase + it*16 + fk*4 + r
    const long rt = rowBase + it * 16;
    float4 sA4 = *(const float4*)&sArow[rt + fk * 4];
    float sAr[4] = {sA4.x, sA4.y, sA4.z, sA4.w};
#pragma unroll
    for (int n = 0; n < 3; ++n) {
      const int col = colBase + wc0 + n * 16 + fr;
      const float bb = bias[col];
#pragma unroll
      for (int r = 0; r < 4; ++r) {
        const int R = (aH[n][r] << 8) + aL[n][r];
        float val = (float)R * (sAr[r] * sW) + bb;
        if (GELU) val = 0.5f * val * (1.0f + erff(val * inv_sqrt2));
        if (OM == 2) {
          float code = fminf(fmaxf(rintf(val * sOinv), -128.f), 127.f);
          C8[(rt + fk * 4 + r) * N + col] = (signed char)code;
        } else {
          vmax = fmaxf(vmax, fabsf(val));
        }
      }
    }
  }

  if (OM == 1) {
    float m = warpMax(vmax);
    if ((tid & 63) == 0) red[tid >> 6] = m;
    __syncthreads();
    if (tid == 0) {
      float r = fmaxf(fmaxf(red[0], red[1]), fmaxf(red[2], red[3]));
      atomicMax(sc + (slotO + colBase / colsPerSlot) * 16 + ((int)(bx + by) & 15),
                __float_as_uint(r));
    }
  }
}

// ---------------------------------------------------------------------------
// i8-MFMA GEMM (A = int8 codes), LDS-free. OM 1: absmax; OM 3: H += fq.
// BM=128 BN=192.
// ---------------------------------------------------------------------------
template <int OM>
__global__ __launch_bounds__(256) void k_gemm8(
    const signed char* __restrict__ A8, int slotA, const signed char* __restrict__ W8,
    int slotW, const float* __restrict__ bias, float* __restrict__ H, int N, int K,
    u32* __restrict__ sc, int slotO) {
  __shared__ float red[4];
  const int tid = threadIdx.x;
  const long rowBase = (long)blockIdx.y * 128;
  const int colBase = blockIdx.x * 192;
  const float alpha = (read_max16(sc, slotA) / 127.0f + 1e-8f) *
                      (read_max16(sc, slotW) / 127.0f + 1e-8f);

  const int lane = tid & 63, wv = tid >> 6;
  const int wm = wv >> 1, wn = wv & 1;
  const int fr = lane & 15, fk = lane >> 4;

  int4v acc[4][6];
#pragma unroll
  for (int m = 0; m < 4; ++m)
#pragma unroll
    for (int n = 0; n < 6; ++n) acc[m][n] = (int4v){0, 0, 0, 0};

  const long arow0 = rowBase + wm * 64;
  const int bcol0 = colBase + wn * 96;

  for (int k0 = 0; k0 < K; k0 += 64) {
    const int ko = k0 + fk * 16;
    int4v bfr[6];
#pragma unroll
    for (int n = 0; n < 6; ++n)
      bfr[n] = *(const int4v*)(W8 + (long)(bcol0 + n * 16 + fr) * K + ko);
#pragma unroll
    for (int m = 0; m < 4; ++m) {
      int4v af = *(const int4v*)(A8 + (arow0 + m * 16 + fr) * (long)K + ko);
#pragma unroll
      for (int n = 0; n < 6; ++n) acc[m][n] = MFMA_I8(af, bfr[n], acc[m][n]);
    }
  }

  float sO = 1.f;
  if (OM == 3) sO = read_max16(sc, slotO) / 127.0f + 1e-8f;
  float vmax = 0.f;
#pragma unroll
  for (int n = 0; n < 6; ++n) {
    const int col = colBase + wn * 96 + n * 16 + fr;
    const float bb = bias[col];
#pragma unroll
    for (int m = 0; m < 4; ++m) {
#pragma unroll
      for (int r = 0; r < 4; ++r) {
        const long row = rowBase + wm * 64 + m * 16 + fk * 4 + r;
        float val = (float)acc[m][n][r] * alpha + bb;
        if (OM == 3) {
          H[row * N + col] += fqs(val, sO);
        } else {
          vmax = fmaxf(vmax, fabsf(val));
        }
      }
    }
  }
  if (OM == 1) {
    float m = warpMax(vmax);
    if ((tid & 63) == 0) red[tid >> 6] = m;
    __syncthreads();
    if (tid == 0) {
      float r = fmaxf(fmaxf(red[0], red[1]), fmaxf(red[2], red[3]));
      atomicMax(sc + slotO * 16 + ((blockIdx.x + blockIdx.y) & 15), __float_as_uint(r));
    }
  }
}

// ---------------------------------------------------------------------------
// k_vt: per (b,h), transpose V codes [400][64] -> VT8[bh][64][400] + colsumV.
// ---------------------------------------------------------------------------
__global__ __launch_bounds__(256) void k_vt(const signed char* __restrict__ qkv8,
                                            signed char* __restrict__ vt8,
                                            int* __restrict__ colsum) {
  __shared__ __align__(16) signed char T[64 * 80];
  __shared__ int cs[64];
  const int tid = threadIdx.x;
  const int bh = blockIdx.x, b = bh / 3, hh = bh % 3;
  const signed char* vb = qkv8 + (long)b * 400 * 576 + hh * 64 + 384;
  if (tid < 64) cs[tid] = 0;
  const int d = tid >> 2, seg = tid & 3;
  for (int c0 = 0; c0 < 448; c0 += 64) {
    __syncthreads();
    {
      int trow = tid >> 2, c = tid & 3;
      int4 v = make_int4(0, 0, 0, 0);
      if (c0 + trow < 400) v = *(const int4*)(vb + (long)(c0 + trow) * 576 + c * 16);
      *(int4*)&T[trow * 80 + c * 16] = v;
    }
    __syncthreads();
    int4 outw;
    int ssum = 0;
    u32 pk[4];
#pragma unroll
    for (int j = 0; j < 4; ++j) {
      u32 p = 0;
#pragma unroll
      for (int e = 0; e < 4; ++e) {
        int t = seg * 16 + j * 4 + e;
        int v = (int)T[t * 80 + d];
        ssum += v;
        p |= ((u32)(v & 0xff)) << (8 * e);
      }
      pk[j] = p;
    }
    outw.x = (int)pk[0]; outw.y = (int)pk[1]; outw.z = (int)pk[2]; outw.w = (int)pk[3];
    if (c0 + seg * 16 < 400)
      *(int4*)&vt8[(long)bh * 25600 + d * 400 + c0 + seg * 16] = outw;
    atomicAdd(&cs[d], ssum);
  }
  __syncthreads();
  if (tid < 64) colsum[bh * 64 + tid] = cs[tid];
}

// ---------------------------------------------------------------------------
// Attention, i8 MFMA, transposed scores, LDS-free (except P exchange in pv).
// 1D grid 5376, XCD-chunked: bh = vid/7, tile = vid%7.
// ---------------------------------------------------------------------------
__device__ __forceinline__ void attn_swz(int& tile, int& bh) {
  int bid = blockIdx.x;
  int vid = (bid & 7) * ((int)gridDim.x >> 3) + (bid >> 3);
  tile = vid % 7;
  bh = vid / 7;
}

__global__ __launch_bounds__(256) void k_attn0(const signed char* __restrict__ qkv8,
                                               int* __restrict__ gmInt, u32* __restrict__ sc,
                                               int slotQ, int slotSc) {
  __shared__ float red[4];
  const int tid = threadIdx.x;
  int tile, bh;
  attn_swz(tile, bh);
  const int r0 = tile * 64;
  const int b = bh / 3, hh = bh % 3;
  const signed char* qb = qkv8 + (long)b * 400 * 576 + hh * 64;
  const signed char* kb = qb + 192;
  const float sQ = read_max16(sc, slotQ) / 127.0f + 1e-8f;
  const float sK = read_max16(sc, slotQ + 1) / 127.0f + 1e-8f;
  const float sSc = sQ * sK * 0.125f;

  const int lane = tid & 63, w = tid >> 6, fr = lane & 15, fk = lane >> 4;
  const int qloc = 16 * w + fr;
  const int gq = r0 + qloc;
  const bool qv = gq < 400;
  int4v qf = *(const int4v*)(qb + (long)(r0 + qloc) * 576 + fk * 16);

  int aim = 0;
  int rim = -(1 << 30);
  for (int c0 = 0; c0 < 400; c0 += 128) {
#pragma unroll
    for (int tf = 0; tf < 8; ++tf) {
      int4v kf = *(const int4v*)(kb + (long)(c0 + tf * 16 + fr) * 576 + fk * 16);
      int4v s = MFMA_I8(kf, qf, ((int4v){0, 0, 0, 0}));
      const bool tv = (c0 + tf * 16 + fk * 4) < 400;
      if (tv && qv) {
#pragma unroll
        for (int r = 0; r < 4; ++r) {
          int sv = s[r];
          aim = max(aim, max(sv, -sv));
          rim = max(rim, sv);
        }
      }
    }
  }
  rim = max(rim, __shfl_xor(rim, 16));
  rim = max(rim, __shfl_xor(rim, 32));
  if (fk == 0 && qv) gmInt[(long)bh * 400 + gq] = rim;
  float m = warpMax((float)aim * sSc);
  if (lane == 0) red[w] = m;
  __syncthreads();
  if (tid == 0) {
    float r = fmaxf(fmaxf(red[0], red[1]), fmaxf(red[2], red[3]));
    atomicMax(sc + slotSc * 16 + (blockIdx.x & 15), __float_as_uint(r));
  }
}

__global__ __launch_bounds__(256) void k_attn1(const signed char* __restrict__ qkv8,
                                               float* __restrict__ gm, float* __restrict__ gl,
                                               const int* __restrict__ gmInt,
                                               u32* __restrict__ sc, int slotQ, int slotSc,
                                               int slotPr) {
  __shared__ float red[4];
  const int tid = threadIdx.x;
  int tile, bh;
  attn_swz(tile, bh);
  const int r0 = tile * 64;
  const int b = bh / 3, hh = bh % 3;
  const signed char* qb = qkv8 + (long)b * 400 * 576 + hh * 64;
  const signed char* kb = qb + 192;
  const float sQ = read_max16(sc, slotQ) / 127.0f + 1e-8f;
  const float sK = read_max16(sc, slotQ + 1) / 127.0f + 1e-8f;
  const float sSc = sQ * sK * 0.125f;
  const float sS = read_max16(sc, slotSc) / 127.0f + 1e-8f;
  const float c1 = sSc / sS;
  const float c2 = sS * LOG2E;

  const int lane = tid & 63, w = tid >> 6, fr = lane & 15, fk = lane >> 4;
  const int qloc = 16 * w + fr;
  const int gq = r0 + qloc;
  const int gqc = (gq > 399) ? 399 : gq;
  int4v qf = *(const int4v*)(qb + (long)(r0 + qloc) * 576 + fk * 16);

  const int mint = gmInt[(long)bh * 400 + gqc];
  const float cm = fminf(fmaxf(rintf((float)mint * c1), -128.f), 127.f);

  float sum = 0.f;
  for (int c0 = 0; c0 < 400; c0 += 128) {
#pragma unroll
    for (int tf = 0; tf < 8; ++tf) {
      int4v kf = *(const int4v*)(kb + (long)(c0 + tf * 16 + fr) * 576 + fk * 16);
      int4v s = MFMA_I8(kf, qf, ((int4v){0, 0, 0, 0}));
      if ((c0 + tf * 16 + fk * 4) < 400) {
#pragma unroll
        for (int r = 0; r < 4; ++r) {
          float cf = fminf(fmaxf(rintf((float)s[r] * c1), -128.f), 127.f);
          sum += exp2f((cf - cm) * c2);
        }
      }
    }
  }
  sum += __shfl_xor(sum, 16);
  sum += __shfl_xor(sum, 32);
  float cand = 0.f;
  if (fk == 0 && gq < 400) {
    gm[(long)bh * 400 + gq] = cm;
    gl[(long)bh * 400 + gq] = sum;
    cand = 1.0f / sum;
  }
  float m = warpMax(cand);
  if (lane == 0) red[w] = m;
  __syncthreads();
  if (tid == 0) {
    float r = fmaxf(fmaxf(red[0], red[1]), fmaxf(red[2], red[3]));
    atomicMax(sc + slotPr * 16 + (blockIdx.x & 15), __float_as_uint(r));
  }
}

__global__ __launch_bounds__(256) void k_attn_pv(
    const signed char* __restrict__ qkv8, const signed char* __restrict__ vt8,
    const int* __restrict__ colsumV, float* __restrict__ ctx, const float* __restrict__ gm,
    const float* __restrict__ gl, u32* __restrict__ sc, int slotQ, int slotSc, int slotPr,
    int slotCtx) {
  __shared__ __align__(16) signed char Ps[64 * 144];
  __shared__ int colsV[64];
  __shared__ float red[4];
  const int tid = threadIdx.x;
  int tile, bh;
  attn_swz(tile, bh);
  const int r0 = tile * 64;
  const int b = bh / 3, hh = bh % 3;
  const signed char* qb = qkv8 + (long)b * 400 * 576 + hh * 64;
  const signed char* kb = qb + 192;
  const signed char* vtb = vt8 + (long)bh * 25600;
  const float sQ = read_max16(sc, slotQ) / 127.0f + 1e-8f;
  const float sK = read_max16(sc, slotQ + 1) / 127.0f + 1e-8f;
  const float sV = read_max16(sc, slotQ + 2) / 127.0f + 1e-8f;
  const float sSc = sQ * sK * 0.125f;
  const float sS = read_max16(sc, slotSc) / 127.0f + 1e-8f;
  const float sP = read_max16(sc, slotPr) / 255.0f + 1e-8f;
  const float sPV = sP * sV;
  const float c1 = sSc / sS;
  const float c2 = sS * LOG2E;

  if (tid < 64) colsV[tid] = colsumV[bh * 64 + tid];
  const int lane = tid & 63, w = tid >> 6, fr = lane & 15, fk = lane >> 4;
  const int qloc = 16 * w + fr;
  int4v qf = *(const int4v*)(qb + (long)(r0 + qloc) * 576 + fk * 16);

  int gq = r0 + qloc;
  if (gq > 399) gq = 399;
  const float cm = gm[(long)bh * 400 + gq];
  const float invLsp = 1.0f / (gl[(long)bh * 400 + gq] * sP);

  int4v accd[4];
#pragma unroll
  for (int dt = 0; dt < 4; ++dt) accd[dt] = (int4v){0, 0, 0, 0};
  __syncthreads();  // colsV ready

  for (int c0 = 0; c0 < 400; c0 += 128) {
#pragma unroll
    for (int tf = 0; tf < 8; ++tf) {
      int4v kf = *(const int4v*)(kb + (long)(c0 + tf * 16 + fr) * 576 + fk * 16);
      int4v s = MFMA_I8(kf, qf, ((int4v){0, 0, 0, 0}));
      const int tbase = c0 + tf * 16 + fk * 4;
      u32 pack = 0;
      if (tbase < 400) {
#pragma unroll
        for (int r = 0; r < 4; ++r) {
          float cf = fminf(fmaxf(rintf((float)s[r] * c1), -128.f), 127.f);
          float e = exp2f((cf - cm) * c2);
          float pu = fminf(fmaxf(rintf(e * invLsp), 0.f), 255.f);
          int pc = (int)pu - 128;
          pack |= ((u32)(pc & 0xff)) << (8 * r);
        }
      }
      *(u32*)&Ps[qloc * 144 + tf * 16 + fk * 4] = pack;
    }
    __syncthreads();
    int4v pf0 = *(const int4v*)&Ps[qloc * 144 + fk * 16];
    int4v pf1 = *(const int4v*)&Ps[qloc * 144 + 64 + fk * 16];
    const bool v0ok = (c0 + fk * 16) < 400;
    const bool v1ok = (c0 + 64 + fk * 16) < 400;
#pragma unroll
    for (int dt = 0; dt < 4; ++dt) {
      const long vrow = (long)(dt * 16 + fr) * 400;
      int4v vf0 = v0ok ? *(const int4v*)(vtb + vrow + c0 + fk * 16) : (int4v){0, 0, 0, 0};
      int4v vf1 = v1ok ? *(const int4v*)(vtb + vrow + c0 + 64 + fk * 16) : (int4v){0, 0, 0, 0};
      accd[dt] = MFMA_I8(vf0, pf0, accd[dt]);
      accd[dt] = MFMA_I8(vf1, pf1, accd[dt]);
    }
    __syncthreads();
  }
  float vmax = 0.f;
  const int q = r0 + qloc;
  if (q < 400) {
#pragma unroll
    for (int dt = 0; dt < 4; ++dt) {
      const int d0 = dt * 16 + fk * 4;
      float4 o;
      o.x = sPV * (float)(accd[dt][0] + 128 * colsV[d0 + 0]);
      o.y = sPV * (float)(accd[dt][1] + 128 * colsV[d0 + 1]);
      o.z = sPV * (float)(accd[dt][2] + 128 * colsV[d0 + 2]);
      o.w = sPV * (float)(accd[dt][3] + 128 * colsV[d0 + 3]);
      vmax = fmaxf(vmax, fmaxf(fmaxf(fabsf(o.x), fabsf(o.y)), fmaxf(fabsf(o.z), fabsf(o.w))));
      *(float4*)&ctx[(long)(b * 400 + q) * 192 + hh * 64 + d0] = o;
    }
  }
  float m = warpMax(vmax);
  if (lane == 0) red[w] = m;
  __syncthreads();
  if (tid == 0) {
    float r = fmaxf(fmaxf(red[0], red[1]), fmaxf(red[2], red[3]));
    atomicMax(sc + slotCtx * 16 + (blockIdx.x & 15), __float_as_uint(r));
  }
}

// ---------------------------------------------------------------------------
// final pool + logits
// ---------------------------------------------------------------------------
__global__ __launch_bounds__(192) void k_pool(const float* __restrict__ xln,
                                              float* __restrict__ pooled,
                                              u32* __restrict__ slot) {
  int b = blockIdx.x, d = threadIdx.x;
  float sum = 0.f;
  for (int s = 0; s < 400; ++s) sum += xln[((long)b * 400 + s) * 192 + d];
  float v = sum / 400.0f;
  pooled[(long)b * 192 + d] = v;
  __shared__ float red[3];
  float m = warpMax(fabsf(v));
  if ((d & 63) == 0) red[d >> 6] = m;
  __syncthreads();
  if (d == 0)
    atomicMax(slot + (b & 15), __float_as_uint(fmaxf(fmaxf(red[0], red[1]), red[2])));
}

__global__ __launch_bounds__(64) void k_logits(const float* __restrict__ pooled,
                                               const float* __restrict__ clfq,
                                               const float* __restrict__ clfb,
                                               const u32* __restrict__ sc,
                                               float* __restrict__ out) {
  int c = blockIdx.x, b = blockIdx.y, lane = threadIdx.x;
  float sp = read_max16(sc, SLOT_POOL) / 127.0f + 1e-8f;
  float acc = 0.f;
#pragma unroll
  for (int j = 0; j < 3; ++j) {
    int d = lane + 64 * j;
    acc += fqs(pooled[(long)b * 192 + d], sp) * clfq[c * 192 + d];
  }
#pragma unroll
  for (int o = 32; o > 0; o >>= 1) acc += __shfl_down(acc, o);
  if (lane == 0) out[b * 7 + c] = acc + clfb[c];
}

// ---------------------------------------------------------------------------
// host
// ---------------------------------------------------------------------------
static inline int gsz(long n4, long cap) {
  long g = (n4 + 255) / 256;
  return (int)(g < cap ? g : cap);
}

extern "C" void kernel_launch(void* const* d_in, const int* in_sizes, int n_in,
                              void* d_out, int out_size, void* d_ws, size_t ws_size,
                              hipStream_t stream) {
  (void)in_sizes; (void)n_in; (void)out_size; (void)ws_size;

  const float* x = (const float*)d_in[0];
  const float* pw = (const float*)d_in[1];
  const float* pb = (const float*)d_in[2];
  const float* ln1g = (const float*)d_in[3];
  const float* ln1b = (const float*)d_in[4];
  const float* wqkv = (const float*)d_in[5];
  const float* bqkv = (const float*)d_in[6];
  const float* wo = (const float*)d_in[7];
  const float* bo = (const float*)d_in[8];
  const float* ln2g = (const float*)d_in[9];
  const float* ln2b = (const float*)d_in[10];
  const float* w1 = (const float*)d_in[11];
  const float* b1 = (const float*)d_in[12];
  const float* w2 = (const float*)d_in[13];
  const float* b2 = (const float*)d_in[14];
  const float* lnfg = (const float*)d_in[15];
  const float* lnfb = (const float*)d_in[16];
  const float* clfw = (const float*)d_in[17];
  const float* clfb = (const float*)d_in[18];

  float* ws = (float*)d_ws;
  u32* sc = (u32*)d_ws;
  float* GM = ws + OFF_GM;
  int* GMI = (int*)GM;
  float* GL = ws + OFF_GL;
  float* POOL = ws + OFF_POOL;
  float* PWQ = ws + OFF_PWQ;
  float* CLFQ = ws + OFF_CLFQ;
  float* H = ws + OFF_H;
  float* Af = ws + OFF_A;
  signed char* AH8 = (signed char*)(ws + OFF_A);
  signed char* AL8 = AH8 + 19660800;
  float* SAROW = (float*)(AH8 + 2 * 19660800);
  signed char* U8 = (signed char*)(ws + OFF_U);
  signed char* VT8 = U8 + 58982400;
  int* COLSUM = (int*)POOL;
  signed char* WQC = (signed char*)POOL;
  signed char* WOC2 = (signed char*)POOL;          // 36,864 B (wo)
  signed char* W1C2 = (signed char*)POOL + 36864;  // 147,456 B (w1; w2 reuses)
  signed char* W2C2 = (signed char*)POOL + 36864;
  float* out = (float*)d_out;

  k_zero<<<(N_SLOT_WORDS + 255) / 256, 256, 0, stream>>>(sc, N_SLOT_WORDS);

  auto amax = [&](const float* p, long n, int slot) {
    k_absmax<<<gsz(n / 4, 256), 256, 0, stream>>>((const float4*)p, n / 4, sc + slot * 16);
  };
  amax(pw, 3840, SLOT_PW);
  amax(clfw, 1344, SLOT_CLF);
  amax(x, 2048000, SLOT_X);
  for (int i = 0; i < NL; ++i) {
    int Lb = 16 + i * 16;
    amax(wqkv + (long)i * 110592, 110592, Lb + 0);
    amax(wo + (long)i * 36864, 36864, Lb + 1);
    amax(w1 + (long)i * 147456, 147456, Lb + 2);
    amax(w2 + (long)i * 147456, 147456, Lb + 3);
  }
  k_quant4<<<gsz(960, 256), 256, 0, stream>>>((const float4*)pw, (float4*)PWQ, 960, sc, SLOT_PW);
  k_quant4<<<gsz(336, 256), 256, 0, stream>>>((const float4*)clfw, (float4*)CLFQ, 336, sc,
                                              SLOT_CLF);

  // patch embed -> Af -> quant into H; first LN -> i16 planes
  k_patch<<<12800, 192, 0, stream>>>(x, PWQ, pb, sc, Af, sc + SLOT_EMB * 16);
  k_quant4<<<2048, 256, 0, stream>>>((const float4*)Af, (float4*)H, 19660800 / 4, sc, SLOT_EMB);
  k_ln<true><<<(int)(ROWS / 4), 256, 0, stream>>>(H, ln1g, ln1b, AH8, AL8, SAROW, nullptr,
                                                  (int)ROWS);

  for (int i = 0; i < NL; ++i) {
    int Lb = 16 + i * 16;
    // --- attention ---
    k_wquant<<<108, 256, 0, stream>>>((const float4*)(wqkv + (long)i * 110592), (u32*)WQC,
                                      27648, sc, Lb + 0);
    k_gemm16<false, 1><<<2400, 256, 0, stream>>>(AH8, AL8, SAROW, WQC, Lb + 0, bqkv + i * 576,
                                                 nullptr, 576, 3, sc, Lb + 4, 192);
    k_gemm16<false, 2><<<2400, 256, 0, stream>>>(AH8, AL8, SAROW, WQC, Lb + 0, bqkv + i * 576,
                                                 U8, 576, 3, sc, Lb + 4, 192);
    k_vt<<<768, 256, 0, stream>>>(U8, VT8, COLSUM);
    k_attn0<<<5376, 256, 0, stream>>>(U8, GMI, sc, Lb + 4, Lb + 7);
    k_attn1<<<5376, 256, 0, stream>>>(U8, GM, GL, GMI, sc, Lb + 4, Lb + 7, Lb + 8);
    k_attn_pv<<<5376, 256, 0, stream>>>(U8, VT8, COLSUM, Af, GM, GL, sc, Lb + 4, Lb + 7,
                                        Lb + 8, Lb + 9);
    // ctx fp32 (Af) -> int8 codes (U8 head); wo codes into POOL
    k_quant_codes<<<2048, 256, 0, stream>>>((const float4*)Af, (u32*)U8, 19660800 / 4, sc,
                                            Lb + 9);
    k_wquant<<<36, 256, 0, stream>>>((const float4*)(wo + (long)i * 36864), (u32*)WOC2, 9216,
                                     sc, Lb + 1);
    {
      dim3 g(1, 800);
      k_gemm8<1><<<g, 256, 0, stream>>>(U8, Lb + 9, WOC2, Lb + 1, bo + i * 192, nullptr, 192,
                                        192, sc, Lb + 10);
      k_gemm8<3><<<g, 256, 0, stream>>>(U8, Lb + 9, WOC2, Lb + 1, bo + i * 192, H, 192, 192,
                                        sc, Lb + 10);
    }
    // LN2 -> i16 planes
    k_ln<true><<<(int)(ROWS / 4), 256, 0, stream>>>(H, ln2g + i * 192, ln2b + i * 192, AH8,
                                                    AL8, SAROW, nullptr, (int)ROWS);
    // --- MLP ---
    k_wquant<<<144, 256, 0, stream>>>((const float4*)(w1 + (long)i * 147456), (u32*)W1C2,
                                      36864, sc, Lb + 2);
    k_gemm16<true, 1><<<3200, 256, 0, stream>>>(AH8, AL8, SAROW, W1C2, Lb + 2, b1 + i * 768,
                                                nullptr, 768, 4, sc, Lb + 11, 768);
    k_gemm16<true, 2><<<3200, 256, 0, stream>>>(AH8, AL8, SAROW, W1C2, Lb + 2, b1 + i * 768,
                                                U8, 768, 4, sc, Lb + 11, 768);
    k_wquant<<<144, 256, 0, stream>>>((const float4*)(w2 + (long)i * 147456), (u32*)W2C2,
                                      36864, sc, Lb + 3);
    {
      dim3 g(1, 800);
      k_gemm8<1><<<g, 256, 0, stream>>>(U8, Lb + 11, W2C2, Lb + 3, b2 + i * 192, nullptr, 192,
                                        768, sc, Lb + 12);
      k_gemm8<3><<<g, 256, 0, stream>>>(U8, Lb + 11, W2C2, Lb + 3, b2 + i * 192, H, 192, 768,
                                        sc, Lb + 12);
    }
    if (i < NL - 1) {
      k_ln<true><<<(int)(ROWS / 4), 256, 0, stream>>>(H, ln1g + (i + 1) * 192,
                                                      ln1b + (i + 1) * 192, AH8, AL8, SAROW,
                                                      nullptr, (int)ROWS);
    } else {
      k_ln<false><<<(int)(ROWS / 4), 256, 0, stream>>>(H, lnfg, lnfb, nullptr, nullptr,
                                                       nullptr, Af, (int)ROWS);
    }
  }

  // pool + classifier
  k_pool<<<256, 192, 0, stream>>>(Af, POOL, sc + SLOT_POOL * 16);
  {
    dim3 g(7, 256);
    k_logits<<<g, 64, 0, stream>>>(POOL, CLFQ, clfb, sc, out);
  }
}

// Round 15
// 6389.570 us; speedup vs baseline: 1.2794x; 1.0954x over previous
//
#include <hip/hip_runtime.h>
#include <math.h>

// ---------------------------------------------------------------------------
// TinyMyo 8ch/400tok quant transformer — v15: v14 + single-pass gemm8
// (OM0: store fp32 val to Af + absmax) + elementwise resadd (H += fq(Af)).
// Removes one full GEMM recompute per wo/w2 per layer.
// ---------------------------------------------------------------------------

typedef unsigned int u32;
typedef unsigned short u16;
typedef __attribute__((ext_vector_type(4))) int int4v;

#define MFMA_I8(a, b, c) __builtin_amdgcn_mfma_i32_16x16x64_i8((a), (b), (c), 0, 0, 0)

constexpr int NL = 8;
constexpr long ROWS = 102400;  // B*SEQ
constexpr float LOG2E = 1.44269504088896340736f;

// ---- scale slots ----
constexpr int SLOT_X = 0, SLOT_PW = 1, SLOT_EMB = 2, SLOT_CLF = 3, SLOT_POOL = 4;
constexpr int N_SLOT_WORDS = 200 * 16;

// ---- ws layout (float units) ----
constexpr long OFF_GM = 3200;
constexpr long OFF_GL = OFF_GM + 307200;
constexpr long OFF_POOL = OFF_GL + 307200;
constexpr long OFF_PWQ = OFF_POOL + 49152;
constexpr long OFF_CLFQ = OFF_PWQ + 3840;
constexpr long OFF_H = OFF_CLFQ + 1344;
constexpr long OFF_A = OFF_H + 19660800;
constexpr long OFF_U = OFF_A + 19660800;

// ---------------------------------------------------------------------------
// helpers
// ---------------------------------------------------------------------------
__device__ __forceinline__ float warpMax(float v) {
#pragma unroll
  for (int o = 32; o > 0; o >>= 1) v = fmaxf(v, __shfl_down(v, o));
  return v;
}

__device__ __forceinline__ float read_max16(const u32* sc, int slot) {
  const u32* p = sc + slot * 16;
  u32 m = 0;
#pragma unroll
  for (int i = 0; i < 16; ++i) m = max(m, p[i]);
  return __uint_as_float(m);
}

__device__ __forceinline__ float fqs(float x, float s) {
  return fminf(fmaxf(rintf(x / s), -128.0f), 127.0f) * s;
}

// ---------------------------------------------------------------------------
// small utility kernels
// ---------------------------------------------------------------------------
__global__ void k_zero(u32* p, int n) {
  int i = blockIdx.x * blockDim.x + threadIdx.x;
  if (i < n) p[i] = 0u;
}

__global__ __launch_bounds__(256) void k_absmax(const float4* __restrict__ x, long n4,
                                                u32* __restrict__ slot) {
  float m = 0.f;
  for (long i = (long)blockIdx.x * blockDim.x + threadIdx.x; i < n4;
       i += (long)gridDim.x * blockDim.x) {
    float4 v = x[i];
    m = fmaxf(m, fmaxf(fmaxf(fabsf(v.x), fabsf(v.y)), fmaxf(fabsf(v.z), fabsf(v.w))));
  }
  __shared__ float red[4];
  m = warpMax(m);
  int lane = threadIdx.x & 63, w = threadIdx.x >> 6;
  if (lane == 0) red[w] = m;
  __syncthreads();
  if (threadIdx.x == 0) {
    float r = fmaxf(fmaxf(red[0], red[1]), fmaxf(red[2], red[3]));
    atomicMax(slot + (blockIdx.x & 15), __float_as_uint(r));
  }
}

__global__ __launch_bounds__(256) void k_quant4(const float4* __restrict__ in,
                                                float4* __restrict__ out, long n4,
                                                const u32* __restrict__ sc, int slot) {
  float s = read_max16(sc, slot) / 127.0f + 1e-8f;
  for (long i = (long)blockIdx.x * blockDim.x + threadIdx.x; i < n4;
       i += (long)gridDim.x * blockDim.x) {
    float4 v = in[i];
    v.x = fqs(v.x, s); v.y = fqs(v.y, s); v.z = fqs(v.z, s); v.w = fqs(v.w, s);
    out[i] = v;
  }
}

// H += fq(raw) elementwise (scale from slot)
__global__ __launch_bounds__(256) void k_resadd4(float4* __restrict__ h,
                                                 const float4* __restrict__ raw, long n4,
                                                 const u32* __restrict__ sc, int slot) {
  float s = read_max16(sc, slot) / 127.0f + 1e-8f;
  for (long i = (long)blockIdx.x * blockDim.x + threadIdx.x; i < n4;
       i += (long)gridDim.x * blockDim.x) {
    float4 r = raw[i];
    float4 v = h[i];
    v.x += fqs(r.x, s); v.y += fqs(r.y, s); v.z += fqs(r.z, s); v.w += fqs(r.w, s);
    h[i] = v;
  }
}

__global__ __launch_bounds__(256) void k_quant_codes(const float4* __restrict__ in,
                                                     u32* __restrict__ out, long n4,
                                                     const u32* __restrict__ sc, int slot) {
  float s = read_max16(sc, slot) / 127.0f + 1e-8f;
  for (long i = (long)blockIdx.x * blockDim.x + threadIdx.x; i < n4;
       i += (long)gridDim.x * blockDim.x) {
    float4 v = in[i];
    int c0 = (int)fminf(fmaxf(rintf(v.x / s), -128.f), 127.f);
    int c1 = (int)fminf(fmaxf(rintf(v.y / s), -128.f), 127.f);
    int c2 = (int)fminf(fmaxf(rintf(v.z / s), -128.f), 127.f);
    int c3 = (int)fminf(fmaxf(rintf(v.w / s), -128.f), 127.f);
    out[i] = (u32)(c0 & 0xff) | ((u32)(c1 & 0xff) << 8) | ((u32)(c2 & 0xff) << 16) |
             ((u32)(c3 & 0xff) << 24);
  }
}

// ---------------------------------------------------------------------------
// patch embed
// ---------------------------------------------------------------------------
__global__ __launch_bounds__(192) void k_patch(const float* __restrict__ x,
                                               const float* __restrict__ pwq,
                                               const float* __restrict__ pb,
                                               const u32* __restrict__ sc,
                                               float* __restrict__ emb,
                                               u32* __restrict__ embSlot) {
  __shared__ float xq[8][20];
  __shared__ float red[3];
  const int tid = threadIdx.x;
  const long rowBase = (long)blockIdx.x * 8;
  const float sx = read_max16(sc, SLOT_X) / 127.0f + 1e-8f;
  if (tid < 160) {
    int r = tid / 20, k = tid % 20;
    xq[r][k] = fqs(x[(rowBase + r) * 20 + k], sx);
  }
  __syncthreads();
  float wreg[20];
#pragma unroll
  for (int k = 0; k < 20; ++k) wreg[k] = pwq[tid * 20 + k];
  const float bias = pb[tid];
  float m = 0.f;
  for (int r = 0; r < 8; ++r) {
    float acc = bias;
#pragma unroll
    for (int k = 0; k < 20; ++k) acc += xq[r][k] * wreg[k];
    emb[(rowBase + r) * 192 + tid] = acc;
    m = fmaxf(m, fabsf(acc));
  }
  m = warpMax(m);
  if ((tid & 63) == 0) red[tid >> 6] = m;
  __syncthreads();
  if (tid == 0)
    atomicMax(embSlot + (blockIdx.x & 15),
              __float_as_uint(fmaxf(fmaxf(red[0], red[1]), red[2])));
}

// ---------------------------------------------------------------------------
// LayerNorm (reads only H), vectorized: lane<48 owns 4 consecutive elements.
// I16: hi/lo i8 planes (packed u32 stores) + per-row scale; else fp32.
// ---------------------------------------------------------------------------
template <bool I16>
__global__ __launch_bounds__(256) void k_ln(const float* __restrict__ x,
                                            const float* __restrict__ g,
                                            const float* __restrict__ bta,
                                            signed char* __restrict__ yh,
                                            signed char* __restrict__ yl,
                                            float* __restrict__ sArow,
                                            float* __restrict__ yf, int rows) {
  int w = threadIdx.x >> 6, lane = threadIdx.x & 63;
  long row = (long)blockIdx.x * 4 + w;
  if (row >= rows) return;
  const bool act = lane < 48;
  float4 v = make_float4(0.f, 0.f, 0.f, 0.f);
  if (act) v = ((const float4*)(x + row * 192))[lane];
  float s = v.x + v.y + v.z + v.w;
#pragma unroll
  for (int o = 32; o > 0; o >>= 1) s += __shfl_down(s, o);
  s = __shfl(s, 0);
  float mean = s / 192.0f;
  float d0 = v.x - mean, d1 = v.y - mean, d2 = v.z - mean, d3 = v.w - mean;
  float q = act ? (d0 * d0 + d1 * d1 + d2 * d2 + d3 * d3) : 0.f;
#pragma unroll
  for (int o = 32; o > 0; o >>= 1) q += __shfl_down(q, o);
  q = __shfl(q, 0);
  float rs = 1.0f / sqrtf(q / 192.0f + 1e-5f);
  float4 gv = make_float4(0.f, 0.f, 0.f, 0.f), bv = gv;
  if (act) {
    gv = ((const float4*)g)[lane];
    bv = ((const float4*)bta)[lane];
  }
  float o0 = d0 * rs * gv.x + bv.x;
  float o1 = d1 * rs * gv.y + bv.y;
  float o2 = d2 * rs * gv.z + bv.z;
  float o3 = d3 * rs * gv.w + bv.w;
  if (I16) {
    float rm = act ? fmaxf(fmaxf(fabsf(o0), fabsf(o1)), fmaxf(fabsf(o2), fabsf(o3))) : 0.f;
#pragma unroll
    for (int o = 32; o > 0; o >>= 1) rm = fmaxf(rm, __shfl_down(rm, o));
    rm = __shfl(rm, 0);
    float sA = rm / 32512.0f + 1e-20f;
    float inv = 1.0f / sA;
    if (act) {
      int c0 = (int)rintf(o0 * inv), c1 = (int)rintf(o1 * inv);
      int c2 = (int)rintf(o2 * inv), c3 = (int)rintf(o3 * inv);
      int h0 = (c0 + 128) >> 8, h1 = (c1 + 128) >> 8;
      int h2 = (c2 + 128) >> 8, h3 = (c3 + 128) >> 8;
      int l0 = c0 - (h0 << 8), l1 = c1 - (h1 << 8);
      int l2 = c2 - (h2 << 8), l3 = c3 - (h3 << 8);
      u32 hw = (u32)(h0 & 0xff) | ((u32)(h1 & 0xff) << 8) | ((u32)(h2 & 0xff) << 16) |
               ((u32)(h3 & 0xff) << 24);
      u32 lw = (u32)(l0 & 0xff) | ((u32)(l1 & 0xff) << 8) | ((u32)(l2 & 0xff) << 16) |
               ((u32)(l3 & 0xff) << 24);
      ((u32*)yh)[row * 48 + lane] = hw;
      ((u32*)yl)[row * 48 + lane] = lw;
    }
    if (lane == 0) sArow[row] = sA;
  } else {
    if (act) ((float4*)(yf + row * 192))[lane] = make_float4(o0, o1, o2, o3);
  }
}

// ---------------------------------------------------------------------------
// weight fp32 -> int8 codes
// ---------------------------------------------------------------------------
__global__ __launch_bounds__(256) void k_wquant(const float4* __restrict__ w,
                                                u32* __restrict__ out, int n4,
                                                const u32* __restrict__ sc, int slot) {
  int i = blockIdx.x * blockDim.x + threadIdx.x;
  if (i >= n4) return;
  float s = read_max16(sc, slot) / 127.0f + 1e-8f;
  float4 v = w[i];
  int c0 = (int)fminf(fmaxf(rintf(v.x / s), -128.f), 127.f);
  int c1 = (int)fminf(fmaxf(rintf(v.y / s), -128.f), 127.f);
  int c2 = (int)fminf(fmaxf(rintf(v.z / s), -128.f), 127.f);
  int c3 = (int)fminf(fmaxf(rintf(v.w / s), -128.f), 127.f);
  out[i] = (u32)(c0 & 0xff) | ((u32)(c1 & 0xff) << 8) | ((u32)(c2 & 0xff) << 16) |
           ((u32)(c3 & 0xff) << 24);
}

// ---------------------------------------------------------------------------
// i16-A x i8-W GEMM. B panel staged ONCE into LDS (padded stride 208);
// row loop NOT unrolled (unroll 1) to keep VGPR low and occupancy high.
// Block = 4 waves, same 128 rows, wave w owns cols [colBase+48w, +48).
// C = sArow*sW*(256*(AH·W)+AL·W)+bias [,gelu].
// OM 1: absmax only; OM 2: int8 code store.
// ---------------------------------------------------------------------------
template <bool GELU, int OM>
__global__ __launch_bounds__(256) void k_gemm16(
    const signed char* __restrict__ AH, const signed char* __restrict__ AL,
    const float* __restrict__ sArow, const signed char* __restrict__ W8, int slotW,
    const float* __restrict__ bias, signed char* __restrict__ C8, int N, int ncol,
    u32* __restrict__ sc, int slotO, int colsPerSlot) {
  __shared__ __align__(16) signed char Bs[192 * 208];
  __shared__ float red[4];
  const int tid = threadIdx.x;
  const int bid = blockIdx.x;
  const int vid = (bid & 7) * ((int)gridDim.x >> 3) + (bid >> 3);
  const int bx = vid % ncol;
  const long by = vid / ncol;
  const long rowBase = by * 128;
  const int colBase = bx * 192;
  const float sW = read_max16(sc, slotW) / 127.0f + 1e-8f;

  {
    const signed char* wp = W8 + (long)colBase * 192;
#pragma unroll
    for (int it = 0; it < 9; ++it) {
      int idx = it * 256 + tid;
      int row = idx / 12, c = idx % 12;
      int4 v = *(const int4*)(wp + (long)row * 192 + c * 16);
      *(int4*)&Bs[row * 208 + c * 16] = v;
    }
  }

  const int lane = tid & 63, w = tid >> 6;
  const int fr = lane & 15, fk = lane >> 4;
  const int wc0 = w * 48;

  float sOinv = 0.f;
  if (OM == 2) sOinv = 1.0f / (read_max16(sc, slotO + colBase / colsPerSlot) / 127.0f + 1e-8f);
  const float inv_sqrt2 = 0.70710678118654752440f;
  float vmax = 0.f;

  const long abase = (rowBase + fr) * 192 + fk * 16;
  __syncthreads();

#pragma unroll 1
  for (int it = 0; it < 8; ++it) {
    const long ab = abase + (long)it * 16 * 192;
    int4v ahc[3], alc[3];
#pragma unroll
    for (int kk = 0; kk < 3; ++kk) {
      ahc[kk] = *(const int4v*)(AH + ab + kk * 64);
      alc[kk] = *(const int4v*)(AL + ab + kk * 64);
    }
    int4v aH[3], aL[3];
#pragma unroll
    for (int n = 0; n < 3; ++n) {
      aH[n] = (int4v){0, 0, 0, 0};
      aL[n] = (int4v){0, 0, 0, 0};
    }
#pragma unroll
    for (int kk = 0; kk < 3; ++kk) {
#pragma unroll
      for (int n = 0; n < 3; ++n) {
        int4v bfr = *(const int4v*)&Bs[(wc0 + n * 16 + fr) * 208 + kk * 64 + fk * 16];
        aH[n] = MFMA_I8(ahc[kk], bfr, aH[n]);
        aL[n] = MFMA_I8(alc[kk], bfr, aL[n]);
      }
    }
    const long rt = rowBase + it * 16;
    float4 sA4 = *(const float4*)&sArow[rt + fk * 4];
    float sAr[4] = {sA4.x, sA4.y, sA4.z, sA4.w};
#pragma unroll
    for (int n = 0; n < 3; ++n) {
      const int col = colBase + wc0 + n * 16 + fr;
      const float bb = bias[col];
#pragma unroll
      for (int r = 0; r < 4; ++r) {
        const int R = (aH[n][r] << 8) + aL[n][r];
        float val = (float)R * (sAr[r] * sW) + bb;
        if (GELU) val = 0.5f * val * (1.0f + erff(val * inv_sqrt2));
        if (OM == 2) {
          float code = fminf(fmaxf(rintf(val * sOinv), -128.f), 127.f);
          C8[(rt + fk * 4 + r) * N + col] = (signed char)code;
        } else {
          vmax = fmaxf(vmax, fabsf(val));
        }
      }
    }
  }

  if (OM == 1) {
    float m = warpMax(vmax);
    if ((tid & 63) == 0) red[tid >> 6] = m;
    __syncthreads();
    if (tid == 0) {
      float r = fmaxf(fmaxf(red[0], red[1]), fmaxf(red[2], red[3]));
      atomicMax(sc + (slotO + colBase / colsPerSlot) * 16 + ((int)(bx + by) & 15),
                __float_as_uint(r));
    }
  }
}

// ---------------------------------------------------------------------------
// i8-MFMA GEMM (A = int8 codes), LDS-free. OM 0: store fp32 val + absmax.
// BM=128 BN=192.
// ---------------------------------------------------------------------------
template <int OM>
__global__ __launch_bounds__(256) void k_gemm8(
    const signed char* __restrict__ A8, int slotA, const signed char* __restrict__ W8,
    int slotW, const float* __restrict__ bias, float* __restrict__ C, int N, int K,
    u32* __restrict__ sc, int slotO) {
  __shared__ float red[4];
  const int tid = threadIdx.x;
  const long rowBase = (long)blockIdx.y * 128;
  const int colBase = blockIdx.x * 192;
  const float alpha = (read_max16(sc, slotA) / 127.0f + 1e-8f) *
                      (read_max16(sc, slotW) / 127.0f + 1e-8f);

  const int lane = tid & 63, wv = tid >> 6;
  const int wm = wv >> 1, wn = wv & 1;
  const int fr = lane & 15, fk = lane >> 4;

  int4v acc[4][6];
#pragma unroll
  for (int m = 0; m < 4; ++m)
#pragma unroll
    for (int n = 0; n < 6; ++n) acc[m][n] = (int4v){0, 0, 0, 0};

  const long arow0 = rowBase + wm * 64;
  const int bcol0 = colBase + wn * 96;

  for (int k0 = 0; k0 < K; k0 += 64) {
    const int ko = k0 + fk * 16;
    int4v bfr[6];
#pragma unroll
    for (int n = 0; n < 6; ++n)
      bfr[n] = *(const int4v*)(W8 + (long)(bcol0 + n * 16 + fr) * K + ko);
#pragma unroll
    for (int m = 0; m < 4; ++m) {
      int4v af = *(const int4v*)(A8 + (arow0 + m * 16 + fr) * (long)K + ko);
#pragma unroll
      for (int n = 0; n < 6; ++n) acc[m][n] = MFMA_I8(af, bfr[n], acc[m][n]);
    }
  }

  float vmax = 0.f;
#pragma unroll
  for (int n = 0; n < 6; ++n) {
    const int col = colBase + wn * 96 + n * 16 + fr;
    const float bb = bias[col];
#pragma unroll
    for (int m = 0; m < 4; ++m) {
#pragma unroll
      for (int r = 0; r < 4; ++r) {
        const long row = rowBase + wm * 64 + m * 16 + fk * 4 + r;
        float val = (float)acc[m][n][r] * alpha + bb;
        C[row * N + col] = val;
        vmax = fmaxf(vmax, fabsf(val));
      }
    }
  }
  {
    float m = warpMax(vmax);
    if ((tid & 63) == 0) red[tid >> 6] = m;
    __syncthreads();
    if (tid == 0) {
      float r = fmaxf(fmaxf(red[0], red[1]), fmaxf(red[2], red[3]));
      atomicMax(sc + slotO * 16 + ((blockIdx.x + blockIdx.y) & 15), __float_as_uint(r));
    }
  }
}

// ---------------------------------------------------------------------------
// k_vt: per (b,h), transpose V codes [400][64] -> VT8[bh][64][400] + colsumV.
// ---------------------------------------------------------------------------
__global__ __launch_bounds__(256) void k_vt(const signed char* __restrict__ qkv8,
                                            signed char* __restrict__ vt8,
                                            int* __restrict__ colsum) {
  __shared__ __align__(16) signed char T[64 * 80];
  __shared__ int cs[64];
  const int tid = threadIdx.x;
  const int bh = blockIdx.x, b = bh / 3, hh = bh % 3;
  const signed char* vb = qkv8 + (long)b * 400 * 576 + hh * 64 + 384;
  if (tid < 64) cs[tid] = 0;
  const int d = tid >> 2, seg = tid & 3;
  for (int c0 = 0; c0 < 448; c0 += 64) {
    __syncthreads();
    {
      int trow = tid >> 2, c = tid & 3;
      int4 v = make_int4(0, 0, 0, 0);
      if (c0 + trow < 400) v = *(const int4*)(vb + (long)(c0 + trow) * 576 + c * 16);
      *(int4*)&T[trow * 80 + c * 16] = v;
    }
    __syncthreads();
    int4 outw;
    int ssum = 0;
    u32 pk[4];
#pragma unroll
    for (int j = 0; j < 4; ++j) {
      u32 p = 0;
#pragma unroll
      for (int e = 0; e < 4; ++e) {
        int t = seg * 16 + j * 4 + e;
        int v = (int)T[t * 80 + d];
        ssum += v;
        p |= ((u32)(v & 0xff)) << (8 * e);
      }
      pk[j] = p;
    }
    outw.x = (int)pk[0]; outw.y = (int)pk[1]; outw.z = (int)pk[2]; outw.w = (int)pk[3];
    if (c0 + seg * 16 < 400)
      *(int4*)&vt8[(long)bh * 25600 + d * 400 + c0 + seg * 16] = outw;
    atomicAdd(&cs[d], ssum);
  }
  __syncthreads();
  if (tid < 64) colsum[bh * 64 + tid] = cs[tid];
}

// ---------------------------------------------------------------------------
// Attention, i8 MFMA, transposed scores, LDS-free (except P exchange in pv).
// 1D grid 5376, XCD-chunked: bh = vid/7, tile = vid%7.
// ---------------------------------------------------------------------------
__device__ __forceinline__ void attn_swz(int& tile, int& bh) {
  int bid = blockIdx.x;
  int vid = (bid & 7) * ((int)gridDim.x >> 3) + (bid >> 3);
  tile = vid % 7;
  bh = vid / 7;
}

__global__ __launch_bounds__(256) void k_attn0(const signed char* __restrict__ qkv8,
                                               int* __restrict__ gmInt, u32* __restrict__ sc,
                                               int slotQ, int slotSc) {
  __shared__ float red[4];
  const int tid = threadIdx.x;
  int tile, bh;
  attn_swz(tile, bh);
  const int r0 = tile * 64;
  const int b = bh / 3, hh = bh % 3;
  const signed char* qb = qkv8 + (long)b * 400 * 576 + hh * 64;
  const signed char* kb = qb + 192;
  const float sQ = read_max16(sc, slotQ) / 127.0f + 1e-8f;
  const float sK = read_max16(sc, slotQ + 1) / 127.0f + 1e-8f;
  const float sSc = sQ * sK * 0.125f;

  const int lane = tid & 63, w = tid >> 6, fr = lane & 15, fk = lane >> 4;
  const int qloc = 16 * w + fr;
  const int gq = r0 + qloc;
  const bool qv = gq < 400;
  int4v qf = *(const int4v*)(qb + (long)(r0 + qloc) * 576 + fk * 16);

  int aim = 0;
  int rim = -(1 << 30);
  for (int c0 = 0; c0 < 400; c0 += 128) {
#pragma unroll
    for (int tf = 0; tf < 8; ++tf) {
      int4v kf = *(const int4v*)(kb + (long)(c0 + tf * 16 + fr) * 576 + fk * 16);
      int4v s = MFMA_I8(kf, qf, ((int4v){0, 0, 0, 0}));
      const bool tv = (c0 + tf * 16 + fk * 4) < 400;
      if (tv && qv) {
#pragma unroll
        for (int r = 0; r < 4; ++r) {
          int sv = s[r];
          aim = max(aim, max(sv, -sv));
          rim = max(rim, sv);
        }
      }
    }
  }
  rim = max(rim, __shfl_xor(rim, 16));
  rim = max(rim, __shfl_xor(rim, 32));
  if (fk == 0 && qv) gmInt[(long)bh * 400 + gq] = rim;
  float m = warpMax((float)aim * sSc);
  if (lane == 0) red[w] = m;
  __syncthreads();
  if (tid == 0) {
    float r = fmaxf(fmaxf(red[0], red[1]), fmaxf(red[2], red[3]));
    atomicMax(sc + slotSc * 16 + (blockIdx.x & 15), __float_as_uint(r));
  }
}

__global__ __launch_bounds__(256) void k_attn1(const signed char* __restrict__ qkv8,
                                               float* __restrict__ gm, float* __restrict__ gl,
                                               const int* __restrict__ gmInt,
                                               u32* __restrict__ sc, int slotQ, int slotSc,
                                               int slotPr) {
  __shared__ float red[4];
  const int tid = threadIdx.x;
  int tile, bh;
  attn_swz(tile, bh);
  const int r0 = tile * 64;
  const int b = bh / 3, hh = bh % 3;
  const signed char* qb = qkv8 + (long)b * 400 * 576 + hh * 64;
  const signed char* kb = qb + 192;
  const float sQ = read_max16(sc, slotQ) / 127.0f + 1e-8f;
  const float sK = read_max16(sc, slotQ + 1) / 127.0f + 1e-8f;
  const float sSc = sQ * sK * 0.125f;
  const float sS = read_max16(sc, slotSc) / 127.0f + 1e-8f;
  const float c1 = sSc / sS;
  const float c2 = sS * LOG2E;

  const int lane = tid & 63, w = tid >> 6, fr = lane & 15, fk = lane >> 4;
  const int qloc = 16 * w + fr;
  const int gq = r0 + qloc;
  const int gqc = (gq > 399) ? 399 : gq;
  int4v qf = *(const int4v*)(qb + (long)(r0 + qloc) * 576 + fk * 16);

  const int mint = gmInt[(long)bh * 400 + gqc];
  const float cm = fminf(fmaxf(rintf((float)mint * c1), -128.f), 127.f);

  float sum = 0.f;
  for (int c0 = 0; c0 < 400; c0 += 128) {
#pragma unroll
    for (int tf = 0; tf < 8; ++tf) {
      int4v kf = *(const int4v*)(kb + (long)(c0 + tf * 16 + fr) * 576 + fk * 16);
      int4v s = MFMA_I8(kf, qf, ((int4v){0, 0, 0, 0}));
      if ((c0 + tf * 16 + fk * 4) < 400) {
#pragma unroll
        for (int r = 0; r < 4; ++r) {
          float cf = fminf(fmaxf(rintf((float)s[r] * c1), -128.f), 127.f);
          sum += exp2f((cf - cm) * c2);
        }
      }
    }
  }
  sum += __shfl_xor(sum, 16);
  sum += __shfl_xor(sum, 32);
  float cand = 0.f;
  if (fk == 0 && gq < 400) {
    gm[(long)bh * 400 + gq] = cm;
    gl[(long)bh * 400 + gq] = sum;
    cand = 1.0f / sum;
  }
  float m = warpMax(cand);
  if (lane == 0) red[w] = m;
  __syncthreads();
  if (tid == 0) {
    float r = fmaxf(fmaxf(red[0], red[1]), fmaxf(red[2], red[3]));
    atomicMax(sc + slotPr * 16 + (blockIdx.x & 15), __float_as_uint(r));
  }
}

__global__ __launch_bounds__(256) void k_attn_pv(
    const signed char* __restrict__ qkv8, const signed char* __restrict__ vt8,
    const int* __restrict__ colsumV, float* __restrict__ ctx, const float* __restrict__ gm,
    const float* __restrict__ gl, u32* __restrict__ sc, int slotQ, int slotSc, int slotPr,
    int slotCtx) {
  __shared__ __align__(16) signed char Ps[64 * 144];
  __shared__ int colsV[64];
  __shared__ float red[4];
  const int tid = threadIdx.x;
  int tile, bh;
  attn_swz(tile, bh);
  const int r0 = tile * 64;
  const int b = bh / 3, hh = bh % 3;
  const signed char* qb = qkv8 + (long)b * 400 * 576 + hh * 64;
  const signed char* kb = qb + 192;
  const signed char* vtb = vt8 + (long)bh * 25600;
  const float sQ = read_max16(sc, slotQ) / 127.0f + 1e-8f;
  const float sK = read_max16(sc, slotQ + 1) / 127.0f + 1e-8f;
  const float sV = read_max16(sc, slotQ + 2) / 127.0f + 1e-8f;
  const float sSc = sQ * sK * 0.125f;
  const float sS = read_max16(sc, slotSc) / 127.0f + 1e-8f;
  const float sP = read_max16(sc, slotPr) / 255.0f + 1e-8f;
  const float sPV = sP * sV;
  const float c1 = sSc / sS;
  const float c2 = sS * LOG2E;

  if (tid < 64) colsV[tid] = colsumV[bh * 64 + tid];
  const int lane = tid & 63, w = tid >> 6, fr = lane & 15, fk = lane >> 4;
  const int qloc = 16 * w + fr;
  int4v qf = *(const int4v*)(qb + (long)(r0 + qloc) * 576 + fk * 16);

  int gq = r0 + qloc;
  if (gq > 399) gq = 399;
  const float cm = gm[(long)bh * 400 + gq];
  const float invLsp = 1.0f / (gl[(long)bh * 400 + gq] * sP);

  int4v accd[4];
#pragma unroll
  for (int dt = 0; dt < 4; ++dt) accd[dt] = (int4v){0, 0, 0, 0};
  __syncthreads();  // colsV ready

  for (int c0 = 0; c0 < 400; c0 += 128) {
#pragma unroll
    for (int tf = 0; tf < 8; ++tf) {
      int4v kf = *(const int4v*)(kb + (long)(c0 + tf * 16 + fr) * 576 + fk * 16);
      int4v s = MFMA_I8(kf, qf, ((int4v){0, 0, 0, 0}));
      const int tbase = c0 + tf * 16 + fk * 4;
      u32 pack = 0;
      if (tbase < 400) {
#pragma unroll
        for (int r = 0; r < 4; ++r) {
          float cf = fminf(fmaxf(rintf((float)s[r] * c1), -128.f), 127.f);
          float e = exp2f((cf - cm) * c2);
          float pu = fminf(fmaxf(rintf(e * invLsp), 0.f), 255.f);
          int pc = (int)pu - 128;
          pack |= ((u32)(pc & 0xff)) << (8 * r);
        }
      }
      *(u32*)&Ps[qloc * 144 + tf * 16 + fk * 4] = pack;
    }
    __syncthreads();
    int4v pf0 = *(const int4v*)&Ps[qloc * 144 + fk * 16];
    int4v pf1 = *(const int4v*)&Ps[qloc * 144 + 64 + fk * 16];
    const bool v0ok = (c0 + fk * 16) < 400;
    const bool v1ok = (c0 + 64 + fk * 16) < 400;
#pragma unroll
    for (int dt = 0; dt < 4; ++dt) {
      const long vrow = (long)(dt * 16 + fr) * 400;
      int4v vf0 = v0ok ? *(const int4v*)(vtb + vrow + c0 + fk * 16) : (int4v){0, 0, 0, 0};
      int4v vf1 = v1ok ? *(const int4v*)(vtb + vrow + c0 + 64 + fk * 16) : (int4v){0, 0, 0, 0};
      accd[dt] = MFMA_I8(vf0, pf0, accd[dt]);
      accd[dt] = MFMA_I8(vf1, pf1, accd[dt]);
    }
    __syncthreads();
  }
  float vmax = 0.f;
  const int q = r0 + qloc;
  if (q < 400) {
#pragma unroll
    for (int dt = 0; dt < 4; ++dt) {
      const int d0 = dt * 16 + fk * 4;
      float4 o;
      o.x = sPV * (float)(accd[dt][0] + 128 * colsV[d0 + 0]);
      o.y = sPV * (float)(accd[dt][1] + 128 * colsV[d0 + 1]);
      o.z = sPV * (float)(accd[dt][2] + 128 * colsV[d0 + 2]);
      o.w = sPV * (float)(accd[dt][3] + 128 * colsV[d0 + 3]);
      vmax = fmaxf(vmax, fmaxf(fmaxf(fabsf(o.x), fabsf(o.y)), fmaxf(fabsf(o.z), fabsf(o.w))));
      *(float4*)&ctx[(long)(b * 400 + q) * 192 + hh * 64 + d0] = o;
    }
  }
  float m = warpMax(vmax);
  if (lane == 0) red[w] = m;
  __syncthreads();
  if (tid == 0) {
    float r = fmaxf(fmaxf(red[0], red[1]), fmaxf(red[2], red[3]));
    atomicMax(sc + slotCtx * 16 + (blockIdx.x & 15), __float_as_uint(r));
  }
}

// ---------------------------------------------------------------------------
// final pool + logits
// ---------------------------------------------------------------------------
__global__ __launch_bounds__(192) void k_pool(const float* __restrict__ xln,
                                              float* __restrict__ pooled,
                                              u32* __restrict__ slot) {
  int b = blockIdx.x, d = threadIdx.x;
  float sum = 0.f;
  for (int s = 0; s < 400; ++s) sum += xln[((long)b * 400 + s) * 192 + d];
  float v = sum / 400.0f;
  pooled[(long)b * 192 + d] = v;
  __shared__ float red[3];
  float m = warpMax(fabsf(v));
  if ((d & 63) == 0) red[d >> 6] = m;
  __syncthreads();
  if (d == 0)
    atomicMax(slot + (b & 15), __float_as_uint(fmaxf(fmaxf(red[0], red[1]), red[2])));
}

__global__ __launch_bounds__(64) void k_logits(const float* __restrict__ pooled,
                                               const float* __restrict__ clfq,
                                               const float* __restrict__ clfb,
                                               const u32* __restrict__ sc,
                                               float* __restrict__ out) {
  int c = blockIdx.x, b = blockIdx.y, lane = threadIdx.x;
  float sp = read_max16(sc, SLOT_POOL) / 127.0f + 1e-8f;
  float acc = 0.f;
#pragma unroll
  for (int j = 0; j < 3; ++j) {
    int d = lane + 64 * j;
    acc += fqs(pooled[(long)b * 192 + d], sp) * clfq[c * 192 + d];
  }
#pragma unroll
  for (int o = 32; o > 0; o >>= 1) acc += __shfl_down(acc, o);
  if (lane == 0) out[b * 7 + c] = acc + clfb[c];
}

// ---------------------------------------------------------------------------
// host
// ---------------------------------------------------------------------------
static inline int gsz(long n4, long cap) {
  long g = (n4 + 255) / 256;
  return (int)(g < cap ? g : cap);
}

extern "C" void kernel_launch(void* const* d_in, const int* in_sizes, int n_in,
                              void* d_out, int out_size, void* d_ws, size_t ws_size,
                              hipStream_t stream) {
  (void)in_sizes; (void)n_in; (void)out_size; (void)ws_size;

  const float* x = (const float*)d_in[0];
  const float* pw = (const float*)d_in[1];
  const float* pb = (const float*)d_in[2];
  const float* ln1g = (const float*)d_in[3];
  const float* ln1b = (const float*)d_in[4];
  const float* wqkv = (const float*)d_in[5];
  const float* bqkv = (const float*)d_in[6];
  const float* wo = (const float*)d_in[7];
  const float* bo = (const float*)d_in[8];
  const float* ln2g = (const float*)d_in[9];
  const float* ln2b = (const float*)d_in[10];
  const float* w1 = (const float*)d_in[11];
  const float* b1 = (const float*)d_in[12];
  const float* w2 = (const float*)d_in[13];
  const float* b2 = (const float*)d_in[14];
  const float* lnfg = (const float*)d_in[15];
  const float* lnfb = (const float*)d_in[16];
  const float* clfw = (const float*)d_in[17];
  const float* clfb = (const float*)d_in[18];

  float* ws = (float*)d_ws;
  u32* sc = (u32*)d_ws;
  float* GM = ws + OFF_GM;
  int* GMI = (int*)GM;
  float* GL = ws + OFF_GL;
  float* POOL = ws + OFF_POOL;
  float* PWQ = ws + OFF_PWQ;
  float* CLFQ = ws + OFF_CLFQ;
  float* H = ws + OFF_H;
  float* Af = ws + OFF_A;
  signed char* AH8 = (signed char*)(ws + OFF_A);
  signed char* AL8 = AH8 + 19660800;
  float* SAROW = (float*)(AH8 + 2 * 19660800);
  signed char* U8 = (signed char*)(ws + OFF_U);
  signed char* VT8 = U8 + 58982400;
  int* COLSUM = (int*)POOL;
  signed char* WQC = (signed char*)POOL;
  signed char* WOC2 = (signed char*)POOL;          // 36,864 B (wo)
  signed char* W1C2 = (signed char*)POOL + 36864;  // 147,456 B (w1; w2 reuses)
  signed char* W2C2 = (signed char*)POOL + 36864;
  float* out = (float*)d_out;

  k_zero<<<(N_SLOT_WORDS + 255) / 256, 256, 0, stream>>>(sc, N_SLOT_WORDS);

  auto amax = [&](const float* p, long n, int slot) {
    k_absmax<<<gsz(n / 4, 256), 256, 0, stream>>>((const float4*)p, n / 4, sc + slot * 16);
  };
  amax(pw, 3840, SLOT_PW);
  amax(clfw, 1344, SLOT_CLF);
  amax(x, 2048000, SLOT_X);
  for (int i = 0; i < NL; ++i) {
    int Lb = 16 + i * 16;
    amax(wqkv + (long)i * 110592, 110592, Lb + 0);
    amax(wo + (long)i * 36864, 36864, Lb + 1);
    amax(w1 + (long)i * 147456, 147456, Lb + 2);
    amax(w2 + (long)i * 147456, 147456, Lb + 3);
  }
  k_quant4<<<gsz(960, 256), 256, 0, stream>>>((const float4*)pw, (float4*)PWQ, 960, sc, SLOT_PW);
  k_quant4<<<gsz(336, 256), 256, 0, stream>>>((const float4*)clfw, (float4*)CLFQ, 336, sc,
                                              SLOT_CLF);

  // patch embed -> Af -> quant into H; first LN -> i16 planes
  k_patch<<<12800, 192, 0, stream>>>(x, PWQ, pb, sc, Af, sc + SLOT_EMB * 16);
  k_quant4<<<2048, 256, 0, stream>>>((const float4*)Af, (float4*)H, 19660800 / 4, sc, SLOT_EMB);
  k_ln<true><<<(int)(ROWS / 4), 256, 0, stream>>>(H, ln1g, ln1b, AH8, AL8, SAROW, nullptr,
                                                  (int)ROWS);

  for (int i = 0; i < NL; ++i) {
    int Lb = 16 + i * 16;
    // --- attention ---
    k_wquant<<<108, 256, 0, stream>>>((const float4*)(wqkv + (long)i * 110592), (u32*)WQC,
                                      27648, sc, Lb + 0);
    k_gemm16<false, 1><<<2400, 256, 0, stream>>>(AH8, AL8, SAROW, WQC, Lb + 0, bqkv + i * 576,
                                                 nullptr, 576, 3, sc, Lb + 4, 192);
    k_gemm16<false, 2><<<2400, 256, 0, stream>>>(AH8, AL8, SAROW, WQC, Lb + 0, bqkv + i * 576,
                                                 U8, 576, 3, sc, Lb + 4, 192);
    k_vt<<<768, 256, 0, stream>>>(U8, VT8, COLSUM);
    k_attn0<<<5376, 256, 0, stream>>>(U8, GMI, sc, Lb + 4, Lb + 7);
    k_attn1<<<5376, 256, 0, stream>>>(U8, GM, GL, GMI, sc, Lb + 4, Lb + 7, Lb + 8);
    k_attn_pv<<<5376, 256, 0, stream>>>(U8, VT8, COLSUM, Af, GM, GL, sc, Lb + 4, Lb + 7,
                                        Lb + 8, Lb + 9);
    // ctx fp32 (Af) -> int8 codes (U8 head); wo codes into POOL
    k_quant_codes<<<2048, 256, 0, stream>>>((const float4*)Af, (u32*)U8, 19660800 / 4, sc,
                                            Lb + 9);
    k_wquant<<<36, 256, 0, stream>>>((const float4*)(wo + (long)i * 36864), (u32*)WOC2, 9216,
                                     sc, Lb + 1);
    {
      // single pass: wo GEMM -> Af fp32 + absmax; then H += fq(Af)
      dim3 g(1, 800);
      k_gemm8<0><<<g, 256, 0, stream>>>(U8, Lb + 9, WOC2, Lb + 1, bo + i * 192, Af, 192, 192,
                                        sc, Lb + 10);
      k_resadd4<<<2048, 256, 0, stream>>>((float4*)H, (const float4*)Af, 19660800 / 4, sc,
                                          Lb + 10);
    }
    // LN2 -> i16 planes
    k_ln<true><<<(int)(ROWS / 4), 256, 0, stream>>>(H, ln2g + i * 192, ln2b + i * 192, AH8,
                                                    AL8, SAROW, nullptr, (int)ROWS);
    // --- MLP ---
    k_wquant<<<144, 256, 0, stream>>>((const float4*)(w1 + (long)i * 147456), (u32*)W1C2,
                                      36864, sc, Lb + 2);
    k_gemm16<true, 1><<<3200, 256, 0, stream>>>(AH8, AL8, SAROW, W1C2, Lb + 2, b1 + i * 768,
                                                nullptr, 768, 4, sc, Lb + 11, 768);
    k_gemm16<true, 2><<<3200, 256, 0, stream>>>(AH8, AL8, SAROW, W1C2, Lb + 2, b1 + i * 768,
                                                U8, 768, 4, sc, Lb + 11, 768);
    k_wquant<<<144, 256, 0, stream>>>((const float4*)(w2 + (long)i * 147456), (u32*)W2C2,
                                      36864, sc, Lb + 3);
    {
      // single pass: w2 GEMM -> Af fp32 + absmax; then H += fq(Af)
      dim3 g(1, 800);
      k_gemm8<0><<<g, 256, 0, stream>>>(U8, Lb + 11, W2C2, Lb + 3, b2 + i * 192, Af, 192, 768,
                                        sc, Lb + 12);
      k_resadd4<<<2048, 256, 0, stream>>>((float4*)H, (const float4*)Af, 19660800 / 4, sc,
                                          Lb + 12);
    }
    if (i < NL - 1) {
      k_ln<true><<<(int)(ROWS / 4), 256, 0, stream>>>(H, ln1g + (i + 1) * 192,
                                                      ln1b + (i + 1) * 192, AH8, AL8, SAROW,
                                                      nullptr, (int)ROWS);
    } else {
      k_ln<false><<<(int)(ROWS / 4), 256, 0, stream>>>(H, lnfg, lnfb, nullptr, nullptr,
                                                       nullptr, Af, (int)ROWS);
    }
  }

  // pool + classifier
  k_pool<<<256, 192, 0, stream>>>(Af, POOL, sc + SLOT_POOL * 16);
  {
    dim3 g(7, 256);
    k_logits<<<g, 64, 0, stream>>>(POOL, CLFQ, clfb, sc, out);
  }
}

// Round 16
// 6070.319 us; speedup vs baseline: 1.3467x; 1.0526x over previous
//
#include <hip/hip_runtime.h>
#include <math.h>

// ---------------------------------------------------------------------------
// TinyMyo 8ch/400tok quant transformer — v16: fused residual+LN via region
// ping-pong (planes and raw always in different regions -> no v3 race),
// LDS-staged k_patch. Numerics element-identical to v15.
// Region plan per layer (RA = old A region, RU = old U region):
//   planes(ln1) RU-head -> qkv codes RA[0..59M) + VT8 RA[59..78.6M)
//   ctx fp32 RU -> ctx codes RA-head -> wo fp32 RU
//   fused resLN2: raw=RU, planes2 -> RA-head
//   gelu codes RU -> w2 fp32 RA
//   fused resLN1'/final: raw=RA, planes -> RU-head (or final fp32 -> RU)
// ---------------------------------------------------------------------------

typedef unsigned int u32;
typedef unsigned short u16;
typedef __attribute__((ext_vector_type(4))) int int4v;

#define MFMA_I8(a, b, c) __builtin_amdgcn_mfma_i32_16x16x64_i8((a), (b), (c), 0, 0, 0)

constexpr int NL = 8;
constexpr long ROWS = 102400;  // B*SEQ
constexpr float LOG2E = 1.44269504088896340736f;

constexpr int SLOT_X = 0, SLOT_PW = 1, SLOT_EMB = 2, SLOT_CLF = 3, SLOT_POOL = 4;
constexpr int N_SLOT_WORDS = 200 * 16;

constexpr long OFF_GM = 3200;
constexpr long OFF_GL = OFF_GM + 307200;
constexpr long OFF_POOL = OFF_GL + 307200;
constexpr long OFF_PWQ = OFF_POOL + 49152;
constexpr long OFF_CLFQ = OFF_PWQ + 3840;
constexpr long OFF_H = OFF_CLFQ + 1344;
constexpr long OFF_A = OFF_H + 19660800;
constexpr long OFF_U = OFF_A + 19660800;

// ---------------------------------------------------------------------------
__device__ __forceinline__ float warpMax(float v) {
#pragma unroll
  for (int o = 32; o > 0; o >>= 1) v = fmaxf(v, __shfl_down(v, o));
  return v;
}

__device__ __forceinline__ float read_max16(const u32* sc, int slot) {
  const u32* p = sc + slot * 16;
  u32 m = 0;
#pragma unroll
  for (int i = 0; i < 16; ++i) m = max(m, p[i]);
  return __uint_as_float(m);
}

__device__ __forceinline__ float fqs(float x, float s) {
  return fminf(fmaxf(rintf(x / s), -128.0f), 127.0f) * s;
}

// ---------------------------------------------------------------------------
__global__ void k_zero(u32* p, int n) {
  int i = blockIdx.x * blockDim.x + threadIdx.x;
  if (i < n) p[i] = 0u;
}

__global__ __launch_bounds__(256) void k_absmax(const float4* __restrict__ x, long n4,
                                                u32* __restrict__ slot) {
  float m = 0.f;
  for (long i = (long)blockIdx.x * blockDim.x + threadIdx.x; i < n4;
       i += (long)gridDim.x * blockDim.x) {
    float4 v = x[i];
    m = fmaxf(m, fmaxf(fmaxf(fabsf(v.x), fabsf(v.y)), fmaxf(fabsf(v.z), fabsf(v.w))));
  }
  __shared__ float red[4];
  m = warpMax(m);
  int lane = threadIdx.x & 63, w = threadIdx.x >> 6;
  if (lane == 0) red[w] = m;
  __syncthreads();
  if (threadIdx.x == 0) {
    float r = fmaxf(fmaxf(red[0], red[1]), fmaxf(red[2], red[3]));
    atomicMax(slot + (blockIdx.x & 15), __float_as_uint(r));
  }
}

__global__ __launch_bounds__(256) void k_quant4(const float4* __restrict__ in,
                                                float4* __restrict__ out, long n4,
                                                const u32* __restrict__ sc, int slot) {
  float s = read_max16(sc, slot) / 127.0f + 1e-8f;
  for (long i = (long)blockIdx.x * blockDim.x + threadIdx.x; i < n4;
       i += (long)gridDim.x * blockDim.x) {
    float4 v = in[i];
    v.x = fqs(v.x, s); v.y = fqs(v.y, s); v.z = fqs(v.z, s); v.w = fqs(v.w, s);
    out[i] = v;
  }
}

__global__ __launch_bounds__(256) void k_quant_codes(const float4* __restrict__ in,
                                                     u32* __restrict__ out, long n4,
                                                     const u32* __restrict__ sc, int slot) {
  float s = read_max16(sc, slot) / 127.0f + 1e-8f;
  for (long i = (long)blockIdx.x * blockDim.x + threadIdx.x; i < n4;
       i += (long)gridDim.x * blockDim.x) {
    float4 v = in[i];
    int c0 = (int)fminf(fmaxf(rintf(v.x / s), -128.f), 127.f);
    int c1 = (int)fminf(fmaxf(rintf(v.y / s), -128.f), 127.f);
    int c2 = (int)fminf(fmaxf(rintf(v.z / s), -128.f), 127.f);
    int c3 = (int)fminf(fmaxf(rintf(v.w / s), -128.f), 127.f);
    out[i] = (u32)(c0 & 0xff) | ((u32)(c1 & 0xff) << 8) | ((u32)(c2 & 0xff) << 16) |
             ((u32)(c3 & 0xff) << 24);
  }
}

// ---------------------------------------------------------------------------
// patch embed: LDS-staged weights (coalesced), float4-staged x.
// ---------------------------------------------------------------------------
__global__ __launch_bounds__(192) void k_patch(const float* __restrict__ x,
                                               const float* __restrict__ pwq,
                                               const float* __restrict__ pb,
                                               const u32* __restrict__ sc,
                                               float* __restrict__ emb,
                                               u32* __restrict__ embSlot) {
  __shared__ float wsm[3840];
  __shared__ float xq[160];
  __shared__ float red[3];
  const int tid = threadIdx.x;
  const long rowBase = (long)blockIdx.x * 8;
  const float sx = read_max16(sc, SLOT_X) / 127.0f + 1e-8f;
#pragma unroll
  for (int j = 0; j < 5; ++j)
    ((float4*)wsm)[j * 192 + tid] = ((const float4*)pwq)[j * 192 + tid];
  if (tid < 40) {
    float4 v = ((const float4*)(x + rowBase * 20))[tid];
    v.x = fqs(v.x, sx); v.y = fqs(v.y, sx); v.z = fqs(v.z, sx); v.w = fqs(v.w, sx);
    ((float4*)xq)[tid] = v;
  }
  __syncthreads();
  float wreg[20];
#pragma unroll
  for (int k = 0; k < 20; ++k) wreg[k] = wsm[tid * 20 + k];
  const float bias = pb[tid];
  float m = 0.f;
#pragma unroll
  for (int r = 0; r < 8; ++r) {
    float acc = bias;
#pragma unroll
    for (int k = 0; k < 20; ++k) acc += xq[r * 20 + k] * wreg[k];
    emb[(rowBase + r) * 192 + tid] = acc;
    m = fmaxf(m, fabsf(acc));
  }
  m = warpMax(m);
  if ((tid & 63) == 0) red[tid >> 6] = m;
  __syncthreads();
  if (tid == 0)
    atomicMax(embSlot + (blockIdx.x & 15),
              __float_as_uint(fmaxf(fmaxf(red[0], red[1]), red[2])));
}

// ---------------------------------------------------------------------------
// Fused [H += fq(raw)] + LayerNorm. One wave/row, 4 rows/block.
// raw and plane outputs are ALWAYS in different ws regions (no aliasing).
// I16: planes + row scale; else fp32 out (yf).
// ---------------------------------------------------------------------------
template <bool RES, bool I16>
__global__ __launch_bounds__(256) void k_resln(float* __restrict__ H,
                                               const float* __restrict__ raw,
                                               const u32* __restrict__ sc, int slotRes,
                                               const float* __restrict__ g,
                                               const float* __restrict__ bta,
                                               signed char* __restrict__ yh,
                                               signed char* __restrict__ yl,
                                               float* __restrict__ sArow,
                                               float* __restrict__ yf, int rows) {
  int w = threadIdx.x >> 6, lane = threadIdx.x & 63;
  long row = (long)blockIdx.x * 4 + w;
  if (row >= rows) return;
  const bool act = lane < 48;
  float4 v = make_float4(0.f, 0.f, 0.f, 0.f);
  if (act) v = ((const float4*)(H + row * 192))[lane];
  if (RES) {
    float sres = read_max16(sc, slotRes) / 127.0f + 1e-8f;
    if (act) {
      float4 r4 = ((const float4*)(raw + row * 192))[lane];
      v.x += fqs(r4.x, sres); v.y += fqs(r4.y, sres);
      v.z += fqs(r4.z, sres); v.w += fqs(r4.w, sres);
      ((float4*)(H + row * 192))[lane] = v;
    }
  }
  float s = v.x + v.y + v.z + v.w;
#pragma unroll
  for (int o = 32; o > 0; o >>= 1) s += __shfl_down(s, o);
  s = __shfl(s, 0);
  float mean = s / 192.0f;
  float d0 = v.x - mean, d1 = v.y - mean, d2 = v.z - mean, d3 = v.w - mean;
  float q = act ? (d0 * d0 + d1 * d1 + d2 * d2 + d3 * d3) : 0.f;
#pragma unroll
  for (int o = 32; o > 0; o >>= 1) q += __shfl_down(q, o);
  q = __shfl(q, 0);
  float rs = 1.0f / sqrtf(q / 192.0f + 1e-5f);
  float4 gv = make_float4(0.f, 0.f, 0.f, 0.f), bv = gv;
  if (act) {
    gv = ((const float4*)g)[lane];
    bv = ((const float4*)bta)[lane];
  }
  float o0 = d0 * rs * gv.x + bv.x;
  float o1 = d1 * rs * gv.y + bv.y;
  float o2 = d2 * rs * gv.z + bv.z;
  float o3 = d3 * rs * gv.w + bv.w;
  if (I16) {
    float rm = act ? fmaxf(fmaxf(fabsf(o0), fabsf(o1)), fmaxf(fabsf(o2), fabsf(o3))) : 0.f;
#pragma unroll
    for (int o = 32; o > 0; o >>= 1) rm = fmaxf(rm, __shfl_down(rm, o));
    rm = __shfl(rm, 0);
    float sA = rm / 32512.0f + 1e-20f;
    float inv = 1.0f / sA;
    if (act) {
      int c0 = (int)rintf(o0 * inv), c1 = (int)rintf(o1 * inv);
      int c2 = (int)rintf(o2 * inv), c3 = (int)rintf(o3 * inv);
      int h0 = (c0 + 128) >> 8, h1 = (c1 + 128) >> 8;
      int h2 = (c2 + 128) >> 8, h3 = (c3 + 128) >> 8;
      int l0 = c0 - (h0 << 8), l1 = c1 - (h1 << 8);
      int l2 = c2 - (h2 << 8), l3 = c3 - (h3 << 8);
      u32 hw = (u32)(h0 & 0xff) | ((u32)(h1 & 0xff) << 8) | ((u32)(h2 & 0xff) << 16) |
               ((u32)(h3 & 0xff) << 24);
      u32 lw = (u32)(l0 & 0xff) | ((u32)(l1 & 0xff) << 8) | ((u32)(l2 & 0xff) << 16) |
               ((u32)(l3 & 0xff) << 24);
      ((u32*)yh)[row * 48 + lane] = hw;
      ((u32*)yl)[row * 48 + lane] = lw;
    }
    if (lane == 0) sArow[row] = sA;
  } else {
    if (act) ((float4*)(yf + row * 192))[lane] = make_float4(o0, o1, o2, o3);
  }
}

// ---------------------------------------------------------------------------
__global__ __launch_bounds__(256) void k_wquant(const float4* __restrict__ w,
                                                u32* __restrict__ out, int n4,
                                                const u32* __restrict__ sc, int slot) {
  int i = blockIdx.x * blockDim.x + threadIdx.x;
  if (i >= n4) return;
  float s = read_max16(sc, slot) / 127.0f + 1e-8f;
  float4 v = w[i];
  int c0 = (int)fminf(fmaxf(rintf(v.x / s), -128.f), 127.f);
  int c1 = (int)fminf(fmaxf(rintf(v.y / s), -128.f), 127.f);
  int c2 = (int)fminf(fmaxf(rintf(v.z / s), -128.f), 127.f);
  int c3 = (int)fminf(fmaxf(rintf(v.w / s), -128.f), 127.f);
  out[i] = (u32)(c0 & 0xff) | ((u32)(c1 & 0xff) << 8) | ((u32)(c2 & 0xff) << 16) |
           ((u32)(c3 & 0xff) << 24);
}

// ---------------------------------------------------------------------------
// i16-A x i8-W GEMM. LDS B panel; row loop unroll 1 (low VGPR, high occ).
// ---------------------------------------------------------------------------
template <bool GELU, int OM>
__global__ __launch_bounds__(256) void k_gemm16(
    const signed char* __restrict__ AH, const signed char* __restrict__ AL,
    const float* __restrict__ sArow, const signed char* __restrict__ W8, int slotW,
    const float* __restrict__ bias, signed char* __restrict__ C8, int N, int ncol,
    u32* __restrict__ sc, int slotO, int colsPerSlot) {
  __shared__ __align__(16) signed char Bs[192 * 208];
  __shared__ float red[4];
  const int tid = threadIdx.x;
  const int bid = blockIdx.x;
  const int vid = (bid & 7) * ((int)gridDim.x >> 3) + (bid >> 3);
  const int bx = vid % ncol;
  const long by = vid / ncol;
  const long rowBase = by * 128;
  const int colBase = bx * 192;
  const float sW = read_max16(sc, slotW) / 127.0f + 1e-8f;

  {
    const signed char* wp = W8 + (long)colBase * 192;
#pragma unroll
    for (int it = 0; it < 9; ++it) {
      int idx = it * 256 + tid;
      int row = idx / 12, c = idx % 12;
      int4 v = *(const int4*)(wp + (long)row * 192 + c * 16);
      *(int4*)&Bs[row * 208 + c * 16] = v;
    }
  }

  const int lane = tid & 63, w = tid >> 6;
  const int fr = lane & 15, fk = lane >> 4;
  const int wc0 = w * 48;

  float sOinv = 0.f;
  if (OM == 2) sOinv = 1.0f / (read_max16(sc, slotO + colBase / colsPerSlot) / 127.0f + 1e-8f);
  const float inv_sqrt2 = 0.70710678118654752440f;
  float vmax = 0.f;

  const long abase = (rowBase + fr) * 192 + fk * 16;
  __syncthreads();

#pragma unroll 1
  for (int it = 0; it < 8; ++it) {
    const long ab = abase + (long)it * 16 * 192;
    int4v ahc[3], alc[3];
#pragma unroll
    for (int kk = 0; kk < 3; ++kk) {
      ahc[kk] = *(const int4v*)(AH + ab + kk * 64);
      alc[kk] = *(const int4v*)(AL + ab + kk * 64);
    }
    int4v aH[3], aL[3];
#pragma unroll
    for (int n = 0; n < 3; ++n) {
      aH[n] = (int4v){0, 0, 0, 0};
      aL[n] = (int4v){0, 0, 0, 0};
    }
#pragma unroll
    for (int kk = 0; kk < 3; ++kk) {
#pragma unroll
      for (int n = 0; n < 3; ++n) {
        int4v bfr = *(const int4v*)&Bs[(wc0 + n * 16 + fr) * 208 + kk * 64 + fk * 16];
        aH[n] = MFMA_I8(ahc[kk], bfr, aH[n]);
        aL[n] = MFMA_I8(alc[kk], bfr, aL[n]);
      }
    }
    const long rt = rowBase + it * 16;
    float4 sA4 = *(const float4*)&sArow[rt + fk * 4];
    float sAr[4] = {sA4.x, sA4.y, sA4.z, sA4.w};
#pragma unroll
    for (int n = 0; n < 3; ++n) {
      const int col = colBase + wc0 + n * 16 + fr;
      const float bb = bias[col];
#pragma unroll
      for (int r = 0; r < 4; ++r) {
        const int R = (aH[n][r] << 8) + aL[n][r];
        float val = (float)R * (sAr[r] * sW) + bb;
        if (GELU) val = 0.5f * val * (1.0f + erff(val * inv_sqrt2));
        if (OM == 2) {
          float code = fminf(fmaxf(rintf(val * sOinv), -128.f), 127.f);
          C8[(rt + fk * 4 + r) * N + col] = (signed char)code;
        } else {
          vmax = fmaxf(vmax, fabsf(val));
        }
      }
    }
  }

  if (OM == 1) {
    float m = warpMax(vmax);
    if ((tid & 63) == 0) red[tid >> 6] = m;
    __syncthreads();
    if (tid == 0) {
      float r = fmaxf(fmaxf(red[0], red[1]), fmaxf(red[2], red[3]));
      atomicMax(sc + (slotO + colBase / colsPerSlot) * 16 + ((int)(bx + by) & 15),
                __float_as_uint(r));
    }
  }
}

// ---------------------------------------------------------------------------
// i8-MFMA GEMM (A codes), LDS-free, single pass: store fp32 + absmax.
// ---------------------------------------------------------------------------
__global__ __launch_bounds__(256) void k_gemm8(
    const signed char* __restrict__ A8, int slotA, const signed char* __restrict__ W8,
    int slotW, const float* __restrict__ bias, float* __restrict__ C, int N, int K,
    u32* __restrict__ sc, int slotO) {
  __shared__ float red[4];
  const int tid = threadIdx.x;
  const long rowBase = (long)blockIdx.y * 128;
  const int colBase = blockIdx.x * 192;
  const float alpha = (read_max16(sc, slotA) / 127.0f + 1e-8f) *
                      (read_max16(sc, slotW) / 127.0f + 1e-8f);

  const int lane = tid & 63, wv = tid >> 6;
  const int wm = wv >> 1, wn = wv & 1;
  const int fr = lane & 15, fk = lane >> 4;

  int4v acc[4][6];
#pragma unroll
  for (int m = 0; m < 4; ++m)
#pragma unroll
    for (int n = 0; n < 6; ++n) acc[m][n] = (int4v){0, 0, 0, 0};

  const long arow0 = rowBase + wm * 64;
  const int bcol0 = colBase + wn * 96;

  for (int k0 = 0; k0 < K; k0 += 64) {
    const int ko = k0 + fk * 16;
    int4v bfr[6];
#pragma unroll
    for (int n = 0; n < 6; ++n)
      bfr[n] = *(const int4v*)(W8 + (long)(bcol0 + n * 16 + fr) * K + ko);
#pragma unroll
    for (int m = 0; m < 4; ++m) {
      int4v af = *(const int4v*)(A8 + (arow0 + m * 16 + fr) * (long)K + ko);
#pragma unroll
      for (int n = 0; n < 6; ++n) acc[m][n] = MFMA_I8(af, bfr[n], acc[m][n]);
    }
  }

  float vmax = 0.f;
#pragma unroll
  for (int n = 0; n < 6; ++n) {
    const int col = colBase + wn * 96 + n * 16 + fr;
    const float bb = bias[col];
#pragma unroll
    for (int m = 0; m < 4; ++m) {
#pragma unroll
      for (int r = 0; r < 4; ++r) {
        const long row = rowBase + wm * 64 + m * 16 + fk * 4 + r;
        float val = (float)acc[m][n][r] * alpha + bb;
        C[row * N + col] = val;
        vmax = fmaxf(vmax, fabsf(val));
      }
    }
  }
  {
    float m = warpMax(vmax);
    if ((tid & 63) == 0) red[tid >> 6] = m;
    __syncthreads();
    if (tid == 0) {
      float r = fmaxf(fmaxf(red[0], red[1]), fmaxf(red[2], red[3]));
      atomicMax(sc + slotO * 16 + ((blockIdx.x + blockIdx.y) & 15), __float_as_uint(r));
    }
  }
}

// ---------------------------------------------------------------------------
// k_vt: per (b,h), transpose V codes -> VT8[bh][64][400] + colsumV.
// ---------------------------------------------------------------------------
__global__ __launch_bounds__(256) void k_vt(const signed char* __restrict__ qkv8,
                                            signed char* __restrict__ vt8,
                                            int* __restrict__ colsum) {
  __shared__ __align__(16) signed char T[64 * 80];
  __shared__ int cs[64];
  const int tid = threadIdx.x;
  const int bh = blockIdx.x, b = bh / 3, hh = bh % 3;
  const signed char* vb = qkv8 + (long)b * 400 * 576 + hh * 64 + 384;
  if (tid < 64) cs[tid] = 0;
  const int d = tid >> 2, seg = tid & 3;
  for (int c0 = 0; c0 < 448; c0 += 64) {
    __syncthreads();
    {
      int trow = tid >> 2, c = tid & 3;
      int4 v = make_int4(0, 0, 0, 0);
      if (c0 + trow < 400) v = *(const int4*)(vb + (long)(c0 + trow) * 576 + c * 16);
      *(int4*)&T[trow * 80 + c * 16] = v;
    }
    __syncthreads();
    int4 outw;
    int ssum = 0;
    u32 pk[4];
#pragma unroll
    for (int j = 0; j < 4; ++j) {
      u32 p = 0;
#pragma unroll
      for (int e = 0; e < 4; ++e) {
        int t = seg * 16 + j * 4 + e;
        int v = (int)T[t * 80 + d];
        ssum += v;
        p |= ((u32)(v & 0xff)) << (8 * e);
      }
      pk[j] = p;
    }
    outw.x = (int)pk[0]; outw.y = (int)pk[1]; outw.z = (int)pk[2]; outw.w = (int)pk[3];
    if (c0 + seg * 16 < 400)
      *(int4*)&vt8[(long)bh * 25600 + d * 400 + c0 + seg * 16] = outw;
    atomicAdd(&cs[d], ssum);
  }
  __syncthreads();
  if (tid < 64) colsum[bh * 64 + tid] = cs[tid];
}

// ---------------------------------------------------------------------------
// Attention, i8 MFMA, transposed scores. 1D grid 5376, XCD-chunked.
// ---------------------------------------------------------------------------
__device__ __forceinline__ void attn_swz(int& tile, int& bh) {
  int bid = blockIdx.x;
  int vid = (bid & 7) * ((int)gridDim.x >> 3) + (bid >> 3);
  tile = vid % 7;
  bh = vid / 7;
}

__global__ __launch_bounds__(256) void k_attn0(const signed char* __restrict__ qkv8,
                                               int* __restrict__ gmInt, u32* __restrict__ sc,
                                               int slotQ, int slotSc) {
  __shared__ float red[4];
  const int tid = threadIdx.x;
  int tile, bh;
  attn_swz(tile, bh);
  const int r0 = tile * 64;
  const int b = bh / 3, hh = bh % 3;
  const signed char* qb = qkv8 + (long)b * 400 * 576 + hh * 64;
  const signed char* kb = qb + 192;
  const float sQ = read_max16(sc, slotQ) / 127.0f + 1e-8f;
  const float sK = read_max16(sc, slotQ + 1) / 127.0f + 1e-8f;
  const float sSc = sQ * sK * 0.125f;

  const int lane = tid & 63, w = tid >> 6, fr = lane & 15, fk = lane >> 4;
  const int qloc = 16 * w + fr;
  const int gq = r0 + qloc;
  const bool qv = gq < 400;
  int4v qf = *(const int4v*)(qb + (long)(r0 + qloc) * 576 + fk * 16);

  int aim = 0;
  int rim = -(1 << 30);
  for (int c0 = 0; c0 < 400; c0 += 128) {
#pragma unroll
    for (int tf = 0; tf < 8; ++tf) {
      int4v kf = *(const int4v*)(kb + (long)(c0 + tf * 16 + fr) * 576 + fk * 16);
      int4v s = MFMA_I8(kf, qf, ((int4v){0, 0, 0, 0}));
      const bool tv = (c0 + tf * 16 + fk * 4) < 400;
      if (tv && qv) {
#pragma unroll
        for (int r = 0; r < 4; ++r) {
          int sv = s[r];
          aim = max(aim, max(sv, -sv));
          rim = max(rim, sv);
        }
      }
    }
  }
  rim = max(rim, __shfl_xor(rim, 16));
  rim = max(rim, __shfl_xor(rim, 32));
  if (fk == 0 && qv) gmInt[(long)bh * 400 + gq] = rim;
  float m = warpMax((float)aim * sSc);
  if (lane == 0) red[w] = m;
  __syncthreads();
  if (tid == 0) {
    float r = fmaxf(fmaxf(red[0], red[1]), fmaxf(red[2], red[3]));
    atomicMax(sc + slotSc * 16 + (blockIdx.x & 15), __float_as_uint(r));
  }
}

__global__ __launch_bounds__(256) void k_attn1(const signed char* __restrict__ qkv8,
                                               float* __restrict__ gm, float* __restrict__ gl,
                                               const int* __restrict__ gmInt,
                                               u32* __restrict__ sc, int slotQ, int slotSc,
                                               int slotPr) {
  __shared__ float red[4];
  const int tid = threadIdx.x;
  int tile, bh;
  attn_swz(tile, bh);
  const int r0 = tile * 64;
  const int b = bh / 3, hh = bh % 3;
  const signed char* qb = qkv8 + (long)b * 400 * 576 + hh * 64;
  const signed char* kb = qb + 192;
  const float sQ = read_max16(sc, slotQ) / 127.0f + 1e-8f;
  const float sK = read_max16(sc, slotQ + 1) / 127.0f + 1e-8f;
  const float sSc = sQ * sK * 0.125f;
  const float sS = read_max16(sc, slotSc) / 127.0f + 1e-8f;
  const float c1 = sSc / sS;
  const float c2 = sS * LOG2E;

  const int lane = tid & 63, w = tid >> 6, fr = lane & 15, fk = lane >> 4;
  const int qloc = 16 * w + fr;
  const int gq = r0 + qloc;
  const int gqc = (gq > 399) ? 399 : gq;
  int4v qf = *(const int4v*)(qb + (long)(r0 + qloc) * 576 + fk * 16);

  const int mint = gmInt[(long)bh * 400 + gqc];
  const float cm = fminf(fmaxf(rintf((float)mint * c1), -128.f), 127.f);

  float sum = 0.f;
  for (int c0 = 0; c0 < 400; c0 += 128) {
#pragma unroll
    for (int tf = 0; tf < 8; ++tf) {
      int4v kf = *(const int4v*)(kb + (long)(c0 + tf * 16 + fr) * 576 + fk * 16);
      int4v s = MFMA_I8(kf, qf, ((int4v){0, 0, 0, 0}));
      if ((c0 + tf * 16 + fk * 4) < 400) {
#pragma unroll
        for (int r = 0; r < 4; ++r) {
          float cf = fminf(fmaxf(rintf((float)s[r] * c1), -128.f), 127.f);
          sum += exp2f((cf - cm) * c2);
        }
      }
    }
  }
  sum += __shfl_xor(sum, 16);
  sum += __shfl_xor(sum, 32);
  float cand = 0.f;
  if (fk == 0 && gq < 400) {
    gm[(long)bh * 400 + gq] = cm;
    gl[(long)bh * 400 + gq] = sum;
    cand = 1.0f / sum;
  }
  float m = warpMax(cand);
  if (lane == 0) red[w] = m;
  __syncthreads();
  if (tid == 0) {
    float r = fmaxf(fmaxf(red[0], red[1]), fmaxf(red[2], red[3]));
    atomicMax(sc + slotPr * 16 + (blockIdx.x & 15), __float_as_uint(r));
  }
}

__global__ __launch_bounds__(256) void k_attn_pv(
    const signed char* __restrict__ qkv8, const signed char* __restrict__ vt8,
    const int* __restrict__ colsumV, float* __restrict__ ctx, const float* __restrict__ gm,
    const float* __restrict__ gl, u32* __restrict__ sc, int slotQ, int slotSc, int slotPr,
    int slotCtx) {
  __shared__ __align__(16) signed char Ps[64 * 144];
  __shared__ int colsV[64];
  __shared__ float red[4];
  const int tid = threadIdx.x;
  int tile, bh;
  attn_swz(tile, bh);
  const int r0 = tile * 64;
  const int b = bh / 3, hh = bh % 3;
  const signed char* qb = qkv8 + (long)b * 400 * 576 + hh * 64;
  const signed char* kb = qb + 192;
  const signed char* vtb = vt8 + (long)bh * 25600;
  const float sQ = read_max16(sc, slotQ) / 127.0f + 1e-8f;
  const float sK = read_max16(sc, slotQ + 1) / 127.0f + 1e-8f;
  const float sV = read_max16(sc, slotQ + 2) / 127.0f + 1e-8f;
  const float sSc = sQ * sK * 0.125f;
  const float sS = read_max16(sc, slotSc) / 127.0f + 1e-8f;
  const float sP = read_max16(sc, slotPr) / 255.0f + 1e-8f;
  const float sPV = sP * sV;
  const float c1 = sSc / sS;
  const float c2 = sS * LOG2E;

  if (tid < 64) colsV[tid] = colsumV[bh * 64 + tid];
  const int lane = tid & 63, w = tid >> 6, fr = lane & 15, fk = lane >> 4;
  const int qloc = 16 * w + fr;
  int4v qf = *(const int4v*)(qb + (long)(r0 + qloc) * 576 + fk * 16);

  int gq = r0 + qloc;
  if (gq > 399) gq = 399;
  const float cm = gm[(long)bh * 400 + gq];
  const float invLsp = 1.0f / (gl[(long)bh * 400 + gq] * sP);

  int4v accd[4];
#pragma unroll
  for (int dt = 0; dt < 4; ++dt) accd[dt] = (int4v){0, 0, 0, 0};
  __syncthreads();

  for (int c0 = 0; c0 < 400; c0 += 128) {
#pragma unroll
    for (int tf = 0; tf < 8; ++tf) {
      int4v kf = *(const int4v*)(kb + (long)(c0 + tf * 16 + fr) * 576 + fk * 16);
      int4v s = MFMA_I8(kf, qf, ((int4v){0, 0, 0, 0}));
      const int tbase = c0 + tf * 16 + fk * 4;
      u32 pack = 0;
      if (tbase < 400) {
#pragma unroll
        for (int r = 0; r < 4; ++r) {
          float cf = fminf(fmaxf(rintf((float)s[r] * c1), -128.f), 127.f);
          float e = exp2f((cf - cm) * c2);
          float pu = fminf(fmaxf(rintf(e * invLsp), 0.f), 255.f);
          int pc = (int)pu - 128;
          pack |= ((u32)(pc & 0xff)) << (8 * r);
        }
      }
      *(u32*)&Ps[qloc * 144 + tf * 16 + fk * 4] = pack;
    }
    __syncthreads();
    int4v pf0 = *(const int4v*)&Ps[qloc * 144 + fk * 16];
    int4v pf1 = *(const int4v*)&Ps[qloc * 144 + 64 + fk * 16];
    const bool v0ok = (c0 + fk * 16) < 400;
    const bool v1ok = (c0 + 64 + fk * 16) < 400;
#pragma unroll
    for (int dt = 0; dt < 4; ++dt) {
      const long vrow = (long)(dt * 16 + fr) * 400;
      int4v vf0 = v0ok ? *(const int4v*)(vtb + vrow + c0 + fk * 16) : (int4v){0, 0, 0, 0};
      int4v vf1 = v1ok ? *(const int4v*)(vtb + vrow + c0 + 64 + fk * 16) : (int4v){0, 0, 0, 0};
      accd[dt] = MFMA_I8(vf0, pf0, accd[dt]);
      accd[dt] = MFMA_I8(vf1, pf1, accd[dt]);
    }
    __syncthreads();
  }
  float vmax = 0.f;
  const int q = r0 + qloc;
  if (q < 400) {
#pragma unroll
    for (int dt = 0; dt < 4; ++dt) {
      const int d0 = dt * 16 + fk * 4;
      float4 o;
      o.x = sPV * (float)(accd[dt][0] + 128 * colsV[d0 + 0]);
      o.y = sPV * (float)(accd[dt][1] + 128 * colsV[d0 + 1]);
      o.z = sPV * (float)(accd[dt][2] + 128 * colsV[d0 + 2]);
      o.w = sPV * (float)(accd[dt][3] + 128 * colsV[d0 + 3]);
      vmax = fmaxf(vmax, fmaxf(fmaxf(fabsf(o.x), fabsf(o.y)), fmaxf(fabsf(o.z), fabsf(o.w))));
      *(float4*)&ctx[(long)(b * 400 + q) * 192 + hh * 64 + d0] = o;
    }
  }
  float m = warpMax(vmax);
  if (lane == 0) red[w] = m;
  __syncthreads();
  if (tid == 0) {
    float r = fmaxf(fmaxf(red[0], red[1]), fmaxf(red[2], red[3]));
    atomicMax(sc + slotCtx * 16 + (blockIdx.x & 15), __float_as_uint(r));
  }
}

// ---------------------------------------------------------------------------
__global__ __launch_bounds__(192) void k_pool(const float* __restrict__ xln,
                                              float* __restrict__ pooled,
                                              u32* __restrict__ slot) {
  int b = blockIdx.x, d = threadIdx.x;
  float sum = 0.f;
  for (int s = 0; s < 400; ++s) sum += xln[((long)b * 400 + s) * 192 + d];
  float v = sum / 400.0f;
  pooled[(long)b * 192 + d] = v;
  __shared__ float red[3];
  float m = warpMax(fabsf(v));
  if ((d & 63) == 0) red[d >> 6] = m;
  __syncthreads();
  if (d == 0)
    atomicMax(slot + (b & 15), __float_as_uint(fmaxf(fmaxf(red[0], red[1]), red[2])));
}

__global__ __launch_bounds__(64) void k_logits(const float* __restrict__ pooled,
                                               const float* __restrict__ clfq,
                                               const float* __restrict__ clfb,
                                               const u32* __restrict__ sc,
                                               float* __restrict__ out) {
  int c = blockIdx.x, b = blockIdx.y, lane = threadIdx.x;
  float sp = read_max16(sc, SLOT_POOL) / 127.0f + 1e-8f;
  float acc = 0.f;
#pragma unroll
  for (int j = 0; j < 3; ++j) {
    int d = lane + 64 * j;
    acc += fqs(pooled[(long)b * 192 + d], sp) * clfq[c * 192 + d];
  }
#pragma unroll
  for (int o = 32; o > 0; o >>= 1) acc += __shfl_down(acc, o);
  if (lane == 0) out[b * 7 + c] = acc + clfb[c];
}

// ---------------------------------------------------------------------------
// host
// ---------------------------------------------------------------------------
static inline int gsz(long n4, long cap) {
  long g = (n4 + 255) / 256;
  return (int)(g < cap ? g : cap);
}

extern "C" void kernel_launch(void* const* d_in, const int* in_sizes, int n_in,
                              void* d_out, int out_size, void* d_ws, size_t ws_size,
                              hipStream_t stream) {
  (void)in_sizes; (void)n_in; (void)out_size; (void)ws_size;

  const float* x = (const float*)d_in[0];
  const float* pw = (const float*)d_in[1];
  const float* pb = (const float*)d_in[2];
  const float* ln1g = (const float*)d_in[3];
  const float* ln1b = (const float*)d_in[4];
  const float* wqkv = (const float*)d_in[5];
  const float* bqkv = (const float*)d_in[6];
  const float* wo = (const float*)d_in[7];
  const float* bo = (const float*)d_in[8];
  const float* ln2g = (const float*)d_in[9];
  const float* ln2b = (const float*)d_in[10];
  const float* w1 = (const float*)d_in[11];
  const float* b1 = (const float*)d_in[12];
  const float* w2 = (const float*)d_in[13];
  const float* b2 = (const float*)d_in[14];
  const float* lnfg = (const float*)d_in[15];
  const float* lnfb = (const float*)d_in[16];
  const float* clfw = (const float*)d_in[17];
  const float* clfb = (const float*)d_in[18];

  float* ws = (float*)d_ws;
  u32* sc = (u32*)d_ws;
  float* GM = ws + OFF_GM;
  int* GMI = (int*)GM;
  float* GL = ws + OFF_GL;
  float* POOL = ws + OFF_POOL;
  float* PWQ = ws + OFF_PWQ;
  float* CLFQ = ws + OFF_CLFQ;
  float* H = ws + OFF_H;

  // ping-pong regions
  signed char* RA = (signed char*)(ws + OFF_A);  // 78.6 MB
  signed char* RU = (signed char*)(ws + OFF_U);  // 78.6 MB
  // planes for ln1/qkv (in RU)
  signed char* PLQ_H = RU;
  signed char* PLQ_L = RU + 19660800;
  float* PLQ_S = (float*)(RU + 39321600);
  // qkv codes + VT8 (in RA)
  signed char* QKV8 = RA;
  signed char* VT8 = RA + 58982400;
  // ctx fp32 (RU), ctx codes (RA head), wo fp32 out (RU)
  float* CTXF = (float*)RU;
  signed char* CTX8 = RA;
  float* WOOUT = (float*)RU;
  // planes for ln2/w1 (in RA)
  signed char* PL2_H = RA;
  signed char* PL2_L = RA + 19660800;
  float* PL2_S = (float*)(RA + 39321600);
  // gelu codes (RU), w2 fp32 out (RA), final LN fp32 (RU)
  signed char* GELU8 = RU;
  float* W2OUT = (float*)RA;
  float* FINALF = (float*)RU;

  int* COLSUM = (int*)POOL;
  signed char* WQC = (signed char*)POOL;
  signed char* WOC2 = (signed char*)POOL;
  signed char* W1C2 = (signed char*)POOL + 36864;
  signed char* W2C2 = (signed char*)POOL + 36864;
  float* out = (float*)d_out;

  k_zero<<<(N_SLOT_WORDS + 255) / 256, 256, 0, stream>>>(sc, N_SLOT_WORDS);

  auto amax = [&](const float* p, long n, int slot) {
    k_absmax<<<gsz(n / 4, 256), 256, 0, stream>>>((const float4*)p, n / 4, sc + slot * 16);
  };
  amax(pw, 3840, SLOT_PW);
  amax(clfw, 1344, SLOT_CLF);
  amax(x, 2048000, SLOT_X);
  for (int i = 0; i < NL; ++i) {
    int Lb = 16 + i * 16;
    amax(wqkv + (long)i * 110592, 110592, Lb + 0);
    amax(wo + (long)i * 36864, 36864, Lb + 1);
    amax(w1 + (long)i * 147456, 147456, Lb + 2);
    amax(w2 + (long)i * 147456, 147456, Lb + 3);
  }
  k_quant4<<<gsz(960, 256), 256, 0, stream>>>((const float4*)pw, (float4*)PWQ, 960, sc, SLOT_PW);
  k_quant4<<<gsz(336, 256), 256, 0, stream>>>((const float4*)clfw, (float4*)CLFQ, 336, sc,
                                              SLOT_CLF);

  // patch embed -> RU fp32 -> quant into H; first LN -> planes (RU head)
  k_patch<<<12800, 192, 0, stream>>>(x, PWQ, pb, sc, (float*)RU, sc + SLOT_EMB * 16);
  k_quant4<<<2048, 256, 0, stream>>>((const float4*)RU, (float4*)H, 19660800 / 4, sc, SLOT_EMB);
  k_resln<false, true><<<(int)(ROWS / 4), 256, 0, stream>>>(
      H, nullptr, sc, 0, ln1g, ln1b, PLQ_H, PLQ_L, PLQ_S, nullptr, (int)ROWS);

  for (int i = 0; i < NL; ++i) {
    int Lb = 16 + i * 16;
    // --- attention ---
    k_wquant<<<108, 256, 0, stream>>>((const float4*)(wqkv + (long)i * 110592), (u32*)WQC,
                                      27648, sc, Lb + 0);
    k_gemm16<false, 1><<<2400, 256, 0, stream>>>(PLQ_H, PLQ_L, PLQ_S, WQC, Lb + 0,
                                                 bqkv + i * 576, nullptr, 576, 3, sc, Lb + 4,
                                                 192);
    k_gemm16<false, 2><<<2400, 256, 0, stream>>>(PLQ_H, PLQ_L, PLQ_S, WQC, Lb + 0,
                                                 bqkv + i * 576, QKV8, 576, 3, sc, Lb + 4,
                                                 192);
    k_vt<<<768, 256, 0, stream>>>(QKV8, VT8, COLSUM);
    k_attn0<<<5376, 256, 0, stream>>>(QKV8, GMI, sc, Lb + 4, Lb + 7);
    k_attn1<<<5376, 256, 0, stream>>>(QKV8, GM, GL, GMI, sc, Lb + 4, Lb + 7, Lb + 8);
    k_attn_pv<<<5376, 256, 0, stream>>>(QKV8, VT8, COLSUM, CTXF, GM, GL, sc, Lb + 4, Lb + 7,
                                        Lb + 8, Lb + 9);
    // ctx fp32 (RU) -> ctx codes (RA head); wo codes into POOL
    k_quant_codes<<<2048, 256, 0, stream>>>((const float4*)CTXF, (u32*)CTX8, 19660800 / 4, sc,
                                            Lb + 9);
    k_wquant<<<36, 256, 0, stream>>>((const float4*)(wo + (long)i * 36864), (u32*)WOC2, 9216,
                                     sc, Lb + 1);
    {
      dim3 g(1, 800);
      k_gemm8<<<g, 256, 0, stream>>>(CTX8, Lb + 9, WOC2, Lb + 1, bo + i * 192, WOOUT, 192, 192,
                                     sc, Lb + 10);
    }
    // fused: H += fq(WOOUT); LN2 -> planes2 (RA head)
    k_resln<true, true><<<(int)(ROWS / 4), 256, 0, stream>>>(
        H, WOOUT, sc, Lb + 10, ln2g + i * 192, ln2b + i * 192, PL2_H, PL2_L, PL2_S, nullptr,
        (int)ROWS);
    // --- MLP ---
    k_wquant<<<144, 256, 0, stream>>>((const float4*)(w1 + (long)i * 147456), (u32*)W1C2,
                                      36864, sc, Lb + 2);
    k_gemm16<true, 1><<<3200, 256, 0, stream>>>(PL2_H, PL2_L, PL2_S, W1C2, Lb + 2,
                                                b1 + i * 768, nullptr, 768, 4, sc, Lb + 11,
                                                768);
    k_gemm16<true, 2><<<3200, 256, 0, stream>>>(PL2_H, PL2_L, PL2_S, W1C2, Lb + 2,
                                                b1 + i * 768, GELU8, 768, 4, sc, Lb + 11, 768);
    k_wquant<<<144, 256, 0, stream>>>((const float4*)(w2 + (long)i * 147456), (u32*)W2C2,
                                      36864, sc, Lb + 3);
    {
      dim3 g(1, 800);
      k_gemm8<<<g, 256, 0, stream>>>(GELU8, Lb + 11, W2C2, Lb + 3, b2 + i * 192, W2OUT, 192,
                                     768, sc, Lb + 12);
    }
    // fused: H += fq(W2OUT); next LN -> planes (RU head) or final LN -> RU fp32
    if (i < NL - 1) {
      k_resln<true, true><<<(int)(ROWS / 4), 256, 0, stream>>>(
          H, W2OUT, sc, Lb + 12, ln1g + (i + 1) * 192, ln1b + (i + 1) * 192, PLQ_H, PLQ_L,
          PLQ_S, nullptr, (int)ROWS);
    } else {
      k_resln<true, false><<<(int)(ROWS / 4), 256, 0, stream>>>(
          H, W2OUT, sc, Lb + 12, lnfg, lnfb, nullptr, nullptr, nullptr, FINALF, (int)ROWS);
    }
  }

  // pool + classifier
  k_pool<<<256, 192, 0, stream>>>(FINALF, POOL, sc + SLOT_POOL * 16);
  {
    dim3 g(7, 256);
    k_logits<<<g, 64, 0, stream>>>(POOL, CLFQ, clfb, sc, out);
  }
}

// Round 17
// 5786.775 us; speedup vs baseline: 1.4127x; 1.0490x over previous
//
#include <hip/hip_runtime.h>
#include <math.h>

// ---------------------------------------------------------------------------
// TinyMyo 8ch/400tok quant transformer — v17: 128-q-row attention tiles
// (shared K/V loads across 2 q-halves), vectorized k_patch stores,
// fused emb-quant+LN (MODE 2). Numerics element-identical to v16.
// ---------------------------------------------------------------------------

typedef unsigned int u32;
typedef unsigned short u16;
typedef __attribute__((ext_vector_type(4))) int int4v;

#define MFMA_I8(a, b, c) __builtin_amdgcn_mfma_i32_16x16x64_i8((a), (b), (c), 0, 0, 0)

constexpr int NL = 8;
constexpr long ROWS = 102400;  // B*SEQ
constexpr float LOG2E = 1.44269504088896340736f;

constexpr int SLOT_X = 0, SLOT_PW = 1, SLOT_EMB = 2, SLOT_CLF = 3, SLOT_POOL = 4;
constexpr int N_SLOT_WORDS = 200 * 16;

constexpr long OFF_GM = 3200;
constexpr long OFF_GL = OFF_GM + 307200;
constexpr long OFF_POOL = OFF_GL + 307200;
constexpr long OFF_PWQ = OFF_POOL + 49152;
constexpr long OFF_CLFQ = OFF_PWQ + 3840;
constexpr long OFF_H = OFF_CLFQ + 1344;
constexpr long OFF_A = OFF_H + 19660800;
constexpr long OFF_U = OFF_A + 19660800;

// ---------------------------------------------------------------------------
__device__ __forceinline__ float warpMax(float v) {
#pragma unroll
  for (int o = 32; o > 0; o >>= 1) v = fmaxf(v, __shfl_down(v, o));
  return v;
}

__device__ __forceinline__ float read_max16(const u32* sc, int slot) {
  const u32* p = sc + slot * 16;
  u32 m = 0;
#pragma unroll
  for (int i = 0; i < 16; ++i) m = max(m, p[i]);
  return __uint_as_float(m);
}

__device__ __forceinline__ float fqs(float x, float s) {
  return fminf(fmaxf(rintf(x / s), -128.0f), 127.0f) * s;
}

// ---------------------------------------------------------------------------
__global__ void k_zero(u32* p, int n) {
  int i = blockIdx.x * blockDim.x + threadIdx.x;
  if (i < n) p[i] = 0u;
}

__global__ __launch_bounds__(256) void k_absmax(const float4* __restrict__ x, long n4,
                                                u32* __restrict__ slot) {
  float m = 0.f;
  for (long i = (long)blockIdx.x * blockDim.x + threadIdx.x; i < n4;
       i += (long)gridDim.x * blockDim.x) {
    float4 v = x[i];
    m = fmaxf(m, fmaxf(fmaxf(fabsf(v.x), fabsf(v.y)), fmaxf(fabsf(v.z), fabsf(v.w))));
  }
  __shared__ float red[4];
  m = warpMax(m);
  int lane = threadIdx.x & 63, w = threadIdx.x >> 6;
  if (lane == 0) red[w] = m;
  __syncthreads();
  if (threadIdx.x == 0) {
    float r = fmaxf(fmaxf(red[0], red[1]), fmaxf(red[2], red[3]));
    atomicMax(slot + (blockIdx.x & 15), __float_as_uint(r));
  }
}

__global__ __launch_bounds__(256) void k_quant4(const float4* __restrict__ in,
                                                float4* __restrict__ out, long n4,
                                                const u32* __restrict__ sc, int slot) {
  float s = read_max16(sc, slot) / 127.0f + 1e-8f;
  for (long i = (long)blockIdx.x * blockDim.x + threadIdx.x; i < n4;
       i += (long)gridDim.x * blockDim.x) {
    float4 v = in[i];
    v.x = fqs(v.x, s); v.y = fqs(v.y, s); v.z = fqs(v.z, s); v.w = fqs(v.w, s);
    out[i] = v;
  }
}

__global__ __launch_bounds__(256) void k_quant_codes(const float4* __restrict__ in,
                                                     u32* __restrict__ out, long n4,
                                                     const u32* __restrict__ sc, int slot) {
  float s = read_max16(sc, slot) / 127.0f + 1e-8f;
  for (long i = (long)blockIdx.x * blockDim.x + threadIdx.x; i < n4;
       i += (long)gridDim.x * blockDim.x) {
    float4 v = in[i];
    int c0 = (int)fminf(fmaxf(rintf(v.x / s), -128.f), 127.f);
    int c1 = (int)fminf(fmaxf(rintf(v.y / s), -128.f), 127.f);
    int c2 = (int)fminf(fmaxf(rintf(v.z / s), -128.f), 127.f);
    int c3 = (int)fminf(fmaxf(rintf(v.w / s), -128.f), 127.f);
    out[i] = (u32)(c0 & 0xff) | ((u32)(c1 & 0xff) << 8) | ((u32)(c2 & 0xff) << 16) |
             ((u32)(c3 & 0xff) << 24);
  }
}

// ---------------------------------------------------------------------------
// patch embed: LDS-staged weights + LDS-staged outputs with float4 stores.
// ---------------------------------------------------------------------------
__global__ __launch_bounds__(192) void k_patch(const float* __restrict__ x,
                                               const float* __restrict__ pwq,
                                               const float* __restrict__ pb,
                                               const u32* __restrict__ sc,
                                               float* __restrict__ emb,
                                               u32* __restrict__ embSlot) {
  __shared__ float wsm[3840];
  __shared__ float xq[160];
  __shared__ float eout[1536];
  __shared__ float red[3];
  const int tid = threadIdx.x;
  const long rowBase = (long)blockIdx.x * 8;
  const float sx = read_max16(sc, SLOT_X) / 127.0f + 1e-8f;
#pragma unroll
  for (int j = 0; j < 5; ++j)
    ((float4*)wsm)[j * 192 + tid] = ((const float4*)pwq)[j * 192 + tid];
  if (tid < 40) {
    float4 v = ((const float4*)(x + rowBase * 20))[tid];
    v.x = fqs(v.x, sx); v.y = fqs(v.y, sx); v.z = fqs(v.z, sx); v.w = fqs(v.w, sx);
    ((float4*)xq)[tid] = v;
  }
  __syncthreads();
  float wreg[20];
#pragma unroll
  for (int k = 0; k < 20; ++k) wreg[k] = wsm[tid * 20 + k];
  const float bias = pb[tid];
  float m = 0.f;
#pragma unroll
  for (int r = 0; r < 8; ++r) {
    float acc = bias;
#pragma unroll
    for (int k = 0; k < 20; ++k) acc += xq[r * 20 + k] * wreg[k];
    eout[r * 192 + tid] = acc;
    m = fmaxf(m, fabsf(acc));
  }
  __syncthreads();
  float4* emb4 = (float4*)(emb + rowBase * 192);
  emb4[tid] = ((const float4*)eout)[tid];
  emb4[tid + 192] = ((const float4*)eout)[tid + 192];
  m = warpMax(m);
  if ((tid & 63) == 0) red[tid >> 6] = m;
  __syncthreads();
  if (tid == 0)
    atomicMax(embSlot + (blockIdx.x & 15),
              __float_as_uint(fmaxf(fmaxf(red[0], red[1]), red[2])));
}

// ---------------------------------------------------------------------------
// Fused residual/init + LayerNorm. MODE: 0 = LN(H); 1 = H += fq(raw) then LN;
// 2 = H = fq(raw) then LN.  I16: planes + row scale; else fp32 out (yf).
// raw and plane outputs are always in different regions (no aliasing).
// ---------------------------------------------------------------------------
template <int MODE, bool I16>
__global__ __launch_bounds__(256) void k_resln(float* __restrict__ H,
                                               const float* __restrict__ raw,
                                               const u32* __restrict__ sc, int slotRes,
                                               const float* __restrict__ g,
                                               const float* __restrict__ bta,
                                               signed char* __restrict__ yh,
                                               signed char* __restrict__ yl,
                                               float* __restrict__ sArow,
                                               float* __restrict__ yf, int rows) {
  int w = threadIdx.x >> 6, lane = threadIdx.x & 63;
  long row = (long)blockIdx.x * 4 + w;
  if (row >= rows) return;
  const bool act = lane < 48;
  float4 v = make_float4(0.f, 0.f, 0.f, 0.f);
  if (MODE == 0 || MODE == 1) {
    if (act) v = ((const float4*)(H + row * 192))[lane];
  }
  if (MODE == 1 || MODE == 2) {
    float sres = read_max16(sc, slotRes) / 127.0f + 1e-8f;
    if (act) {
      float4 r4 = ((const float4*)(raw + row * 192))[lane];
      v.x += fqs(r4.x, sres); v.y += fqs(r4.y, sres);
      v.z += fqs(r4.z, sres); v.w += fqs(r4.w, sres);
      ((float4*)(H + row * 192))[lane] = v;
    }
  }
  float s = v.x + v.y + v.z + v.w;
#pragma unroll
  for (int o = 32; o > 0; o >>= 1) s += __shfl_down(s, o);
  s = __shfl(s, 0);
  float mean = s / 192.0f;
  float d0 = v.x - mean, d1 = v.y - mean, d2 = v.z - mean, d3 = v.w - mean;
  float q = act ? (d0 * d0 + d1 * d1 + d2 * d2 + d3 * d3) : 0.f;
#pragma unroll
  for (int o = 32; o > 0; o >>= 1) q += __shfl_down(q, o);
  q = __shfl(q, 0);
  float rs = 1.0f / sqrtf(q / 192.0f + 1e-5f);
  float4 gv = make_float4(0.f, 0.f, 0.f, 0.f), bv = gv;
  if (act) {
    gv = ((const float4*)g)[lane];
    bv = ((const float4*)bta)[lane];
  }
  float o0 = d0 * rs * gv.x + bv.x;
  float o1 = d1 * rs * gv.y + bv.y;
  float o2 = d2 * rs * gv.z + bv.z;
  float o3 = d3 * rs * gv.w + bv.w;
  if (I16) {
    float rm = act ? fmaxf(fmaxf(fabsf(o0), fabsf(o1)), fmaxf(fabsf(o2), fabsf(o3))) : 0.f;
#pragma unroll
    for (int o = 32; o > 0; o >>= 1) rm = fmaxf(rm, __shfl_down(rm, o));
    rm = __shfl(rm, 0);
    float sA = rm / 32512.0f + 1e-20f;
    float inv = 1.0f / sA;
    if (act) {
      int c0 = (int)rintf(o0 * inv), c1 = (int)rintf(o1 * inv);
      int c2 = (int)rintf(o2 * inv), c3 = (int)rintf(o3 * inv);
      int h0 = (c0 + 128) >> 8, h1 = (c1 + 128) >> 8;
      int h2 = (c2 + 128) >> 8, h3 = (c3 + 128) >> 8;
      int l0 = c0 - (h0 << 8), l1 = c1 - (h1 << 8);
      int l2 = c2 - (h2 << 8), l3 = c3 - (h3 << 8);
      u32 hw = (u32)(h0 & 0xff) | ((u32)(h1 & 0xff) << 8) | ((u32)(h2 & 0xff) << 16) |
               ((u32)(h3 & 0xff) << 24);
      u32 lw = (u32)(l0 & 0xff) | ((u32)(l1 & 0xff) << 8) | ((u32)(l2 & 0xff) << 16) |
               ((u32)(l3 & 0xff) << 24);
      ((u32*)yh)[row * 48 + lane] = hw;
      ((u32*)yl)[row * 48 + lane] = lw;
    }
    if (lane == 0) sArow[row] = sA;
  } else {
    if (act) ((float4*)(yf + row * 192))[lane] = make_float4(o0, o1, o2, o3);
  }
}

// ---------------------------------------------------------------------------
__global__ __launch_bounds__(256) void k_wquant(const float4* __restrict__ w,
                                                u32* __restrict__ out, int n4,
                                                const u32* __restrict__ sc, int slot) {
  int i = blockIdx.x * blockDim.x + threadIdx.x;
  if (i >= n4) return;
  float s = read_max16(sc, slot) / 127.0f + 1e-8f;
  float4 v = w[i];
  int c0 = (int)fminf(fmaxf(rintf(v.x / s), -128.f), 127.f);
  int c1 = (int)fminf(fmaxf(rintf(v.y / s), -128.f), 127.f);
  int c2 = (int)fminf(fmaxf(rintf(v.z / s), -128.f), 127.f);
  int c3 = (int)fminf(fmaxf(rintf(v.w / s), -128.f), 127.f);
  out[i] = (u32)(c0 & 0xff) | ((u32)(c1 & 0xff) << 8) | ((u32)(c2 & 0xff) << 16) |
           ((u32)(c3 & 0xff) << 24);
}

// ---------------------------------------------------------------------------
// i16-A x i8-W GEMM. LDS B panel; row loop unroll 1.
// ---------------------------------------------------------------------------
template <bool GELU, int OM>
__global__ __launch_bounds__(256) void k_gemm16(
    const signed char* __restrict__ AH, const signed char* __restrict__ AL,
    const float* __restrict__ sArow, const signed char* __restrict__ W8, int slotW,
    const float* __restrict__ bias, signed char* __restrict__ C8, int N, int ncol,
    u32* __restrict__ sc, int slotO, int colsPerSlot) {
  __shared__ __align__(16) signed char Bs[192 * 208];
  __shared__ float red[4];
  const int tid = threadIdx.x;
  const int bid = blockIdx.x;
  const int vid = (bid & 7) * ((int)gridDim.x >> 3) + (bid >> 3);
  const int bx = vid % ncol;
  const long by = vid / ncol;
  const long rowBase = by * 128;
  const int colBase = bx * 192;
  const float sW = read_max16(sc, slotW) / 127.0f + 1e-8f;

  {
    const signed char* wp = W8 + (long)colBase * 192;
#pragma unroll
    for (int it = 0; it < 9; ++it) {
      int idx = it * 256 + tid;
      int row = idx / 12, c = idx % 12;
      int4 v = *(const int4*)(wp + (long)row * 192 + c * 16);
      *(int4*)&Bs[row * 208 + c * 16] = v;
    }
  }

  const int lane = tid & 63, w = tid >> 6;
  const int fr = lane & 15, fk = lane >> 4;
  const int wc0 = w * 48;

  float sOinv = 0.f;
  if (OM == 2) sOinv = 1.0f / (read_max16(sc, slotO + colBase / colsPerSlot) / 127.0f + 1e-8f);
  const float inv_sqrt2 = 0.70710678118654752440f;
  float vmax = 0.f;

  const long abase = (rowBase + fr) * 192 + fk * 16;
  __syncthreads();

#pragma unroll 1
  for (int it = 0; it < 8; ++it) {
    const long ab = abase + (long)it * 16 * 192;
    int4v ahc[3], alc[3];
#pragma unroll
    for (int kk = 0; kk < 3; ++kk) {
      ahc[kk] = *(const int4v*)(AH + ab + kk * 64);
      alc[kk] = *(const int4v*)(AL + ab + kk * 64);
    }
    int4v aH[3], aL[3];
#pragma unroll
    for (int n = 0; n < 3; ++n) {
      aH[n] = (int4v){0, 0, 0, 0};
      aL[n] = (int4v){0, 0, 0, 0};
    }
#pragma unroll
    for (int kk = 0; kk < 3; ++kk) {
#pragma unroll
      for (int n = 0; n < 3; ++n) {
        int4v bfr = *(const int4v*)&Bs[(wc0 + n * 16 + fr) * 208 + kk * 64 + fk * 16];
        aH[n] = MFMA_I8(ahc[kk], bfr, aH[n]);
        aL[n] = MFMA_I8(alc[kk], bfr, aL[n]);
      }
    }
    const long rt = rowBase + it * 16;
    float4 sA4 = *(const float4*)&sArow[rt + fk * 4];
    float sAr[4] = {sA4.x, sA4.y, sA4.z, sA4.w};
#pragma unroll
    for (int n = 0; n < 3; ++n) {
      const int col = colBase + wc0 + n * 16 + fr;
      const float bb = bias[col];
#pragma unroll
      for (int r = 0; r < 4; ++r) {
        const int R = (aH[n][r] << 8) + aL[n][r];
        float val = (float)R * (sAr[r] * sW) + bb;
        if (GELU) val = 0.5f * val * (1.0f + erff(val * inv_sqrt2));
        if (OM == 2) {
          float code = fminf(fmaxf(rintf(val * sOinv), -128.f), 127.f);
          C8[(rt + fk * 4 + r) * N + col] = (signed char)code;
        } else {
          vmax = fmaxf(vmax, fabsf(val));
        }
      }
    }
  }

  if (OM == 1) {
    float m = warpMax(vmax);
    if ((tid & 63) == 0) red[tid >> 6] = m;
    __syncthreads();
    if (tid == 0) {
      float r = fmaxf(fmaxf(red[0], red[1]), fmaxf(red[2], red[3]));
      atomicMax(sc + (slotO + colBase / colsPerSlot) * 16 + ((int)(bx + by) & 15),
                __float_as_uint(r));
    }
  }
}

// ---------------------------------------------------------------------------
// i8-MFMA GEMM (A codes), LDS-free, single pass: store fp32 + absmax.
// ---------------------------------------------------------------------------
__global__ __launch_bounds__(256) void k_gemm8(
    const signed char* __restrict__ A8, int slotA, const signed char* __restrict__ W8,
    int slotW, const float* __restrict__ bias, float* __restrict__ C, int N, int K,
    u32* __restrict__ sc, int slotO) {
  __shared__ float red[4];
  const int tid = threadIdx.x;
  const long rowBase = (long)blockIdx.y * 128;
  const int colBase = blockIdx.x * 192;
  const float alpha = (read_max16(sc, slotA) / 127.0f + 1e-8f) *
                      (read_max16(sc, slotW) / 127.0f + 1e-8f);

  const int lane = tid & 63, wv = tid >> 6;
  const int wm = wv >> 1, wn = wv & 1;
  const int fr = lane & 15, fk = lane >> 4;

  int4v acc[4][6];
#pragma unroll
  for (int m = 0; m < 4; ++m)
#pragma unroll
    for (int n = 0; n < 6; ++n) acc[m][n] = (int4v){0, 0, 0, 0};

  const long arow0 = rowBase + wm * 64;
  const int bcol0 = colBase + wn * 96;

  for (int k0 = 0; k0 < K; k0 += 64) {
    const int ko = k0 + fk * 16;
    int4v bfr[6];
#pragma unroll
    for (int n = 0; n < 6; ++n)
      bfr[n] = *(const int4v*)(W8 + (long)(bcol0 + n * 16 + fr) * K + ko);
#pragma unroll
    for (int m = 0; m < 4; ++m) {
      int4v af = *(const int4v*)(A8 + (arow0 + m * 16 + fr) * (long)K + ko);
#pragma unroll
      for (int n = 0; n < 6; ++n) acc[m][n] = MFMA_I8(af, bfr[n], acc[m][n]);
    }
  }

  float vmax = 0.f;
#pragma unroll
  for (int n = 0; n < 6; ++n) {
    const int col = colBase + wn * 96 + n * 16 + fr;
    const float bb = bias[col];
#pragma unroll
    for (int m = 0; m < 4; ++m) {
#pragma unroll
      for (int r = 0; r < 4; ++r) {
        const long row = rowBase + wm * 64 + m * 16 + fk * 4 + r;
        float val = (float)acc[m][n][r] * alpha + bb;
        C[row * N + col] = val;
        vmax = fmaxf(vmax, fabsf(val));
      }
    }
  }
  {
    float m = warpMax(vmax);
    if ((tid & 63) == 0) red[tid >> 6] = m;
    __syncthreads();
    if (tid == 0) {
      float r = fmaxf(fmaxf(red[0], red[1]), fmaxf(red[2], red[3]));
      atomicMax(sc + slotO * 16 + ((blockIdx.x + blockIdx.y) & 15), __float_as_uint(r));
    }
  }
}

// ---------------------------------------------------------------------------
// k_vt: per (b,h), transpose V codes -> VT8[bh][64][400] + colsumV.
// ---------------------------------------------------------------------------
__global__ __launch_bounds__(256) void k_vt(const signed char* __restrict__ qkv8,
                                            signed char* __restrict__ vt8,
                                            int* __restrict__ colsum) {
  __shared__ __align__(16) signed char T[64 * 80];
  __shared__ int cs[64];
  const int tid = threadIdx.x;
  const int bh = blockIdx.x, b = bh / 3, hh = bh % 3;
  const signed char* vb = qkv8 + (long)b * 400 * 576 + hh * 64 + 384;
  if (tid < 64) cs[tid] = 0;
  const int d = tid >> 2, seg = tid & 3;
  for (int c0 = 0; c0 < 448; c0 += 64) {
    __syncthreads();
    {
      int trow = tid >> 2, c = tid & 3;
      int4 v = make_int4(0, 0, 0, 0);
      if (c0 + trow < 400) v = *(const int4*)(vb + (long)(c0 + trow) * 576 + c * 16);
      *(int4*)&T[trow * 80 + c * 16] = v;
    }
    __syncthreads();
    int4 outw;
    int ssum = 0;
    u32 pk[4];
#pragma unroll
    for (int j = 0; j < 4; ++j) {
      u32 p = 0;
#pragma unroll
      for (int e = 0; e < 4; ++e) {
        int t = seg * 16 + j * 4 + e;
        int v = (int)T[t * 80 + d];
        ssum += v;
        p |= ((u32)(v & 0xff)) << (8 * e);
      }
      pk[j] = p;
    }
    outw.x = (int)pk[0]; outw.y = (int)pk[1]; outw.z = (int)pk[2]; outw.w = (int)pk[3];
    if (c0 + seg * 16 < 400)
      *(int4*)&vt8[(long)bh * 25600 + d * 400 + c0 + seg * 16] = outw;
    atomicAdd(&cs[d], ssum);
  }
  __syncthreads();
  if (tid < 64) colsum[bh * 64 + tid] = cs[tid];
}

// ---------------------------------------------------------------------------
// Attention, i8 MFMA, transposed scores, 128 q rows per block (2 q-halves
// share every K/V load). Grid 3072, XCD-chunked: tile = vid&3, bh = vid>>2.
// ---------------------------------------------------------------------------
__device__ __forceinline__ void attn_swz(int& tile, int& bh) {
  int bid = blockIdx.x;
  int vid = (bid & 7) * ((int)gridDim.x >> 3) + (bid >> 3);
  tile = vid & 3;
  bh = vid >> 2;
}

__global__ __launch_bounds__(256) void k_attn0(const signed char* __restrict__ qkv8,
                                               int* __restrict__ gmInt, u32* __restrict__ sc,
                                               int slotQ, int slotSc) {
  __shared__ float red[4];
  const int tid = threadIdx.x;
  int tile, bh;
  attn_swz(tile, bh);
  const int r0 = tile * 128;
  const int b = bh / 3, hh = bh % 3;
  const signed char* qb = qkv8 + (long)b * 400 * 576 + hh * 64;
  const signed char* kb = qb + 192;
  const float sQ = read_max16(sc, slotQ) / 127.0f + 1e-8f;
  const float sK = read_max16(sc, slotQ + 1) / 127.0f + 1e-8f;
  const float sSc = sQ * sK * 0.125f;

  const int lane = tid & 63, w = tid >> 6, fr = lane & 15, fk = lane >> 4;
  const int qloc = 16 * w + fr;
  const int gq0 = r0 + qloc, gq1 = gq0 + 64;
  const bool qv0 = gq0 < 400, qv1 = gq1 < 400;
  int4v qf0 = *(const int4v*)(qb + (long)gq0 * 576 + fk * 16);
  int4v qf1 = *(const int4v*)(qb + (long)gq1 * 576 + fk * 16);

  int aim = 0;
  int rim0 = -(1 << 30), rim1 = -(1 << 30);
  for (int c0 = 0; c0 < 400; c0 += 128) {
#pragma unroll
    for (int tf = 0; tf < 8; ++tf) {
      int4v kf = *(const int4v*)(kb + (long)(c0 + tf * 16 + fr) * 576 + fk * 16);
      int4v s0 = MFMA_I8(kf, qf0, ((int4v){0, 0, 0, 0}));
      int4v s1 = MFMA_I8(kf, qf1, ((int4v){0, 0, 0, 0}));
      const bool tv = (c0 + tf * 16 + fk * 4) < 400;
      if (tv) {
#pragma unroll
        for (int r = 0; r < 4; ++r) {
          if (qv0) {
            int sv = s0[r];
            aim = max(aim, max(sv, -sv));
            rim0 = max(rim0, sv);
          }
          if (qv1) {
            int sv = s1[r];
            aim = max(aim, max(sv, -sv));
            rim1 = max(rim1, sv);
          }
        }
      }
    }
  }
  rim0 = max(rim0, __shfl_xor(rim0, 16));
  rim0 = max(rim0, __shfl_xor(rim0, 32));
  rim1 = max(rim1, __shfl_xor(rim1, 16));
  rim1 = max(rim1, __shfl_xor(rim1, 32));
  if (fk == 0) {
    if (qv0) gmInt[(long)bh * 400 + gq0] = rim0;
    if (qv1) gmInt[(long)bh * 400 + gq1] = rim1;
  }
  float m = warpMax((float)aim * sSc);
  if (lane == 0) red[w] = m;
  __syncthreads();
  if (tid == 0) {
    float r = fmaxf(fmaxf(red[0], red[1]), fmaxf(red[2], red[3]));
    atomicMax(sc + slotSc * 16 + (blockIdx.x & 15), __float_as_uint(r));
  }
}

__global__ __launch_bounds__(256) void k_attn1(const signed char* __restrict__ qkv8,
                                               float* __restrict__ gm, float* __restrict__ gl,
                                               const int* __restrict__ gmInt,
                                               u32* __restrict__ sc, int slotQ, int slotSc,
                                               int slotPr) {
  __shared__ float red[4];
  const int tid = threadIdx.x;
  int tile, bh;
  attn_swz(tile, bh);
  const int r0 = tile * 128;
  const int b = bh / 3, hh = bh % 3;
  const signed char* qb = qkv8 + (long)b * 400 * 576 + hh * 64;
  const signed char* kb = qb + 192;
  const float sQ = read_max16(sc, slotQ) / 127.0f + 1e-8f;
  const float sK = read_max16(sc, slotQ + 1) / 127.0f + 1e-8f;
  const float sSc = sQ * sK * 0.125f;
  const float sS = read_max16(sc, slotSc) / 127.0f + 1e-8f;
  const float c1 = sSc / sS;
  const float c2 = sS * LOG2E;

  const int lane = tid & 63, w = tid >> 6, fr = lane & 15, fk = lane >> 4;
  const int qloc = 16 * w + fr;
  const int gq0 = r0 + qloc, gq1 = gq0 + 64;
  const int gqc0 = (gq0 > 399) ? 399 : gq0;
  const int gqc1 = (gq1 > 399) ? 399 : gq1;
  int4v qf0 = *(const int4v*)(qb + (long)gq0 * 576 + fk * 16);
  int4v qf1 = *(const int4v*)(qb + (long)gq1 * 576 + fk * 16);

  const float cm0 = fminf(fmaxf(rintf((float)gmInt[(long)bh * 400 + gqc0] * c1), -128.f), 127.f);
  const float cm1 = fminf(fmaxf(rintf((float)gmInt[(long)bh * 400 + gqc1] * c1), -128.f), 127.f);

  float sum0 = 0.f, sum1 = 0.f;
  for (int c0 = 0; c0 < 400; c0 += 128) {
#pragma unroll
    for (int tf = 0; tf < 8; ++tf) {
      int4v kf = *(const int4v*)(kb + (long)(c0 + tf * 16 + fr) * 576 + fk * 16);
      int4v s0 = MFMA_I8(kf, qf0, ((int4v){0, 0, 0, 0}));
      int4v s1 = MFMA_I8(kf, qf1, ((int4v){0, 0, 0, 0}));
      if ((c0 + tf * 16 + fk * 4) < 400) {
#pragma unroll
        for (int r = 0; r < 4; ++r) {
          float cf0 = fminf(fmaxf(rintf((float)s0[r] * c1), -128.f), 127.f);
          sum0 += exp2f((cf0 - cm0) * c2);
          float cf1 = fminf(fmaxf(rintf((float)s1[r] * c1), -128.f), 127.f);
          sum1 += exp2f((cf1 - cm1) * c2);
        }
      }
    }
  }
  sum0 += __shfl_xor(sum0, 16);
  sum0 += __shfl_xor(sum0, 32);
  sum1 += __shfl_xor(sum1, 16);
  sum1 += __shfl_xor(sum1, 32);
  float cand = 0.f;
  if (fk == 0) {
    if (gq0 < 400) {
      gm[(long)bh * 400 + gq0] = cm0;
      gl[(long)bh * 400 + gq0] = sum0;
      cand = fmaxf(cand, 1.0f / sum0);
    }
    if (gq1 < 400) {
      gm[(long)bh * 400 + gq1] = cm1;
      gl[(long)bh * 400 + gq1] = sum1;
      cand = fmaxf(cand, 1.0f / sum1);
    }
  }
  float m = warpMax(cand);
  if (lane == 0) red[w] = m;
  __syncthreads();
  if (tid == 0) {
    float r = fmaxf(fmaxf(red[0], red[1]), fmaxf(red[2], red[3]));
    atomicMax(sc + slotPr * 16 + (blockIdx.x & 15), __float_as_uint(r));
  }
}

__global__ __launch_bounds__(256) void k_attn_pv(
    const signed char* __restrict__ qkv8, const signed char* __restrict__ vt8,
    const int* __restrict__ colsumV, float* __restrict__ ctx, const float* __restrict__ gm,
    const float* __restrict__ gl, u32* __restrict__ sc, int slotQ, int slotSc, int slotPr,
    int slotCtx) {
  __shared__ __align__(16) signed char Ps[128 * 144];
  __shared__ int colsV[64];
  __shared__ float red[4];
  const int tid = threadIdx.x;
  int tile, bh;
  attn_swz(tile, bh);
  const int r0 = tile * 128;
  const int b = bh / 3, hh = bh % 3;
  const signed char* qb = qkv8 + (long)b * 400 * 576 + hh * 64;
  const signed char* kb = qb + 192;
  const signed char* vtb = vt8 + (long)bh * 25600;
  const float sQ = read_max16(sc, slotQ) / 127.0f + 1e-8f;
  const float sK = read_max16(sc, slotQ + 1) / 127.0f + 1e-8f;
  const float sV = read_max16(sc, slotQ + 2) / 127.0f + 1e-8f;
  const float sSc = sQ * sK * 0.125f;
  const float sS = read_max16(sc, slotSc) / 127.0f + 1e-8f;
  const float sP = read_max16(sc, slotPr) / 255.0f + 1e-8f;
  const float sPV = sP * sV;
  const float c1 = sSc / sS;
  const float c2 = sS * LOG2E;

  if (tid < 64) colsV[tid] = colsumV[bh * 64 + tid];
  const int lane = tid & 63, w = tid >> 6, fr = lane & 15, fk = lane >> 4;
  const int qloc = 16 * w + fr;
  const int gq0r = r0 + qloc, gq1r = gq0r + 64;
  int4v qf0 = *(const int4v*)(qb + (long)gq0r * 576 + fk * 16);
  int4v qf1 = *(const int4v*)(qb + (long)gq1r * 576 + fk * 16);

  const int gq0 = (gq0r > 399) ? 399 : gq0r;
  const int gq1 = (gq1r > 399) ? 399 : gq1r;
  const float cm0 = gm[(long)bh * 400 + gq0];
  const float invLsp0 = 1.0f / (gl[(long)bh * 400 + gq0] * sP);
  const float cm1 = gm[(long)bh * 400 + gq1];
  const float invLsp1 = 1.0f / (gl[(long)bh * 400 + gq1] * sP);

  int4v accd0[4], accd1[4];
#pragma unroll
  for (int dt = 0; dt < 4; ++dt) {
    accd0[dt] = (int4v){0, 0, 0, 0};
    accd1[dt] = (int4v){0, 0, 0, 0};
  }
  __syncthreads();

  for (int c0 = 0; c0 < 400; c0 += 128) {
#pragma unroll
    for (int tf = 0; tf < 8; ++tf) {
      int4v kf = *(const int4v*)(kb + (long)(c0 + tf * 16 + fr) * 576 + fk * 16);
      int4v s0 = MFMA_I8(kf, qf0, ((int4v){0, 0, 0, 0}));
      int4v s1 = MFMA_I8(kf, qf1, ((int4v){0, 0, 0, 0}));
      const int tbase = c0 + tf * 16 + fk * 4;
      u32 pack0 = 0, pack1 = 0;
      if (tbase < 400) {
#pragma unroll
        for (int r = 0; r < 4; ++r) {
          float cf0 = fminf(fmaxf(rintf((float)s0[r] * c1), -128.f), 127.f);
          float e0 = exp2f((cf0 - cm0) * c2);
          float pu0 = fminf(fmaxf(rintf(e0 * invLsp0), 0.f), 255.f);
          pack0 |= ((u32)(((int)pu0 - 128) & 0xff)) << (8 * r);
          float cf1 = fminf(fmaxf(rintf((float)s1[r] * c1), -128.f), 127.f);
          float e1 = exp2f((cf1 - cm1) * c2);
          float pu1 = fminf(fmaxf(rintf(e1 * invLsp1), 0.f), 255.f);
          pack1 |= ((u32)(((int)pu1 - 128) & 0xff)) << (8 * r);
        }
      }
      *(u32*)&Ps[qloc * 144 + tf * 16 + fk * 4] = pack0;
      *(u32*)&Ps[(qloc + 64) * 144 + tf * 16 + fk * 4] = pack1;
    }
    __syncthreads();
    int4v pf00 = *(const int4v*)&Ps[qloc * 144 + fk * 16];
    int4v pf01 = *(const int4v*)&Ps[qloc * 144 + 64 + fk * 16];
    int4v pf10 = *(const int4v*)&Ps[(qloc + 64) * 144 + fk * 16];
    int4v pf11 = *(const int4v*)&Ps[(qloc + 64) * 144 + 64 + fk * 16];
    const bool v0ok = (c0 + fk * 16) < 400;
    const bool v1ok = (c0 + 64 + fk * 16) < 400;
#pragma unroll
    for (int dt = 0; dt < 4; ++dt) {
      const long vrow = (long)(dt * 16 + fr) * 400;
      int4v vf0 = v0ok ? *(const int4v*)(vtb + vrow + c0 + fk * 16) : (int4v){0, 0, 0, 0};
      int4v vf1 = v1ok ? *(const int4v*)(vtb + vrow + c0 + 64 + fk * 16) : (int4v){0, 0, 0, 0};
      accd0[dt] = MFMA_I8(vf0, pf00, accd0[dt]);
      accd0[dt] = MFMA_I8(vf1, pf01, accd0[dt]);
      accd1[dt] = MFMA_I8(vf0, pf10, accd1[dt]);
      accd1[dt] = MFMA_I8(vf1, pf11, accd1[dt]);
    }
    __syncthreads();
  }
  float vmax = 0.f;
  if (gq0r < 400) {
#pragma unroll
    for (int dt = 0; dt < 4; ++dt) {
      const int d0 = dt * 16 + fk * 4;
      float4 o;
      o.x = sPV * (float)(accd0[dt][0] + 128 * colsV[d0 + 0]);
      o.y = sPV * (float)(accd0[dt][1] + 128 * colsV[d0 + 1]);
      o.z = sPV * (float)(accd0[dt][2] + 128 * colsV[d0 + 2]);
      o.w = sPV * (float)(accd0[dt][3] + 128 * colsV[d0 + 3]);
      vmax = fmaxf(vmax, fmaxf(fmaxf(fabsf(o.x), fabsf(o.y)), fmaxf(fabsf(o.z), fabsf(o.w))));
      *(float4*)&ctx[(long)(b * 400 + gq0r) * 192 + hh * 64 + d0] = o;
    }
  }
  if (gq1r < 400) {
#pragma unroll
    for (int dt = 0; dt < 4; ++dt) {
      const int d0 = dt * 16 + fk * 4;
      float4 o;
      o.x = sPV * (float)(accd1[dt][0] + 128 * colsV[d0 + 0]);
      o.y = sPV * (float)(accd1[dt][1] + 128 * colsV[d0 + 1]);
      o.z = sPV * (float)(accd1[dt][2] + 128 * colsV[d0 + 2]);
      o.w = sPV * (float)(accd1[dt][3] + 128 * colsV[d0 + 3]);
      vmax = fmaxf(vmax, fmaxf(fmaxf(fabsf(o.x), fabsf(o.y)), fmaxf(fabsf(o.z), fabsf(o.w))));
      *(float4*)&ctx[(long)(b * 400 + gq1r) * 192 + hh * 64 + d0] = o;
    }
  }
  float m = warpMax(vmax);
  if (lane == 0) red[w] = m;
  __syncthreads();
  if (tid == 0) {
    float r = fmaxf(fmaxf(red[0], red[1]), fmaxf(red[2], red[3]));
    atomicMax(sc + slotCtx * 16 + (blockIdx.x & 15), __float_as_uint(r));
  }
}

// ---------------------------------------------------------------------------
__global__ __launch_bounds__(192) void k_pool(const float* __restrict__ xln,
                                              float* __restrict__ pooled,
                                              u32* __restrict__ slot) {
  int b = blockIdx.x, d = threadIdx.x;
  float sum = 0.f;
  for (int s = 0; s < 400; ++s) sum += xln[((long)b * 400 + s) * 192 + d];
  float v = sum / 400.0f;
  pooled[(long)b * 192 + d] = v;
  __shared__ float red[3];
  float m = warpMax(fabsf(v));
  if ((d & 63) == 0) red[d >> 6] = m;
  __syncthreads();
  if (d == 0)
    atomicMax(slot + (b & 15), __float_as_uint(fmaxf(fmaxf(red[0], red[1]), red[2])));
}

__global__ __launch_bounds__(64) void k_logits(const float* __restrict__ pooled,
                                               const float* __restrict__ clfq,
                                               const float* __restrict__ clfb,
                                               const u32* __restrict__ sc,
                                               float* __restrict__ out) {
  int c = blockIdx.x, b = blockIdx.y, lane = threadIdx.x;
  float sp = read_max16(sc, SLOT_POOL) / 127.0f + 1e-8f;
  float acc = 0.f;
#pragma unroll
  for (int j = 0; j < 3; ++j) {
    int d = lane + 64 * j;
    acc += fqs(pooled[(long)b * 192 + d], sp) * clfq[c * 192 + d];
  }
#pragma unroll
  for (int o = 32; o > 0; o >>= 1) acc += __shfl_down(acc, o);
  if (lane == 0) out[b * 7 + c] = acc + clfb[c];
}

// ---------------------------------------------------------------------------
// host
// ---------------------------------------------------------------------------
static inline int gsz(long n4, long cap) {
  long g = (n4 + 255) / 256;
  return (int)(g < cap ? g : cap);
}

extern "C" void kernel_launch(void* const* d_in, const int* in_sizes, int n_in,
                              void* d_out, int out_size, void* d_ws, size_t ws_size,
                              hipStream_t stream) {
  (void)in_sizes; (void)n_in; (void)out_size; (void)ws_size;

  const float* x = (const float*)d_in[0];
  const float* pw = (const float*)d_in[1];
  const float* pb = (const float*)d_in[2];
  const float* ln1g = (const float*)d_in[3];
  const float* ln1b = (const float*)d_in[4];
  const float* wqkv = (const float*)d_in[5];
  const float* bqkv = (const float*)d_in[6];
  const float* wo = (const float*)d_in[7];
  const float* bo = (const float*)d_in[8];
  const float* ln2g = (const float*)d_in[9];
  const float* ln2b = (const float*)d_in[10];
  const float* w1 = (const float*)d_in[11];
  const float* b1 = (const float*)d_in[12];
  const float* w2 = (const float*)d_in[13];
  const float* b2 = (const float*)d_in[14];
  const float* lnfg = (const float*)d_in[15];
  const float* lnfb = (const float*)d_in[16];
  const float* clfw = (const float*)d_in[17];
  const float* clfb = (const float*)d_in[18];

  float* ws = (float*)d_ws;
  u32* sc = (u32*)d_ws;
  float* GM = ws + OFF_GM;
  int* GMI = (int*)GM;
  float* GL = ws + OFF_GL;
  float* POOL = ws + OFF_POOL;
  float* PWQ = ws + OFF_PWQ;
  float* CLFQ = ws + OFF_CLFQ;
  float* H = ws + OFF_H;

  signed char* RA = (signed char*)(ws + OFF_A);
  signed char* RU = (signed char*)(ws + OFF_U);
  signed char* PLQ_H = RU;
  signed char* PLQ_L = RU + 19660800;
  float* PLQ_S = (float*)(RU + 39321600);
  signed char* QKV8 = RA;
  signed char* VT8 = RA + 58982400;
  float* CTXF = (float*)RU;
  signed char* CTX8 = RA;
  float* WOOUT = (float*)RU;
  signed char* PL2_H = RA;
  signed char* PL2_L = RA + 19660800;
  float* PL2_S = (float*)(RA + 39321600);
  signed char* GELU8 = RU;
  float* W2OUT = (float*)RA;
  float* FINALF = (float*)RU;

  int* COLSUM = (int*)POOL;
  signed char* WQC = (signed char*)POOL;
  signed char* WOC2 = (signed char*)POOL;
  signed char* W1C2 = (signed char*)POOL + 36864;
  signed char* W2C2 = (signed char*)POOL + 36864;
  float* out = (float*)d_out;

  k_zero<<<(N_SLOT_WORDS + 255) / 256, 256, 0, stream>>>(sc, N_SLOT_WORDS);

  auto amax = [&](const float* p, long n, int slot) {
    k_absmax<<<gsz(n / 4, 256), 256, 0, stream>>>((const float4*)p, n / 4, sc + slot * 16);
  };
  amax(pw, 3840, SLOT_PW);
  amax(clfw, 1344, SLOT_CLF);
  amax(x, 2048000, SLOT_X);
  for (int i = 0; i < NL; ++i) {
    int Lb = 16 + i * 16;
    amax(wqkv + (long)i * 110592, 110592, Lb + 0);
    amax(wo + (long)i * 36864, 36864, Lb + 1);
    amax(w1 + (long)i * 147456, 147456, Lb + 2);
    amax(w2 + (long)i * 147456, 147456, Lb + 3);
  }
  k_quant4<<<gsz(960, 256), 256, 0, stream>>>((const float4*)pw, (float4*)PWQ, 960, sc, SLOT_PW);
  k_quant4<<<gsz(336, 256), 256, 0, stream>>>((const float4*)clfw, (float4*)CLFQ, 336, sc,
                                              SLOT_CLF);

  // patch embed -> RU fp32; fused H = fq(emb) + first LN -> planes (RU head OK:
  // resln writes planes rows it already consumed... planes are in RU but raw
  // is also RU! Keep the safe split: emb lives in RU, planes must go elsewhere.
  // Use RA head for the first LN planes instead, then copy layout: simplest is
  // to write first planes into RA (dead), and layer 0 qkv reads planes from RA,
  // writes QKV8 into... conflict. To keep v16's proven region plan, do the
  // init without fusion into H only, then LN from H into RU planes after emb
  // region is dead.
  k_patch<<<12800, 192, 0, stream>>>(x, PWQ, pb, sc, (float*)RA, sc + SLOT_EMB * 16);
  k_resln<2, true><<<(int)(ROWS / 4), 256, 0, stream>>>(
      H, (const float*)RA, sc, SLOT_EMB, ln1g, ln1b, PLQ_H, PLQ_L, PLQ_S, nullptr, (int)ROWS);

  for (int i = 0; i < NL; ++i) {
    int Lb = 16 + i * 16;
    // --- attention ---
    k_wquant<<<108, 256, 0, stream>>>((const float4*)(wqkv + (long)i * 110592), (u32*)WQC,
                                      27648, sc, Lb + 0);
    k_gemm16<false, 1><<<2400, 256, 0, stream>>>(PLQ_H, PLQ_L, PLQ_S, WQC, Lb + 0,
                                                 bqkv + i * 576, nullptr, 576, 3, sc, Lb + 4,
                                                 192);
    k_gemm16<false, 2><<<2400, 256, 0, stream>>>(PLQ_H, PLQ_L, PLQ_S, WQC, Lb + 0,
                                                 bqkv + i * 576, QKV8, 576, 3, sc, Lb + 4,
                                                 192);
    k_vt<<<768, 256, 0, stream>>>(QKV8, VT8, COLSUM);
    k_attn0<<<3072, 256, 0, stream>>>(QKV8, GMI, sc, Lb + 4, Lb + 7);
    k_attn1<<<3072, 256, 0, stream>>>(QKV8, GM, GL, GMI, sc, Lb + 4, Lb + 7, Lb + 8);
    k_attn_pv<<<3072, 256, 0, stream>>>(QKV8, VT8, COLSUM, CTXF, GM, GL, sc, Lb + 4, Lb + 7,
                                        Lb + 8, Lb + 9);
    k_quant_codes<<<2048, 256, 0, stream>>>((const float4*)CTXF, (u32*)CTX8, 19660800 / 4, sc,
                                            Lb + 9);
    k_wquant<<<36, 256, 0, stream>>>((const float4*)(wo + (long)i * 36864), (u32*)WOC2, 9216,
                                     sc, Lb + 1);
    {
      dim3 g(1, 800);
      k_gemm8<<<g, 256, 0, stream>>>(CTX8, Lb + 9, WOC2, Lb + 1, bo + i * 192, WOOUT, 192, 192,
                                     sc, Lb + 10);
    }
    k_resln<1, true><<<(int)(ROWS / 4), 256, 0, stream>>>(
        H, WOOUT, sc, Lb + 10, ln2g + i * 192, ln2b + i * 192, PL2_H, PL2_L, PL2_S, nullptr,
        (int)ROWS);
    // --- MLP ---
    k_wquant<<<144, 256, 0, stream>>>((const float4*)(w1 + (long)i * 147456), (u32*)W1C2,
                                      36864, sc, Lb + 2);
    k_gemm16<true, 1><<<3200, 256, 0, stream>>>(PL2_H, PL2_L, PL2_S, W1C2, Lb + 2,
                                                b1 + i * 768, nullptr, 768, 4, sc, Lb + 11,
                                                768);
    k_gemm16<true, 2><<<3200, 256, 0, stream>>>(PL2_H, PL2_L, PL2_S, W1C2, Lb + 2,
                                                b1 + i * 768, GELU8, 768, 4, sc, Lb + 11, 768);
    k_wquant<<<144, 256, 0, stream>>>((const float4*)(w2 + (long)i * 147456), (u32*)W2C2,
                                      36864, sc, Lb + 3);
    {
      dim3 g(1, 800);
      k_gemm8<<<g, 256, 0, stream>>>(GELU8, Lb + 11, W2C2, Lb + 3, b2 + i * 192, W2OUT, 192,
                                     768, sc, Lb + 12);
    }
    if (i < NL - 1) {
      k_resln<1, true><<<(int)(ROWS / 4), 256, 0, stream>>>(
          H, W2OUT, sc, Lb + 12, ln1g + (i + 1) * 192, ln1b + (i + 1) * 192, PLQ_H, PLQ_L,
          PLQ_S, nullptr, (int)ROWS);
    } else {
      k_resln<1, false><<<(int)(ROWS / 4), 256, 0, stream>>>(
          H, W2OUT, sc, Lb + 12, lnfg, lnfb, nullptr, nullptr, nullptr, FINALF, (int)ROWS);
    }
  }

  // pool + classifier
  k_pool<<<256, 192, 0, stream>>>(FINALF, POOL, sc + SLOT_POOL * 16);
  {
    dim3 g(7, 256);
    k_logits<<<g, 64, 0, stream>>>(POOL, CLFQ, clfb, sc, out);
  }
}

// Round 18
// 5701.135 us; speedup vs baseline: 1.4339x; 1.0150x over previous
//
#include <hip/hip_runtime.h>
#include <math.h>

// ---------------------------------------------------------------------------
// TinyMyo 8ch/400tok quant transformer — v18: v17 + 32-row k_patch (weight
// stage amortized 4x) + gemm8 AFP32 mode (ctx quantization fused into wo GEMM,
// k_quant_codes deleted). Numerics element-identical to v17.
// ---------------------------------------------------------------------------

typedef unsigned int u32;
typedef unsigned short u16;
typedef __attribute__((ext_vector_type(4))) int int4v;

#define MFMA_I8(a, b, c) __builtin_amdgcn_mfma_i32_16x16x64_i8((a), (b), (c), 0, 0, 0)

constexpr int NL = 8;
constexpr long ROWS = 102400;  // B*SEQ
constexpr float LOG2E = 1.44269504088896340736f;

constexpr int SLOT_X = 0, SLOT_PW = 1, SLOT_EMB = 2, SLOT_CLF = 3, SLOT_POOL = 4;
constexpr int N_SLOT_WORDS = 200 * 16;

constexpr long OFF_GM = 3200;
constexpr long OFF_GL = OFF_GM + 307200;
constexpr long OFF_POOL = OFF_GL + 307200;
constexpr long OFF_PWQ = OFF_POOL + 49152;
constexpr long OFF_CLFQ = OFF_PWQ + 3840;
constexpr long OFF_H = OFF_CLFQ + 1344;
constexpr long OFF_A = OFF_H + 19660800;
constexpr long OFF_U = OFF_A + 19660800;

// ---------------------------------------------------------------------------
__device__ __forceinline__ float warpMax(float v) {
#pragma unroll
  for (int o = 32; o > 0; o >>= 1) v = fmaxf(v, __shfl_down(v, o));
  return v;
}

__device__ __forceinline__ float read_max16(const u32* sc, int slot) {
  const u32* p = sc + slot * 16;
  u32 m = 0;
#pragma unroll
  for (int i = 0; i < 16; ++i) m = max(m, p[i]);
  return __uint_as_float(m);
}

__device__ __forceinline__ float fqs(float x, float s) {
  return fminf(fmaxf(rintf(x / s), -128.0f), 127.0f) * s;
}

__device__ __forceinline__ u32 pack4(float4 v, float s) {
  int c0 = (int)fminf(fmaxf(rintf(v.x / s), -128.f), 127.f);
  int c1 = (int)fminf(fmaxf(rintf(v.y / s), -128.f), 127.f);
  int c2 = (int)fminf(fmaxf(rintf(v.z / s), -128.f), 127.f);
  int c3 = (int)fminf(fmaxf(rintf(v.w / s), -128.f), 127.f);
  return (u32)(c0 & 0xff) | ((u32)(c1 & 0xff) << 8) | ((u32)(c2 & 0xff) << 16) |
         ((u32)(c3 & 0xff) << 24);
}

// ---------------------------------------------------------------------------
__global__ void k_zero(u32* p, int n) {
  int i = blockIdx.x * blockDim.x + threadIdx.x;
  if (i < n) p[i] = 0u;
}

__global__ __launch_bounds__(256) void k_absmax(const float4* __restrict__ x, long n4,
                                                u32* __restrict__ slot) {
  float m = 0.f;
  for (long i = (long)blockIdx.x * blockDim.x + threadIdx.x; i < n4;
       i += (long)gridDim.x * blockDim.x) {
    float4 v = x[i];
    m = fmaxf(m, fmaxf(fmaxf(fabsf(v.x), fabsf(v.y)), fmaxf(fabsf(v.z), fabsf(v.w))));
  }
  __shared__ float red[4];
  m = warpMax(m);
  int lane = threadIdx.x & 63, w = threadIdx.x >> 6;
  if (lane == 0) red[w] = m;
  __syncthreads();
  if (threadIdx.x == 0) {
    float r = fmaxf(fmaxf(red[0], red[1]), fmaxf(red[2], red[3]));
    atomicMax(slot + (blockIdx.x & 15), __float_as_uint(r));
  }
}

__global__ __launch_bounds__(256) void k_quant4(const float4* __restrict__ in,
                                                float4* __restrict__ out, long n4,
                                                const u32* __restrict__ sc, int slot) {
  float s = read_max16(sc, slot) / 127.0f + 1e-8f;
  for (long i = (long)blockIdx.x * blockDim.x + threadIdx.x; i < n4;
       i += (long)gridDim.x * blockDim.x) {
    float4 v = in[i];
    v.x = fqs(v.x, s); v.y = fqs(v.y, s); v.z = fqs(v.z, s); v.w = fqs(v.w, s);
    out[i] = v;
  }
}

// ---------------------------------------------------------------------------
// patch embed: 32 rows/block, weights staged once.
// ---------------------------------------------------------------------------
__global__ __launch_bounds__(192) void k_patch(const float* __restrict__ x,
                                               const float* __restrict__ pwq,
                                               const float* __restrict__ pb,
                                               const u32* __restrict__ sc,
                                               float* __restrict__ emb,
                                               u32* __restrict__ embSlot) {
  __shared__ float wsm[3840];
  __shared__ float xq[160];
  __shared__ float eout[1536];
  __shared__ float red[3];
  const int tid = threadIdx.x;
  const long rowBase = (long)blockIdx.x * 32;
  const float sx = read_max16(sc, SLOT_X) / 127.0f + 1e-8f;
#pragma unroll
  for (int j = 0; j < 5; ++j)
    ((float4*)wsm)[j * 192 + tid] = ((const float4*)pwq)[j * 192 + tid];
  __syncthreads();
  float wreg[20];
#pragma unroll
  for (int k = 0; k < 20; ++k) wreg[k] = wsm[tid * 20 + k];
  const float bias = pb[tid];
  float m = 0.f;
#pragma unroll 1
  for (int chunk = 0; chunk < 4; ++chunk) {
    const long rb = rowBase + chunk * 8;
    __syncthreads();
    if (tid < 40) {
      float4 v = ((const float4*)(x + rb * 20))[tid];
      v.x = fqs(v.x, sx); v.y = fqs(v.y, sx); v.z = fqs(v.z, sx); v.w = fqs(v.w, sx);
      ((float4*)xq)[tid] = v;
    }
    __syncthreads();
#pragma unroll
    for (int r = 0; r < 8; ++r) {
      float acc = bias;
#pragma unroll
      for (int k = 0; k < 20; ++k) acc += xq[r * 20 + k] * wreg[k];
      eout[r * 192 + tid] = acc;
      m = fmaxf(m, fabsf(acc));
    }
    __syncthreads();
    float4* emb4 = (float4*)(emb + rb * 192);
    emb4[tid] = ((const float4*)eout)[tid];
    emb4[tid + 192] = ((const float4*)eout)[tid + 192];
  }
  m = warpMax(m);
  if ((tid & 63) == 0) red[tid >> 6] = m;
  __syncthreads();
  if (tid == 0)
    atomicMax(embSlot + (blockIdx.x & 15),
              __float_as_uint(fmaxf(fmaxf(red[0], red[1]), red[2])));
}

// ---------------------------------------------------------------------------
// Fused residual/init + LayerNorm. MODE: 0 = LN(H); 1 = H += fq(raw) then LN;
// 2 = H = fq(raw) then LN.  I16: planes + row scale; else fp32 out (yf).
// ---------------------------------------------------------------------------
template <int MODE, bool I16>
__global__ __launch_bounds__(256) void k_resln(float* __restrict__ H,
                                               const float* __restrict__ raw,
                                               const u32* __restrict__ sc, int slotRes,
                                               const float* __restrict__ g,
                                               const float* __restrict__ bta,
                                               signed char* __restrict__ yh,
                                               signed char* __restrict__ yl,
                                               float* __restrict__ sArow,
                                               float* __restrict__ yf, int rows) {
  int w = threadIdx.x >> 6, lane = threadIdx.x & 63;
  long row = (long)blockIdx.x * 4 + w;
  if (row >= rows) return;
  const bool act = lane < 48;
  float4 v = make_float4(0.f, 0.f, 0.f, 0.f);
  if (MODE == 0 || MODE == 1) {
    if (act) v = ((const float4*)(H + row * 192))[lane];
  }
  if (MODE == 1 || MODE == 2) {
    float sres = read_max16(sc, slotRes) / 127.0f + 1e-8f;
    if (act) {
      float4 r4 = ((const float4*)(raw + row * 192))[lane];
      v.x += fqs(r4.x, sres); v.y += fqs(r4.y, sres);
      v.z += fqs(r4.z, sres); v.w += fqs(r4.w, sres);
      ((float4*)(H + row * 192))[lane] = v;
    }
  }
  float s = v.x + v.y + v.z + v.w;
#pragma unroll
  for (int o = 32; o > 0; o >>= 1) s += __shfl_down(s, o);
  s = __shfl(s, 0);
  float mean = s / 192.0f;
  float d0 = v.x - mean, d1 = v.y - mean, d2 = v.z - mean, d3 = v.w - mean;
  float q = act ? (d0 * d0 + d1 * d1 + d2 * d2 + d3 * d3) : 0.f;
#pragma unroll
  for (int o = 32; o > 0; o >>= 1) q += __shfl_down(q, o);
  q = __shfl(q, 0);
  float rs = 1.0f / sqrtf(q / 192.0f + 1e-5f);
  float4 gv = make_float4(0.f, 0.f, 0.f, 0.f), bv = gv;
  if (act) {
    gv = ((const float4*)g)[lane];
    bv = ((const float4*)bta)[lane];
  }
  float o0 = d0 * rs * gv.x + bv.x;
  float o1 = d1 * rs * gv.y + bv.y;
  float o2 = d2 * rs * gv.z + bv.z;
  float o3 = d3 * rs * gv.w + bv.w;
  if (I16) {
    float rm = act ? fmaxf(fmaxf(fabsf(o0), fabsf(o1)), fmaxf(fabsf(o2), fabsf(o3))) : 0.f;
#pragma unroll
    for (int o = 32; o > 0; o >>= 1) rm = fmaxf(rm, __shfl_down(rm, o));
    rm = __shfl(rm, 0);
    float sA = rm / 32512.0f + 1e-20f;
    float inv = 1.0f / sA;
    if (act) {
      int c0 = (int)rintf(o0 * inv), c1 = (int)rintf(o1 * inv);
      int c2 = (int)rintf(o2 * inv), c3 = (int)rintf(o3 * inv);
      int h0 = (c0 + 128) >> 8, h1 = (c1 + 128) >> 8;
      int h2 = (c2 + 128) >> 8, h3 = (c3 + 128) >> 8;
      int l0 = c0 - (h0 << 8), l1 = c1 - (h1 << 8);
      int l2 = c2 - (h2 << 8), l3 = c3 - (h3 << 8);
      u32 hw = (u32)(h0 & 0xff) | ((u32)(h1 & 0xff) << 8) | ((u32)(h2 & 0xff) << 16) |
               ((u32)(h3 & 0xff) << 24);
      u32 lw = (u32)(l0 & 0xff) | ((u32)(l1 & 0xff) << 8) | ((u32)(l2 & 0xff) << 16) |
               ((u32)(l3 & 0xff) << 24);
      ((u32*)yh)[row * 48 + lane] = hw;
      ((u32*)yl)[row * 48 + lane] = lw;
    }
    if (lane == 0) sArow[row] = sA;
  } else {
    if (act) ((float4*)(yf + row * 192))[lane] = make_float4(o0, o1, o2, o3);
  }
}

// ---------------------------------------------------------------------------
__global__ __launch_bounds__(256) void k_wquant(const float4* __restrict__ w,
                                                u32* __restrict__ out, int n4,
                                                const u32* __restrict__ sc, int slot) {
  int i = blockIdx.x * blockDim.x + threadIdx.x;
  if (i >= n4) return;
  float s = read_max16(sc, slot) / 127.0f + 1e-8f;
  float4 v = w[i];
  out[i] = pack4(v, s);
}

// ---------------------------------------------------------------------------
// i16-A x i8-W GEMM. LDS B panel; row loop unroll 1.
// ---------------------------------------------------------------------------
template <bool GELU, int OM>
__global__ __launch_bounds__(256) void k_gemm16(
    const signed char* __restrict__ AH, const signed char* __restrict__ AL,
    const float* __restrict__ sArow, const signed char* __restrict__ W8, int slotW,
    const float* __restrict__ bias, signed char* __restrict__ C8, int N, int ncol,
    u32* __restrict__ sc, int slotO, int colsPerSlot) {
  __shared__ __align__(16) signed char Bs[192 * 208];
  __shared__ float red[4];
  const int tid = threadIdx.x;
  const int bid = blockIdx.x;
  const int vid = (bid & 7) * ((int)gridDim.x >> 3) + (bid >> 3);
  const int bx = vid % ncol;
  const long by = vid / ncol;
  const long rowBase = by * 128;
  const int colBase = bx * 192;
  const float sW = read_max16(sc, slotW) / 127.0f + 1e-8f;

  {
    const signed char* wp = W8 + (long)colBase * 192;
#pragma unroll
    for (int it = 0; it < 9; ++it) {
      int idx = it * 256 + tid;
      int row = idx / 12, c = idx % 12;
      int4 v = *(const int4*)(wp + (long)row * 192 + c * 16);
      *(int4*)&Bs[row * 208 + c * 16] = v;
    }
  }

  const int lane = tid & 63, w = tid >> 6;
  const int fr = lane & 15, fk = lane >> 4;
  const int wc0 = w * 48;

  float sOinv = 0.f;
  if (OM == 2) sOinv = 1.0f / (read_max16(sc, slotO + colBase / colsPerSlot) / 127.0f + 1e-8f);
  const float inv_sqrt2 = 0.70710678118654752440f;
  float vmax = 0.f;

  const long abase = (rowBase + fr) * 192 + fk * 16;
  __syncthreads();

#pragma unroll 1
  for (int it = 0; it < 8; ++it) {
    const long ab = abase + (long)it * 16 * 192;
    int4v ahc[3], alc[3];
#pragma unroll
    for (int kk = 0; kk < 3; ++kk) {
      ahc[kk] = *(const int4v*)(AH + ab + kk * 64);
      alc[kk] = *(const int4v*)(AL + ab + kk * 64);
    }
    int4v aH[3], aL[3];
#pragma unroll
    for (int n = 0; n < 3; ++n) {
      aH[n] = (int4v){0, 0, 0, 0};
      aL[n] = (int4v){0, 0, 0, 0};
    }
#pragma unroll
    for (int kk = 0; kk < 3; ++kk) {
#pragma unroll
      for (int n = 0; n < 3; ++n) {
        int4v bfr = *(const int4v*)&Bs[(wc0 + n * 16 + fr) * 208 + kk * 64 + fk * 16];
        aH[n] = MFMA_I8(ahc[kk], bfr, aH[n]);
        aL[n] = MFMA_I8(alc[kk], bfr, aL[n]);
      }
    }
    const long rt = rowBase + it * 16;
    float4 sA4 = *(const float4*)&sArow[rt + fk * 4];
    float sAr[4] = {sA4.x, sA4.y, sA4.z, sA4.w};
#pragma unroll
    for (int n = 0; n < 3; ++n) {
      const int col = colBase + wc0 + n * 16 + fr;
      const float bb = bias[col];
#pragma unroll
      for (int r = 0; r < 4; ++r) {
        const int R = (aH[n][r] << 8) + aL[n][r];
        float val = (float)R * (sAr[r] * sW) + bb;
        if (GELU) val = 0.5f * val * (1.0f + erff(val * inv_sqrt2));
        if (OM == 2) {
          float code = fminf(fmaxf(rintf(val * sOinv), -128.f), 127.f);
          C8[(rt + fk * 4 + r) * N + col] = (signed char)code;
        } else {
          vmax = fmaxf(vmax, fabsf(val));
        }
      }
    }
  }

  if (OM == 1) {
    float m = warpMax(vmax);
    if ((tid & 63) == 0) red[tid >> 6] = m;
    __syncthreads();
    if (tid == 0) {
      float r = fmaxf(fmaxf(red[0], red[1]), fmaxf(red[2], red[3]));
      atomicMax(sc + (slotO + colBase / colsPerSlot) * 16 + ((int)(bx + by) & 15),
                __float_as_uint(r));
    }
  }
}

// ---------------------------------------------------------------------------
// i8-MFMA GEMM. AFP32: A is fp32, quantized inline with slotA scale
// (bit-identical to the old quant_codes pass). Single pass: fp32 out + absmax.
// A and C may alias the same region -> __syncthreads before epilogue.
// ---------------------------------------------------------------------------
template <bool AFP32>
__global__ __launch_bounds__(256) void k_gemm8(
    const signed char* __restrict__ A8, const float* __restrict__ Af, int slotA,
    const signed char* __restrict__ W8, int slotW, const float* __restrict__ bias,
    float* __restrict__ C, int N, int K, u32* __restrict__ sc, int slotO) {
  __shared__ float red[4];
  const int tid = threadIdx.x;
  const long rowBase = (long)blockIdx.y * 128;
  const int colBase = blockIdx.x * 192;
  const float sAq = read_max16(sc, slotA) / 127.0f + 1e-8f;
  const float alpha = sAq * (read_max16(sc, slotW) / 127.0f + 1e-8f);

  const int lane = tid & 63, wv = tid >> 6;
  const int wm = wv >> 1, wn = wv & 1;
  const int fr = lane & 15, fk = lane >> 4;

  int4v acc[4][6];
#pragma unroll
  for (int m = 0; m < 4; ++m)
#pragma unroll
    for (int n = 0; n < 6; ++n) acc[m][n] = (int4v){0, 0, 0, 0};

  const long arow0 = rowBase + wm * 64;
  const int bcol0 = colBase + wn * 96;

  for (int k0 = 0; k0 < K; k0 += 64) {
    const int ko = k0 + fk * 16;
    int4v bfr[6];
#pragma unroll
    for (int n = 0; n < 6; ++n)
      bfr[n] = *(const int4v*)(W8 + (long)(bcol0 + n * 16 + fr) * K + ko);
#pragma unroll
    for (int m = 0; m < 4; ++m) {
      int4v af;
      if (AFP32) {
        const float* ap = Af + (arow0 + m * 16 + fr) * (long)K + ko;
        float4 a0 = *(const float4*)ap;
        float4 a1 = *(const float4*)(ap + 4);
        float4 a2 = *(const float4*)(ap + 8);
        float4 a3 = *(const float4*)(ap + 12);
        af[0] = (int)pack4(a0, sAq);
        af[1] = (int)pack4(a1, sAq);
        af[2] = (int)pack4(a2, sAq);
        af[3] = (int)pack4(a3, sAq);
      } else {
        af = *(const int4v*)(A8 + (arow0 + m * 16 + fr) * (long)K + ko);
      }
#pragma unroll
      for (int n = 0; n < 6; ++n) acc[m][n] = MFMA_I8(af, bfr[n], acc[m][n]);
    }
  }

  __syncthreads();  // A/C may alias (AFP32 wo path): drain all A reads first

  float vmax = 0.f;
#pragma unroll
  for (int n = 0; n < 6; ++n) {
    const int col = colBase + wn * 96 + n * 16 + fr;
    const float bb = bias[col];
#pragma unroll
    for (int m = 0; m < 4; ++m) {
#pragma unroll
      for (int r = 0; r < 4; ++r) {
        const long row = rowBase + wm * 64 + m * 16 + fk * 4 + r;
        float val = (float)acc[m][n][r] * alpha + bb;
        C[row * N + col] = val;
        vmax = fmaxf(vmax, fabsf(val));
      }
    }
  }
  {
    float m = warpMax(vmax);
    if ((tid & 63) == 0) red[tid >> 6] = m;
    __syncthreads();
    if (tid == 0) {
      float r = fmaxf(fmaxf(red[0], red[1]), fmaxf(red[2], red[3]));
      atomicMax(sc + slotO * 16 + ((blockIdx.x + blockIdx.y) & 15), __float_as_uint(r));
    }
  }
}

// ---------------------------------------------------------------------------
// k_vt: per (b,h), transpose V codes -> VT8[bh][64][400] + colsumV.
// ---------------------------------------------------------------------------
__global__ __launch_bounds__(256) void k_vt(const signed char* __restrict__ qkv8,
                                            signed char* __restrict__ vt8,
                                            int* __restrict__ colsum) {
  __shared__ __align__(16) signed char T[64 * 80];
  __shared__ int cs[64];
  const int tid = threadIdx.x;
  const int bh = blockIdx.x, b = bh / 3, hh = bh % 3;
  const signed char* vb = qkv8 + (long)b * 400 * 576 + hh * 64 + 384;
  if (tid < 64) cs[tid] = 0;
  const int d = tid >> 2, seg = tid & 3;
  for (int c0 = 0; c0 < 448; c0 += 64) {
    __syncthreads();
    {
      int trow = tid >> 2, c = tid & 3;
      int4 v = make_int4(0, 0, 0, 0);
      if (c0 + trow < 400) v = *(const int4*)(vb + (long)(c0 + trow) * 576 + c * 16);
      *(int4*)&T[trow * 80 + c * 16] = v;
    }
    __syncthreads();
    int4 outw;
    int ssum = 0;
    u32 pk[4];
#pragma unroll
    for (int j = 0; j < 4; ++j) {
      u32 p = 0;
#pragma unroll
      for (int e = 0; e < 4; ++e) {
        int t = seg * 16 + j * 4 + e;
        int v = (int)T[t * 80 + d];
        ssum += v;
        p |= ((u32)(v & 0xff)) << (8 * e);
      }
      pk[j] = p;
    }
    outw.x = (int)pk[0]; outw.y = (int)pk[1]; outw.z = (int)pk[2]; outw.w = (int)pk[3];
    if (c0 + seg * 16 < 400)
      *(int4*)&vt8[(long)bh * 25600 + d * 400 + c0 + seg * 16] = outw;
    atomicAdd(&cs[d], ssum);
  }
  __syncthreads();
  if (tid < 64) colsum[bh * 64 + tid] = cs[tid];
}

// ---------------------------------------------------------------------------
// Attention, i8 MFMA, transposed scores, 128 q rows per block.
// Grid 3072, XCD-chunked: tile = vid&3, bh = vid>>2.
// ---------------------------------------------------------------------------
__device__ __forceinline__ void attn_swz(int& tile, int& bh) {
  int bid = blockIdx.x;
  int vid = (bid & 7) * ((int)gridDim.x >> 3) + (bid >> 3);
  tile = vid & 3;
  bh = vid >> 2;
}

__global__ __launch_bounds__(256) void k_attn0(const signed char* __restrict__ qkv8,
                                               int* __restrict__ gmInt, u32* __restrict__ sc,
                                               int slotQ, int slotSc) {
  __shared__ float red[4];
  const int tid = threadIdx.x;
  int tile, bh;
  attn_swz(tile, bh);
  const int r0 = tile * 128;
  const int b = bh / 3, hh = bh % 3;
  const signed char* qb = qkv8 + (long)b * 400 * 576 + hh * 64;
  const signed char* kb = qb + 192;
  const float sQ = read_max16(sc, slotQ) / 127.0f + 1e-8f;
  const float sK = read_max16(sc, slotQ + 1) / 127.0f + 1e-8f;
  const float sSc = sQ * sK * 0.125f;

  const int lane = tid & 63, w = tid >> 6, fr = lane & 15, fk = lane >> 4;
  const int qloc = 16 * w + fr;
  const int gq0 = r0 + qloc, gq1 = gq0 + 64;
  const bool qv0 = gq0 < 400, qv1 = gq1 < 400;
  int4v qf0 = *(const int4v*)(qb + (long)gq0 * 576 + fk * 16);
  int4v qf1 = *(const int4v*)(qb + (long)gq1 * 576 + fk * 16);

  int aim = 0;
  int rim0 = -(1 << 30), rim1 = -(1 << 30);
  for (int c0 = 0; c0 < 400; c0 += 128) {
#pragma unroll
    for (int tf = 0; tf < 8; ++tf) {
      int4v kf = *(const int4v*)(kb + (long)(c0 + tf * 16 + fr) * 576 + fk * 16);
      int4v s0 = MFMA_I8(kf, qf0, ((int4v){0, 0, 0, 0}));
      int4v s1 = MFMA_I8(kf, qf1, ((int4v){0, 0, 0, 0}));
      const bool tv = (c0 + tf * 16 + fk * 4) < 400;
      if (tv) {
#pragma unroll
        for (int r = 0; r < 4; ++r) {
          if (qv0) {
            int sv = s0[r];
            aim = max(aim, max(sv, -sv));
            rim0 = max(rim0, sv);
          }
          if (qv1) {
            int sv = s1[r];
            aim = max(aim, max(sv, -sv));
            rim1 = max(rim1, sv);
          }
        }
      }
    }
  }
  rim0 = max(rim0, __shfl_xor(rim0, 16));
  rim0 = max(rim0, __shfl_xor(rim0, 32));
  rim1 = max(rim1, __shfl_xor(rim1, 16));
  rim1 = max(rim1, __shfl_xor(rim1, 32));
  if (fk == 0) {
    if (qv0) gmInt[(long)bh * 400 + gq0] = rim0;
    if (qv1) gmInt[(long)bh * 400 + gq1] = rim1;
  }
  float m = warpMax((float)aim * sSc);
  if (lane == 0) red[w] = m;
  __syncthreads();
  if (tid == 0) {
    float r = fmaxf(fmaxf(red[0], red[1]), fmaxf(red[2], red[3]));
    atomicMax(sc + slotSc * 16 + (blockIdx.x & 15), __float_as_uint(r));
  }
}

__global__ __launch_bounds__(256) void k_attn1(const signed char* __restrict__ qkv8,
                                               float* __restrict__ gm, float* __restrict__ gl,
                                               const int* __restrict__ gmInt,
                                               u32* __restrict__ sc, int slotQ, int slotSc,
                                               int slotPr) {
  __shared__ float red[4];
  const int tid = threadIdx.x;
  int tile, bh;
  attn_swz(tile, bh);
  const int r0 = tile * 128;
  const int b = bh / 3, hh = bh % 3;
  const signed char* qb = qkv8 + (long)b * 400 * 576 + hh * 64;
  const signed char* kb = qb + 192;
  const float sQ = read_max16(sc, slotQ) / 127.0f + 1e-8f;
  const float sK = read_max16(sc, slotQ + 1) / 127.0f + 1e-8f;
  const float sSc = sQ * sK * 0.125f;
  const float sS = read_max16(sc, slotSc) / 127.0f + 1e-8f;
  const float c1 = sSc / sS;
  const float c2 = sS * LOG2E;

  const int lane = tid & 63, w = tid >> 6, fr = lane & 15, fk = lane >> 4;
  const int qloc = 16 * w + fr;
  const int gq0 = r0 + qloc, gq1 = gq0 + 64;
  const int gqc0 = (gq0 > 399) ? 399 : gq0;
  const int gqc1 = (gq1 > 399) ? 399 : gq1;
  int4v qf0 = *(const int4v*)(qb + (long)gq0 * 576 + fk * 16);
  int4v qf1 = *(const int4v*)(qb + (long)gq1 * 576 + fk * 16);

  const float cm0 = fminf(fmaxf(rintf((float)gmInt[(long)bh * 400 + gqc0] * c1), -128.f), 127.f);
  const float cm1 = fminf(fmaxf(rintf((float)gmInt[(long)bh * 400 + gqc1] * c1), -128.f), 127.f);

  float sum0 = 0.f, sum1 = 0.f;
  for (int c0 = 0; c0 < 400; c0 += 128) {
#pragma unroll
    for (int tf = 0; tf < 8; ++tf) {
      int4v kf = *(const int4v*)(kb + (long)(c0 + tf * 16 + fr) * 576 + fk * 16);
      int4v s0 = MFMA_I8(kf, qf0, ((int4v){0, 0, 0, 0}));
      int4v s1 = MFMA_I8(kf, qf1, ((int4v){0, 0, 0, 0}));
      if ((c0 + tf * 16 + fk * 4) < 400) {
#pragma unroll
        for (int r = 0; r < 4; ++r) {
          float cf0 = fminf(fmaxf(rintf((float)s0[r] * c1), -128.f), 127.f);
          sum0 += exp2f((cf0 - cm0) * c2);
          float cf1 = fminf(fmaxf(rintf((float)s1[r] * c1), -128.f), 127.f);
          sum1 += exp2f((cf1 - cm1) * c2);
        }
      }
    }
  }
  sum0 += __shfl_xor(sum0, 16);
  sum0 += __shfl_xor(sum0, 32);
  sum1 += __shfl_xor(sum1, 16);
  sum1 += __shfl_xor(sum1, 32);
  float cand = 0.f;
  if (fk == 0) {
    if (gq0 < 400) {
      gm[(long)bh * 400 + gq0] = cm0;
      gl[(long)bh * 400 + gq0] = sum0;
      cand = fmaxf(cand, 1.0f / sum0);
    }
    if (gq1 < 400) {
      gm[(long)bh * 400 + gq1] = cm1;
      gl[(long)bh * 400 + gq1] = sum1;
      cand = fmaxf(cand, 1.0f / sum1);
    }
  }
  float m = warpMax(cand);
  if (lane == 0) red[w] = m;
  __syncthreads();
  if (tid == 0) {
    float r = fmaxf(fmaxf(red[0], red[1]), fmaxf(red[2], red[3]));
    atomicMax(sc + slotPr * 16 + (blockIdx.x & 15), __float_as_uint(r));
  }
}

__global__ __launch_bounds__(256) void k_attn_pv(
    const signed char* __restrict__ qkv8, const signed char* __restrict__ vt8,
    const int* __restrict__ colsumV, float* __restrict__ ctx, const float* __restrict__ gm,
    const float* __restrict__ gl, u32* __restrict__ sc, int slotQ, int slotSc, int slotPr,
    int slotCtx) {
  __shared__ __align__(16) signed char Ps[128 * 144];
  __shared__ int colsV[64];
  __shared__ float red[4];
  const int tid = threadIdx.x;
  int tile, bh;
  attn_swz(tile, bh);
  const int r0 = tile * 128;
  const int b = bh / 3, hh = bh % 3;
  const signed char* qb = qkv8 + (long)b * 400 * 576 + hh * 64;
  const signed char* kb = qb + 192;
  const signed char* vtb = vt8 + (long)bh * 25600;
  const float sQ = read_max16(sc, slotQ) / 127.0f + 1e-8f;
  const float sK = read_max16(sc, slotQ + 1) / 127.0f + 1e-8f;
  const float sV = read_max16(sc, slotQ + 2) / 127.0f + 1e-8f;
  const float sSc = sQ * sK * 0.125f;
  const float sS = read_max16(sc, slotSc) / 127.0f + 1e-8f;
  const float sP = read_max16(sc, slotPr) / 255.0f + 1e-8f;
  const float sPV = sP * sV;
  const float c1 = sSc / sS;
  const float c2 = sS * LOG2E;

  if (tid < 64) colsV[tid] = colsumV[bh * 64 + tid];
  const int lane = tid & 63, w = tid >> 6, fr = lane & 15, fk = lane >> 4;
  const int qloc = 16 * w + fr;
  const int gq0r = r0 + qloc, gq1r = gq0r + 64;
  int4v qf0 = *(const int4v*)(qb + (long)gq0r * 576 + fk * 16);
  int4v qf1 = *(const int4v*)(qb + (long)gq1r * 576 + fk * 16);

  const int gq0 = (gq0r > 399) ? 399 : gq0r;
  const int gq1 = (gq1r > 399) ? 399 : gq1r;
  const float cm0 = gm[(long)bh * 400 + gq0];
  const float invLsp0 = 1.0f / (gl[(long)bh * 400 + gq0] * sP);
  const float cm1 = gm[(long)bh * 400 + gq1];
  const float invLsp1 = 1.0f / (gl[(long)bh * 400 + gq1] * sP);

  int4v accd0[4], accd1[4];
#pragma unroll
  for (int dt = 0; dt < 4; ++dt) {
    accd0[dt] = (int4v){0, 0, 0, 0};
    accd1[dt] = (int4v){0, 0, 0, 0};
  }
  __syncthreads();

  for (int c0 = 0; c0 < 400; c0 += 128) {
#pragma unroll
    for (int tf = 0; tf < 8; ++tf) {
      int4v kf = *(const int4v*)(kb + (long)(c0 + tf * 16 + fr) * 576 + fk * 16);
      int4v s0 = MFMA_I8(kf, qf0, ((int4v){0, 0, 0, 0}));
      int4v s1 = MFMA_I8(kf, qf1, ((int4v){0, 0, 0, 0}));
      const int tbase = c0 + tf * 16 + fk * 4;
      u32 pack0 = 0, pack1 = 0;
      if (tbase < 400) {
#pragma unroll
        for (int r = 0; r < 4; ++r) {
          float cf0 = fminf(fmaxf(rintf((float)s0[r] * c1), -128.f), 127.f);
          float e0 = exp2f((cf0 - cm0) * c2);
          float pu0 = fminf(fmaxf(rintf(e0 * invLsp0), 0.f), 255.f);
          pack0 |= ((u32)(((int)pu0 - 128) & 0xff)) << (8 * r);
          float cf1 = fminf(fmaxf(rintf((float)s1[r] * c1), -128.f), 127.f);
          float e1 = exp2f((cf1 - cm1) * c2);
          float pu1 = fminf(fmaxf(rintf(e1 * invLsp1), 0.f), 255.f);
          pack1 |= ((u32)(((int)pu1 - 128) & 0xff)) << (8 * r);
        }
      }
      *(u32*)&Ps[qloc * 144 + tf * 16 + fk * 4] = pack0;
      *(u32*)&Ps[(qloc + 64) * 144 + tf * 16 + fk * 4] = pack1;
    }
    __syncthreads();
    int4v pf00 = *(const int4v*)&Ps[qloc * 144 + fk * 16];
    int4v pf01 = *(const int4v*)&Ps[qloc * 144 + 64 + fk * 16];
    int4v pf10 = *(const int4v*)&Ps[(qloc + 64) * 144 + fk * 16];
    int4v pf11 = *(const int4v*)&Ps[(qloc + 64) * 144 + 64 + fk * 16];
    const bool v0ok = (c0 + fk * 16) < 400;
    const bool v1ok = (c0 + 64 + fk * 16) < 400;
#pragma unroll
    for (int dt = 0; dt < 4; ++dt) {
      const long vrow = (long)(dt * 16 + fr) * 400;
      int4v vf0 = v0ok ? *(const int4v*)(vtb + vrow + c0 + fk * 16) : (int4v){0, 0, 0, 0};
      int4v vf1 = v1ok ? *(const int4v*)(vtb + vrow + c0 + 64 + fk * 16) : (int4v){0, 0, 0, 0};
      accd0[dt] = MFMA_I8(vf0, pf00, accd0[dt]);
      accd0[dt] = MFMA_I8(vf1, pf01, accd0[dt]);
      accd1[dt] = MFMA_I8(vf0, pf10, accd1[dt]);
      accd1[dt] = MFMA_I8(vf1, pf11, accd1[dt]);
    }
    __syncthreads();
  }
  float vmax = 0.f;
  if (gq0r < 400) {
#pragma unroll
    for (int dt = 0; dt < 4; ++dt) {
      const int d0 = dt * 16 + fk * 4;
      float4 o;
      o.x = sPV * (float)(accd0[dt][0] + 128 * colsV[d0 + 0]);
      o.y = sPV * (float)(accd0[dt][1] + 128 * colsV[d0 + 1]);
      o.z = sPV * (float)(accd0[dt][2] + 128 * colsV[d0 + 2]);
      o.w = sPV * (float)(accd0[dt][3] + 128 * colsV[d0 + 3]);
      vmax = fmaxf(vmax, fmaxf(fmaxf(fabsf(o.x), fabsf(o.y)), fmaxf(fabsf(o.z), fabsf(o.w))));
      *(float4*)&ctx[(long)(b * 400 + gq0r) * 192 + hh * 64 + d0] = o;
    }
  }
  if (gq1r < 400) {
#pragma unroll
    for (int dt = 0; dt < 4; ++dt) {
      const int d0 = dt * 16 + fk * 4;
      float4 o;
      o.x = sPV * (float)(accd1[dt][0] + 128 * colsV[d0 + 0]);
      o.y = sPV * (float)(accd1[dt][1] + 128 * colsV[d0 + 1]);
      o.z = sPV * (float)(accd1[dt][2] + 128 * colsV[d0 + 2]);
      o.w = sPV * (float)(accd1[dt][3] + 128 * colsV[d0 + 3]);
      vmax = fmaxf(vmax, fmaxf(fmaxf(fabsf(o.x), fabsf(o.y)), fmaxf(fabsf(o.z), fabsf(o.w))));
      *(float4*)&ctx[(long)(b * 400 + gq1r) * 192 + hh * 64 + d0] = o;
    }
  }
  float m = warpMax(vmax);
  if (lane == 0) red[w] = m;
  __syncthreads();
  if (tid == 0) {
    float r = fmaxf(fmaxf(red[0], red[1]), fmaxf(red[2], red[3]));
    atomicMax(sc + slotCtx * 16 + (blockIdx.x & 15), __float_as_uint(r));
  }
}

// ---------------------------------------------------------------------------
__global__ __launch_bounds__(192) void k_pool(const float* __restrict__ xln,
                                              float* __restrict__ pooled,
                                              u32* __restrict__ slot) {
  int b = blockIdx.x, d = threadIdx.x;
  float sum = 0.f;
  for (int s = 0; s < 400; ++s) sum += xln[((long)b * 400 + s) * 192 + d];
  float v = sum / 400.0f;
  pooled[(long)b * 192 + d] = v;
  __shared__ float red[3];
  float m = warpMax(fabsf(v));
  if ((d & 63) == 0) red[d >> 6] = m;
  __syncthreads();
  if (d == 0)
    atomicMax(slot + (b & 15), __float_as_uint(fmaxf(fmaxf(red[0], red[1]), red[2])));
}

__global__ __launch_bounds__(64) void k_logits(const float* __restrict__ pooled,
                                               const float* __restrict__ clfq,
                                               const float* __restrict__ clfb,
                                               const u32* __restrict__ sc,
                                               float* __restrict__ out) {
  int c = blockIdx.x, b = blockIdx.y, lane = threadIdx.x;
  float sp = read_max16(sc, SLOT_POOL) / 127.0f + 1e-8f;
  float acc = 0.f;
#pragma unroll
  for (int j = 0; j < 3; ++j) {
    int d = lane + 64 * j;
    acc += fqs(pooled[(long)b * 192 + d], sp) * clfq[c * 192 + d];
  }
#pragma unroll
  for (int o = 32; o > 0; o >>= 1) acc += __shfl_down(acc, o);
  if (lane == 0) out[b * 7 + c] = acc + clfb[c];
}

// ---------------------------------------------------------------------------
// host
// ---------------------------------------------------------------------------
static inline int gsz(long n4, long cap) {
  long g = (n4 + 255) / 256;
  return (int)(g < cap ? g : cap);
}

extern "C" void kernel_launch(void* const* d_in, const int* in_sizes, int n_in,
                              void* d_out, int out_size, void* d_ws, size_t ws_size,
                              hipStream_t stream) {
  (void)in_sizes; (void)n_in; (void)out_size; (void)ws_size;

  const float* x = (const float*)d_in[0];
  const float* pw = (const float*)d_in[1];
  const float* pb = (const float*)d_in[2];
  const float* ln1g = (const float*)d_in[3];
  const float* ln1b = (const float*)d_in[4];
  const float* wqkv = (const float*)d_in[5];
  const float* bqkv = (const float*)d_in[6];
  const float* wo = (const float*)d_in[7];
  const float* bo = (const float*)d_in[8];
  const float* ln2g = (const float*)d_in[9];
  const float* ln2b = (const float*)d_in[10];
  const float* w1 = (const float*)d_in[11];
  const float* b1 = (const float*)d_in[12];
  const float* w2 = (const float*)d_in[13];
  const float* b2 = (const float*)d_in[14];
  const float* lnfg = (const float*)d_in[15];
  const float* lnfb = (const float*)d_in[16];
  const float* clfw = (const float*)d_in[17];
  const float* clfb = (const float*)d_in[18];

  float* ws = (float*)d_ws;
  u32* sc = (u32*)d_ws;
  float* GM = ws + OFF_GM;
  int* GMI = (int*)GM;
  float* GL = ws + OFF_GL;
  float* POOL = ws + OFF_POOL;
  float* PWQ = ws + OFF_PWQ;
  float* CLFQ = ws + OFF_CLFQ;
  float* H = ws + OFF_H;

  signed char* RA = (signed char*)(ws + OFF_A);
  signed char* RU = (signed char*)(ws + OFF_U);
  signed char* PLQ_H = RU;
  signed char* PLQ_L = RU + 19660800;
  float* PLQ_S = (float*)(RU + 39321600);
  signed char* QKV8 = RA;
  signed char* VT8 = RA + 58982400;
  float* CTXF = (float*)RU;
  float* WOOUT = (float*)RU;  // aliases CTXF: gemm8<true> syncs before writes
  signed char* PL2_H = RA;
  signed char* PL2_L = RA + 19660800;
  float* PL2_S = (float*)(RA + 39321600);
  signed char* GELU8 = RU;
  float* W2OUT = (float*)RA;
  float* FINALF = (float*)RU;

  int* COLSUM = (int*)POOL;
  signed char* WQC = (signed char*)POOL;
  signed char* WOC2 = (signed char*)POOL;
  signed char* W1C2 = (signed char*)POOL + 36864;
  signed char* W2C2 = (signed char*)POOL + 36864;
  float* out = (float*)d_out;

  k_zero<<<(N_SLOT_WORDS + 255) / 256, 256, 0, stream>>>(sc, N_SLOT_WORDS);

  auto amax = [&](const float* p, long n, int slot) {
    k_absmax<<<gsz(n / 4, 256), 256, 0, stream>>>((const float4*)p, n / 4, sc + slot * 16);
  };
  amax(pw, 3840, SLOT_PW);
  amax(clfw, 1344, SLOT_CLF);
  amax(x, 2048000, SLOT_X);
  for (int i = 0; i < NL; ++i) {
    int Lb = 16 + i * 16;
    amax(wqkv + (long)i * 110592, 110592, Lb + 0);
    amax(wo + (long)i * 36864, 36864, Lb + 1);
    amax(w1 + (long)i * 147456, 147456, Lb + 2);
    amax(w2 + (long)i * 147456, 147456, Lb + 3);
  }
  k_quant4<<<gsz(960, 256), 256, 0, stream>>>((const float4*)pw, (float4*)PWQ, 960, sc, SLOT_PW);
  k_quant4<<<gsz(336, 256), 256, 0, stream>>>((const float4*)clfw, (float4*)CLFQ, 336, sc,
                                              SLOT_CLF);

  // patch embed -> RA fp32; fused H = fq(emb) + first LN -> planes (RU head)
  k_patch<<<3200, 192, 0, stream>>>(x, PWQ, pb, sc, (float*)RA, sc + SLOT_EMB * 16);
  k_resln<2, true><<<(int)(ROWS / 4), 256, 0, stream>>>(
      H, (const float*)RA, sc, SLOT_EMB, ln1g, ln1b, PLQ_H, PLQ_L, PLQ_S, nullptr, (int)ROWS);

  for (int i = 0; i < NL; ++i) {
    int Lb = 16 + i * 16;
    // --- attention ---
    k_wquant<<<108, 256, 0, stream>>>((const float4*)(wqkv + (long)i * 110592), (u32*)WQC,
                                      27648, sc, Lb + 0);
    k_gemm16<false, 1><<<2400, 256, 0, stream>>>(PLQ_H, PLQ_L, PLQ_S, WQC, Lb + 0,
                                                 bqkv + i * 576, nullptr, 576, 3, sc, Lb + 4,
                                                 192);
    k_gemm16<false, 2><<<2400, 256, 0, stream>>>(PLQ_H, PLQ_L, PLQ_S, WQC, Lb + 0,
                                                 bqkv + i * 576, QKV8, 576, 3, sc, Lb + 4,
                                                 192);
    k_vt<<<768, 256, 0, stream>>>(QKV8, VT8, COLSUM);
    k_attn0<<<3072, 256, 0, stream>>>(QKV8, GMI, sc, Lb + 4, Lb + 7);
    k_attn1<<<3072, 256, 0, stream>>>(QKV8, GM, GL, GMI, sc, Lb + 4, Lb + 7, Lb + 8);
    k_attn_pv<<<3072, 256, 0, stream>>>(QKV8, VT8, COLSUM, CTXF, GM, GL, sc, Lb + 4, Lb + 7,
                                        Lb + 8, Lb + 9);
    k_wquant<<<36, 256, 0, stream>>>((const float4*)(wo + (long)i * 36864), (u32*)WOC2, 9216,
                                     sc, Lb + 1);
    {
      // wo GEMM: fp32 ctx quantized inline (slot Lb+9), out fp32 + absmax
      dim3 g(1, 800);
      k_gemm8<true><<<g, 256, 0, stream>>>(nullptr, CTXF, Lb + 9, WOC2, Lb + 1, bo + i * 192,
                                           WOOUT, 192, 192, sc, Lb + 10);
    }
    k_resln<1, true><<<(int)(ROWS / 4), 256, 0, stream>>>(
        H, WOOUT, sc, Lb + 10, ln2g + i * 192, ln2b + i * 192, PL2_H, PL2_L, PL2_S, nullptr,
        (int)ROWS);
    // --- MLP ---
    k_wquant<<<144, 256, 0, stream>>>((const float4*)(w1 + (long)i * 147456), (u32*)W1C2,
                                      36864, sc, Lb + 2);
    k_gemm16<true, 1><<<3200, 256, 0, stream>>>(PL2_H, PL2_L, PL2_S, W1C2, Lb + 2,
                                                b1 + i * 768, nullptr, 768, 4, sc, Lb + 11,
                                                768);
    k_gemm16<true, 2><<<3200, 256, 0, stream>>>(PL2_H, PL2_L, PL2_S, W1C2, Lb + 2,
                                                b1 + i * 768, GELU8, 768, 4, sc, Lb + 11, 768);
    k_wquant<<<144, 256, 0, stream>>>((const float4*)(w2 + (long)i * 147456), (u32*)W2C2,
                                      36864, sc, Lb + 3);
    {
      dim3 g(1, 800);
      k_gemm8<false><<<g, 256, 0, stream>>>(GELU8, nullptr, Lb + 11, W2C2, Lb + 3,
                                            b2 + i * 192, W2OUT, 192, 768, sc, Lb + 12);
    }
    if (i < NL - 1) {
      k_resln<1, true><<<(int)(ROWS / 4), 256, 0, stream>>>(
          H, W2OUT, sc, Lb + 12, ln1g + (i + 1) * 192, ln1b + (i + 1) * 192, PLQ_H, PLQ_L,
          PLQ_S, nullptr, (int)ROWS);
    } else {
      k_resln<1, false><<<(int)(ROWS / 4), 256, 0, stream>>>(
          H, W2OUT, sc, Lb + 12, lnfg, lnfb, nullptr, nullptr, nullptr, FINALF, (int)ROWS);
    }
  }

  // pool + classifier
  k_pool<<<256, 192, 0, stream>>>(FINALF, POOL, sc + SLOT_POOL * 16);
  {
    dim3 g(7, 256);
    k_logits<<<g, 64, 0, stream>>>(POOL, CLFQ, clfb, sc, out);
  }
}